// Round 1
// baseline (1291.929 us; speedup 1.0000x reference)
//
#include <hip/hip_runtime.h>
#include <math.h>

// ---------------------------------------------------------------------------
// GATv2 x3 + LN + graph max-pool + MLP.  fp32 everywhere (round 1: correctness).
// Layout: H=4 heads x C=32 ch = 128 features. Edges get +N self-loops with
// fill_value='mean' edge attr.  CSR by dst built per call (counting sort).
// ---------------------------------------------------------------------------

#define LN_EPS 1e-5f

// ---------------- prepass ----------------

__global__ void k_degree(const int* __restrict__ ei, const float* __restrict__ ea,
                         int* __restrict__ cnt, float* __restrict__ asum, int E) {
  int e = blockIdx.x * blockDim.x + threadIdx.x;
  if (e >= E) return;
  int d = ei[E + e];
  atomicAdd(&cnt[d], 1);
  atomicAdd(&asum[d * 3 + 0], ea[e * 3 + 0]);
  atomicAdd(&asum[d * 3 + 1], ea[e * 3 + 1]);
  atomicAdd(&asum[d * 3 + 2], ea[e * 3 + 2]);
}

__global__ void k_loopattr(const int* __restrict__ cnt, float* __restrict__ asum, int N) {
  int n = blockIdx.x * blockDim.x + threadIdx.x;
  if (n >= N) return;
  float c = fmaxf((float)cnt[n], 1.0f);
  float inv = 1.0f / c;
  asum[n * 3 + 0] *= inv;
  asum[n * 3 + 1] *= inv;
  asum[n * 3 + 2] *= inv;
}

// deg[n] = cnt[n] + 1 (self loop).  3-kernel exclusive scan over N elements.
__global__ void k_scan1(const int* __restrict__ cnt, int* __restrict__ bsum, int N) {
  __shared__ int sh[256];
  int t = threadIdx.x;
  int n = blockIdx.x * 256 + t;
  sh[t] = (n < N) ? (cnt[n] + 1) : 0;
  __syncthreads();
  for (int s = 128; s > 0; s >>= 1) {
    if (t < s) sh[t] += sh[t + s];
    __syncthreads();
  }
  if (t == 0) bsum[blockIdx.x] = sh[0];
}

__global__ void k_scan2(int* __restrict__ bsum, int* __restrict__ offs, int nb, int total, int N) {
  __shared__ int sh[256];
  int t = threadIdx.x;
  int v = (t < nb) ? bsum[t] : 0;
  sh[t] = v;
  __syncthreads();
  for (int d = 1; d < 256; d <<= 1) {
    int add = (t >= d) ? sh[t - d] : 0;
    __syncthreads();
    sh[t] += add;
    __syncthreads();
  }
  if (t < nb) bsum[t] = sh[t] - v;  // exclusive block bases
  if (t == 0) offs[N] = total;
}

__global__ void k_scan3(const int* __restrict__ cnt, const int* __restrict__ bsum,
                        int* __restrict__ offs, int* __restrict__ cursor, int N) {
  __shared__ int sh[256];
  int t = threadIdx.x;
  int n = blockIdx.x * 256 + t;
  int v = (n < N) ? (cnt[n] + 1) : 0;
  sh[t] = v;
  __syncthreads();
  for (int d = 1; d < 256; d <<= 1) {
    int add = (t >= d) ? sh[t - d] : 0;
    __syncthreads();
    sh[t] += add;
    __syncthreads();
  }
  if (n < N) {
    int o = bsum[blockIdx.x] + sh[t] - v;
    offs[n] = o;
    cursor[n] = o;
  }
}

__global__ void k_scatter(const int* __restrict__ ei, const float* __restrict__ ea,
                          const float* __restrict__ loop_attr, int* __restrict__ cursor,
                          int* __restrict__ csr_src, int* __restrict__ csr_dst,
                          float* __restrict__ csr_ea, int E, int EP) {
  int e = blockIdx.x * blockDim.x + threadIdx.x;
  if (e >= EP) return;
  int s, d;
  float a0, a1, a2;
  if (e < E) {
    s = ei[e];
    d = ei[E + e];
    a0 = ea[e * 3 + 0];
    a1 = ea[e * 3 + 1];
    a2 = ea[e * 3 + 2];
  } else {
    int n = e - E;
    s = n;
    d = n;
    a0 = loop_attr[n * 3 + 0];
    a1 = loop_attr[n * 3 + 1];
    a2 = loop_attr[n * 3 + 2];
  }
  int pos = atomicAdd(&cursor[d], 1);
  csr_src[pos] = s;
  csr_dst[pos] = d;
  csr_ea[pos * 3 + 0] = a0;
  csr_ea[pos * 3 + 1] = a1;
  csr_ea[pos * 3 + 2] = a2;
}

// ---------------- GEMM: out[n][j] = bias[j] + sum_k x[n][k] * W[j][k] ----------------
// BM=64 nodes, BN=128 (full), BK=32 slices; 256 threads, 4x8 register tile.
__global__ __launch_bounds__(256) void k_gemm(const float* __restrict__ x,
                                              const float* __restrict__ Wl, const float* __restrict__ bl,
                                              const float* __restrict__ Wr, const float* __restrict__ br,
                                              float* __restrict__ xl, float* __restrict__ xr, int N) {
  const float* W = blockIdx.y ? Wr : Wl;
  const float* bias = blockIdx.y ? br : bl;
  float* out = blockIdx.y ? xr : xl;

  __shared__ float Ws[32 * 132];  // Ws[k][j] (transposed), pad 132
  __shared__ float xs[32 * 68];   // xs[k][i], pad 68

  int t = threadIdx.x;
  int tx = t & 15;   // j0 = tx*8
  int ty = t >> 4;   // i0 = ty*4
  int i0 = blockIdx.x * 64;

  float acc[4][8];
#pragma unroll
  for (int a = 0; a < 4; ++a)
#pragma unroll
    for (int b = 0; b < 8; ++b) acc[a][b] = 0.f;

  for (int kt = 0; kt < 4; ++kt) {
    int kb = kt * 32;
#pragma unroll
    for (int r = 0; r < 16; ++r) {
      int idx = r * 256 + t;  // 0..4095
      int j = idx >> 5, k = idx & 31;
      Ws[k * 132 + j] = W[j * 128 + kb + k];
    }
#pragma unroll
    for (int r = 0; r < 8; ++r) {
      int idx = r * 256 + t;  // 0..2047
      int i = idx >> 5, k = idx & 31;
      int n = i0 + i;
      xs[k * 68 + i] = (n < N) ? x[(size_t)n * 128 + kb + k] : 0.f;
    }
    __syncthreads();
#pragma unroll
    for (int k = 0; k < 32; ++k) {
      const float4 a4 = *(const float4*)&xs[k * 68 + ty * 4];
      const float4 w0 = *(const float4*)&Ws[k * 132 + tx * 8];
      const float4 w1 = *(const float4*)&Ws[k * 132 + tx * 8 + 4];
      float av[4] = {a4.x, a4.y, a4.z, a4.w};
      float wv[8] = {w0.x, w0.y, w0.z, w0.w, w1.x, w1.y, w1.z, w1.w};
#pragma unroll
      for (int a = 0; a < 4; ++a)
#pragma unroll
        for (int b = 0; b < 8; ++b) acc[a][b] += av[a] * wv[b];
    }
    __syncthreads();
  }

  float4 b0 = *(const float4*)&bias[tx * 8];
  float4 b1 = *(const float4*)&bias[tx * 8 + 4];
#pragma unroll
  for (int a = 0; a < 4; ++a) {
    int n = i0 + ty * 4 + a;
    if (n < N) {
      float4 o0 = {acc[a][0] + b0.x, acc[a][1] + b0.y, acc[a][2] + b0.z, acc[a][3] + b0.w};
      float4 o1 = {acc[a][4] + b1.x, acc[a][5] + b1.y, acc[a][6] + b1.z, acc[a][7] + b1.w};
      *(float4*)&out[(size_t)n * 128 + tx * 8] = o0;
      *(float4*)&out[(size_t)n * 128 + tx * 8 + 4] = o1;
    }
  }
}

// ---------------- edge scores: s[pos][h] = sum_c leakyrelu(xl[src]+xr[dst]+We@ea)*att ----------------
// half-wave (32 lanes) per edge; lane handles channels 4*lane..4*lane+3 (head = lane>>3)
__global__ __launch_bounds__(256) void k_score(const float* __restrict__ xl, const float* __restrict__ xr,
                                               const int* __restrict__ csr_src, const int* __restrict__ csr_dst,
                                               const float* __restrict__ csr_ea,
                                               const float* __restrict__ We, const float* __restrict__ att,
                                               float* __restrict__ sbuf, int EP) {
  int lane = threadIdx.x & 31;
  int c0 = lane * 4;
  float we[4][3], at[4];
#pragma unroll
  for (int j = 0; j < 4; ++j) {
    we[j][0] = We[(c0 + j) * 3 + 0];
    we[j][1] = We[(c0 + j) * 3 + 1];
    we[j][2] = We[(c0 + j) * 3 + 2];
    at[j] = att[c0 + j];  // att[h][c] flat == channel index
  }
  int hw0 = (blockIdx.x * blockDim.x + threadIdx.x) >> 5;
  int nhw = (gridDim.x * blockDim.x) >> 5;
  for (int p = hw0; p < EP; p += nhw) {
    int src = csr_src[p], dst = csr_dst[p];
    float ea0 = csr_ea[p * 3 + 0], ea1 = csr_ea[p * 3 + 1], ea2 = csr_ea[p * 3 + 2];
    const float4 a = *(const float4*)&xl[(size_t)src * 128 + c0];
    const float4 b = *(const float4*)&xr[(size_t)dst * 128 + c0];
    float av[4] = {a.x, a.y, a.z, a.w};
    float bv[4] = {b.x, b.y, b.z, b.w};
    float sacc = 0.f;
#pragma unroll
    for (int j = 0; j < 4; ++j) {
      float m = av[j] + bv[j] + we[j][0] * ea0 + we[j][1] * ea1 + we[j][2] * ea2;
      m = (m > 0.f) ? m : 0.2f * m;
      sacc += m * at[j];
    }
    sacc += __shfl_xor(sacc, 1);
    sacc += __shfl_xor(sacc, 2);
    sacc += __shfl_xor(sacc, 4);
    if ((lane & 7) == 0) sbuf[(size_t)p * 4 + (lane >> 3)] = sacc;
  }
}

// ---------------- per-node softmax + weighted aggregate + (bias, relu, LN) epilogue ----------------
// one wave (64 lanes) per node; lane handles channels 2*lane, 2*lane+1; head = lane>>4
__global__ __launch_bounds__(256) void k_agg(const float* __restrict__ xl, const float* __restrict__ sbuf,
                                             const int* __restrict__ csr_src, const int* __restrict__ offs,
                                             const float* __restrict__ bo,
                                             const float* __restrict__ lng, const float* __restrict__ lnb,
                                             float* __restrict__ xnext, float* __restrict__ emb,
                                             float* __restrict__ pin, int last, int N) {
  int w = (blockIdx.x * blockDim.x + threadIdx.x) >> 6;
  if (w >= N) return;
  int lane = threadIdx.x & 63;
  int beg = offs[w], end = offs[w + 1];
  int h = lane >> 4, sub = lane & 15;

  float mx = -1e30f;
  for (int p = beg + sub; p < end; p += 16) mx = fmaxf(mx, sbuf[(size_t)p * 4 + h]);
  mx = fmaxf(mx, __shfl_xor(mx, 1));
  mx = fmaxf(mx, __shfl_xor(mx, 2));
  mx = fmaxf(mx, __shfl_xor(mx, 4));
  mx = fmaxf(mx, __shfl_xor(mx, 8));

  float den = 0.f;
  for (int p = beg + sub; p < end; p += 16) den += __expf(sbuf[(size_t)p * 4 + h] - mx);
  den += __shfl_xor(den, 1);
  den += __shfl_xor(den, 2);
  den += __shfl_xor(den, 4);
  den += __shfl_xor(den, 8);
  float inv = 1.0f / (den + 1e-16f);

  int c = lane * 2;
  float ax = 0.f, ay = 0.f;
  for (int p = beg; p < end; ++p) {
    int src = csr_src[p];
    float alpha = __expf(sbuf[(size_t)p * 4 + h] - mx) * inv;
    float2 v = *(const float2*)&xl[(size_t)src * 128 + c];
    ax += alpha * v.x;
    ay += alpha * v.y;
  }
  ax += bo[c];
  ay += bo[c + 1];

  if (last) {
    emb[(size_t)w * 128 + c] = ax;
    emb[(size_t)w * 128 + c + 1] = ay;
    pin[(size_t)w * 128 + c] = fmaxf(ax, 0.f);
    pin[(size_t)w * 128 + c + 1] = fmaxf(ay, 0.f);
  } else {
    float rx = fmaxf(ax, 0.f), ry = fmaxf(ay, 0.f);
    float s = rx + ry;
    s += __shfl_xor(s, 1);
    s += __shfl_xor(s, 2);
    s += __shfl_xor(s, 4);
    s += __shfl_xor(s, 8);
    s += __shfl_xor(s, 16);
    s += __shfl_xor(s, 32);
    float mu = s * 0.0078125f;  // /128
    float dx = rx - mu, dy = ry - mu;
    float v2 = dx * dx + dy * dy;
    v2 += __shfl_xor(v2, 1);
    v2 += __shfl_xor(v2, 2);
    v2 += __shfl_xor(v2, 4);
    v2 += __shfl_xor(v2, 8);
    v2 += __shfl_xor(v2, 16);
    v2 += __shfl_xor(v2, 32);
    float var = v2 * 0.0078125f;
    float rstd = rsqrtf(var + LN_EPS);
    xnext[(size_t)w * 128 + c] = dx * rstd * lng[c] + lnb[c];
    xnext[(size_t)w * 128 + c + 1] = dy * rstd * lng[c + 1] + lnb[c + 1];
  }
}

// ---------------- graph max-pool (values >= 0, so uint atomicMax on 0-init works) ----------------
__global__ void k_pool(const float* __restrict__ pin, const int* __restrict__ batch,
                       float* __restrict__ pooled, int N) {
  int c = threadIdx.x;  // 128 channels
  int base = blockIdx.x * 64;
  int limit = min(base + 64, N);
  float cur = 0.f;
  int curg = -1;
  for (int n = base; n < limit; ++n) {
    int g = batch[n];
    if (g != curg) {
      if (curg >= 0) atomicMax((unsigned int*)&pooled[curg * 128 + c], __float_as_uint(cur));
      curg = g;
      cur = 0.f;
    }
    cur = fmaxf(cur, pin[(size_t)n * 128 + c]);
  }
  if (curg >= 0) atomicMax((unsigned int*)&pooled[curg * 128 + c], __float_as_uint(cur));
}

// ---------------- MLP: 128 -> 32 -> 32 -> 32 -> 1 ----------------
__global__ void k_mlp(const float* __restrict__ pooled,
                      const float* __restrict__ pw1, const float* __restrict__ pb1,
                      const float* __restrict__ pw2, const float* __restrict__ pb2,
                      const float* __restrict__ pw3, const float* __restrict__ pb3,
                      const float* __restrict__ pw4, const float* __restrict__ pb4,
                      float* __restrict__ out) {
  int g = blockIdx.x;
  int t = threadIdx.x;  // 64 threads
  __shared__ float buf1[32], buf2[32];
  if (t < 32) {
    float acc = pb1[t];
    for (int k = 0; k < 128; ++k) acc += pw1[t * 128 + k] * pooled[g * 128 + k];
    buf1[t] = fmaxf(acc, 0.f);
  }
  __syncthreads();
  if (t < 32) {
    float acc = pb2[t];
    for (int k = 0; k < 32; ++k) acc += pw2[t * 32 + k] * buf1[k];
    buf2[t] = fmaxf(acc, 0.f);
  }
  __syncthreads();
  if (t < 32) {
    float acc = pb3[t];
    for (int k = 0; k < 32; ++k) acc += pw3[t * 32 + k] * buf2[k];
    buf1[t] = fmaxf(acc, 0.f);
  }
  __syncthreads();
  if (t == 0) {
    float acc = pb4[0];
    for (int k = 0; k < 32; ++k) acc += pw4[k] * buf1[k];
    out[g] = acc;
  }
}

// ---------------------------------------------------------------------------

extern "C" void kernel_launch(void* const* d_in, const int* in_sizes, int n_in,
                              void* d_out, int out_size, void* d_ws, size_t ws_size,
                              hipStream_t stream) {
  const float* x_in = (const float*)d_in[0];
  const int* ei = (const int*)d_in[1];
  const int* batch = (const int*)d_in[2];
  const float* ea = (const float*)d_in[3];

  const int N = in_sizes[0] / 128;
  const int E = in_sizes[1] / 2;
  const int EP = E + N;
  const int G = out_size - N * 128;

  // layer params
  const float *Wl[3], *bl[3], *Wr[3], *br[3], *We[3], *att[3], *bo[3];
  for (int l = 0; l < 3; ++l) {
    Wl[l] = (const float*)d_in[4 + 7 * l];
    bl[l] = (const float*)d_in[5 + 7 * l];
    Wr[l] = (const float*)d_in[6 + 7 * l];
    br[l] = (const float*)d_in[7 + 7 * l];
    We[l] = (const float*)d_in[8 + 7 * l];
    att[l] = (const float*)d_in[9 + 7 * l];
    bo[l] = (const float*)d_in[10 + 7 * l];
  }
  const float* lng[2] = {(const float*)d_in[25], (const float*)d_in[27]};
  const float* lnb[2] = {(const float*)d_in[26], (const float*)d_in[28]};
  const float* pw1 = (const float*)d_in[29];
  const float* pb1 = (const float*)d_in[30];
  const float* pw2 = (const float*)d_in[31];
  const float* pb2 = (const float*)d_in[32];
  const float* pw3 = (const float*)d_in[33];
  const float* pb3 = (const float*)d_in[34];
  const float* pw4 = (const float*)d_in[35];
  const float* pb4 = (const float*)d_in[36];

  // workspace carve-up
  char* base = (char*)d_ws;
  size_t cur = 0;
  auto carve = [&](size_t bytes) -> char* {
    char* p = base + cur;
    cur += (bytes + 255) & ~(size_t)255;
    return p;
  };
  float* xl = (float*)carve((size_t)N * 128 * 4);
  float* xr = (float*)carve((size_t)N * 128 * 4);
  float* xbuf = (float*)carve((size_t)N * 128 * 4);
  float* sbuf = (float*)carve((size_t)EP * 4 * 4);
  int* csr_src = (int*)carve((size_t)EP * 4);
  int* csr_dst = (int*)carve((size_t)EP * 4);
  float* csr_ea = (float*)carve((size_t)EP * 3 * 4);
  int* offs = (int*)carve((size_t)(N + 1) * 4);
  int* cursor = (int*)carve((size_t)N * 4);
  int* cnt = (int*)carve((size_t)N * 4);
  float* asum = (float*)carve((size_t)N * 3 * 4);  // becomes loop_attr
  int* bsum = (int*)carve(1024);
  float* pooled = (float*)carve((size_t)G * 128 * 4);

  float* emb_out = (float*)d_out;
  float* mlp_out = (float*)d_out + (size_t)N * 128;

  const int NB = (N + 255) / 256;

  hipMemsetAsync(cnt, 0, (size_t)N * 4, stream);
  hipMemsetAsync(asum, 0, (size_t)N * 3 * 4, stream);
  hipMemsetAsync(pooled, 0, (size_t)G * 128 * 4, stream);

  k_degree<<<(E + 255) / 256, 256, 0, stream>>>(ei, ea, cnt, asum, E);
  k_loopattr<<<(N + 255) / 256, 256, 0, stream>>>(cnt, asum, N);
  k_scan1<<<NB, 256, 0, stream>>>(cnt, bsum, N);
  k_scan2<<<1, 256, 0, stream>>>(bsum, offs, NB, EP, N);
  k_scan3<<<NB, 256, 0, stream>>>(cnt, bsum, offs, cursor, N);
  k_scatter<<<(EP + 255) / 256, 256, 0, stream>>>(ei, ea, asum, cursor, csr_src, csr_dst, csr_ea, E, EP);

  for (int l = 0; l < 3; ++l) {
    const float* xsrc = (l == 0) ? x_in : xbuf;
    dim3 ggrid((N + 63) / 64, 2);
    k_gemm<<<ggrid, 256, 0, stream>>>(xsrc, Wl[l], bl[l], Wr[l], br[l], xl, xr, N);
    k_score<<<8192, 256, 0, stream>>>(xl, xr, csr_src, csr_dst, csr_ea, We[l], att[l], sbuf, EP);
    int last = (l == 2) ? 1 : 0;
    const float* g = last ? (const float*)nullptr : lng[l];
    const float* b = last ? (const float*)nullptr : lnb[l];
    k_agg<<<(N * 64 + 255) / 256, 256, 0, stream>>>(xl, sbuf, csr_src, offs, bo[l],
                                                    last ? bo[l] : g, last ? bo[l] : b,
                                                    xbuf, emb_out, xbuf, last, N);
  }

  k_pool<<<(N + 63) / 64, 128, 0, stream>>>(xbuf, batch, pooled, N);
  k_mlp<<<G, 64, 0, stream>>>(pooled, pw1, pb1, pw2, pb2, pw3, pb3, pw4, pb4, mlp_out);
}

// Round 2
// 1008.221 us; speedup vs baseline: 1.2814x; 1.2814x over previous
//
#include <hip/hip_runtime.h>
#include <math.h>

// ---------------------------------------------------------------------------
// GATv2 x3 + LN + graph max-pool + MLP.  fp32.
// Round 2: (a) int-only degree atomics, loop_attr computed from CSR (no fp
// atomics); (b) score+softmax+aggregate fused into one online-softmax pass
// per node (one wave/node) -- eliminates k_score and sbuf entirely.
// CSR by dst built per call; self-loop reserved at slot offs[n+1]-1.
// ---------------------------------------------------------------------------

#define LN_EPS 1e-5f

// ---------------- prepass ----------------

__global__ void k_degree(const int* __restrict__ ei, int* __restrict__ cnt, int E) {
  int e = blockIdx.x * blockDim.x + threadIdx.x;
  if (e >= E) return;
  atomicAdd(&cnt[ei[E + e]], 1);
}

// deg[n] = cnt[n] + 1 (self loop).  3-kernel exclusive scan over N elements.
__global__ void k_scan1(const int* __restrict__ cnt, int* __restrict__ bsum, int N) {
  __shared__ int sh[256];
  int t = threadIdx.x;
  int n = blockIdx.x * 256 + t;
  sh[t] = (n < N) ? (cnt[n] + 1) : 0;
  __syncthreads();
  for (int s = 128; s > 0; s >>= 1) {
    if (t < s) sh[t] += sh[t + s];
    __syncthreads();
  }
  if (t == 0) bsum[blockIdx.x] = sh[0];
}

__global__ void k_scan2(int* __restrict__ bsum, int* __restrict__ offs, int nb, int total, int N) {
  __shared__ int sh[256];
  int t = threadIdx.x;
  int v = (t < nb) ? bsum[t] : 0;
  sh[t] = v;
  __syncthreads();
  for (int d = 1; d < 256; d <<= 1) {
    int add = (t >= d) ? sh[t - d] : 0;
    __syncthreads();
    sh[t] += add;
    __syncthreads();
  }
  if (t < nb) bsum[t] = sh[t] - v;  // exclusive block bases
  if (t == 0) offs[N] = total;
}

__global__ void k_scan3(const int* __restrict__ cnt, const int* __restrict__ bsum,
                        int* __restrict__ offs, int* __restrict__ cursor, int N) {
  __shared__ int sh[256];
  int t = threadIdx.x;
  int n = blockIdx.x * 256 + t;
  int v = (n < N) ? (cnt[n] + 1) : 0;
  sh[t] = v;
  __syncthreads();
  for (int d = 1; d < 256; d <<= 1) {
    int add = (t >= d) ? sh[t - d] : 0;
    __syncthreads();
    sh[t] += add;
    __syncthreads();
  }
  if (n < N) {
    int o = bsum[blockIdx.x] + sh[t] - v;
    offs[n] = o;
    cursor[n] = o;  // real edges fill from offs[n]; self-loop slot is offs[n+1]-1
  }
}

// scatter real edges only (self-loop slot left for k_selfloop)
__global__ void k_scatter(const int* __restrict__ ei, const float* __restrict__ ea,
                          int* __restrict__ cursor, int* __restrict__ csr_src,
                          float* __restrict__ csr_ea, int E) {
  int e = blockIdx.x * blockDim.x + threadIdx.x;
  if (e >= E) return;
  int s = ei[e];
  int d = ei[E + e];
  int pos = atomicAdd(&cursor[d], 1);
  csr_src[pos] = s;
  csr_ea[pos * 3 + 0] = ea[e * 3 + 0];
  csr_ea[pos * 3 + 1] = ea[e * 3 + 1];
  csr_ea[pos * 3 + 2] = ea[e * 3 + 2];
}

// per-node: mean of real-edge attrs -> self-loop entry at offs[n+1]-1
__global__ void k_selfloop(const int* __restrict__ offs, int* __restrict__ csr_src,
                           float* __restrict__ csr_ea, int N) {
  int n = blockIdx.x * blockDim.x + threadIdx.x;
  if (n >= N) return;
  int beg = offs[n], last = offs[n + 1] - 1;
  float s0 = 0.f, s1 = 0.f, s2 = 0.f;
  for (int p = beg; p < last; ++p) {
    s0 += csr_ea[p * 3 + 0];
    s1 += csr_ea[p * 3 + 1];
    s2 += csr_ea[p * 3 + 2];
  }
  float invc = 1.0f / fmaxf((float)(last - beg), 1.0f);
  csr_src[last] = n;
  csr_ea[last * 3 + 0] = s0 * invc;
  csr_ea[last * 3 + 1] = s1 * invc;
  csr_ea[last * 3 + 2] = s2 * invc;
}

// ---------------- GEMM: out[n][j] = bias[j] + sum_k x[n][k] * W[j][k] ----------------
// BM=64 nodes, BN=128 (full), BK=32 slices; 256 threads, 4x8 register tile.
__global__ __launch_bounds__(256) void k_gemm(const float* __restrict__ x,
                                              const float* __restrict__ Wl, const float* __restrict__ bl,
                                              const float* __restrict__ Wr, const float* __restrict__ br,
                                              float* __restrict__ xl, float* __restrict__ xr, int N) {
  const float* W = blockIdx.y ? Wr : Wl;
  const float* bias = blockIdx.y ? br : bl;
  float* out = blockIdx.y ? xr : xl;

  __shared__ float Ws[32 * 132];  // Ws[k][j] (transposed), pad 132
  __shared__ float xs[32 * 68];   // xs[k][i], pad 68

  int t = threadIdx.x;
  int tx = t & 15;   // j0 = tx*8
  int ty = t >> 4;   // i0 = ty*4
  int i0 = blockIdx.x * 64;

  float acc[4][8];
#pragma unroll
  for (int a = 0; a < 4; ++a)
#pragma unroll
    for (int b = 0; b < 8; ++b) acc[a][b] = 0.f;

  for (int kt = 0; kt < 4; ++kt) {
    int kb = kt * 32;
#pragma unroll
    for (int r = 0; r < 16; ++r) {
      int idx = r * 256 + t;  // 0..4095
      int j = idx >> 5, k = idx & 31;
      Ws[k * 132 + j] = W[j * 128 + kb + k];
    }
#pragma unroll
    for (int r = 0; r < 8; ++r) {
      int idx = r * 256 + t;  // 0..2047
      int i = idx >> 5, k = idx & 31;
      int n = i0 + i;
      xs[k * 68 + i] = (n < N) ? x[(size_t)n * 128 + kb + k] : 0.f;
    }
    __syncthreads();
#pragma unroll
    for (int k = 0; k < 32; ++k) {
      const float4 a4 = *(const float4*)&xs[k * 68 + ty * 4];
      const float4 w0 = *(const float4*)&Ws[k * 132 + tx * 8];
      const float4 w1 = *(const float4*)&Ws[k * 132 + tx * 8 + 4];
      float av[4] = {a4.x, a4.y, a4.z, a4.w};
      float wv[8] = {w0.x, w0.y, w0.z, w0.w, w1.x, w1.y, w1.z, w1.w};
#pragma unroll
      for (int a = 0; a < 4; ++a)
#pragma unroll
        for (int b = 0; b < 8; ++b) acc[a][b] += av[a] * wv[b];
    }
    __syncthreads();
  }

  float4 b0 = *(const float4*)&bias[tx * 8];
  float4 b1 = *(const float4*)&bias[tx * 8 + 4];
#pragma unroll
  for (int a = 0; a < 4; ++a) {
    int n = i0 + ty * 4 + a;
    if (n < N) {
      float4 o0 = {acc[a][0] + b0.x, acc[a][1] + b0.y, acc[a][2] + b0.z, acc[a][3] + b0.w};
      float4 o1 = {acc[a][4] + b1.x, acc[a][5] + b1.y, acc[a][6] + b1.z, acc[a][7] + b1.w};
      *(float4*)&out[(size_t)n * 128 + tx * 8] = o0;
      *(float4*)&out[(size_t)n * 128 + tx * 8 + 4] = o1;
    }
  }
}

// ---------------- fused: score + online softmax + weighted agg + (bias, relu, LN) ----------------
// one wave (64 lanes) per node; lane handles channels 2*lane, 2*lane+1; head = lane>>4.
// Head group = 16 contiguous lanes => shfl_xor {1,2,4,8} reduces per-head score.
__global__ __launch_bounds__(256) void k_agg(const float* __restrict__ xl, const float* __restrict__ xr,
                                             const int* __restrict__ csr_src, const float* __restrict__ csr_ea,
                                             const int* __restrict__ offs,
                                             const float* __restrict__ We, const float* __restrict__ att,
                                             const float* __restrict__ bo,
                                             const float* __restrict__ lng, const float* __restrict__ lnb,
                                             float* __restrict__ xnext, float* __restrict__ emb,
                                             float* __restrict__ pin, int last, int N) {
  int w = (blockIdx.x * blockDim.x + threadIdx.x) >> 6;
  if (w >= N) return;
  int lane = threadIdx.x & 63;
  int c = lane * 2;
  int beg = offs[w], end = offs[w + 1];

  const float2 xrv = *(const float2*)&xr[(size_t)w * 128 + c];
  float we00 = We[c * 3 + 0], we01 = We[c * 3 + 1], we02 = We[c * 3 + 2];
  float we10 = We[c * 3 + 3], we11 = We[c * 3 + 4], we12 = We[c * 3 + 5];
  float a0 = att[c], a1 = att[c + 1];  // att[h][c] flat == channel index

  float m = -1e30f, l = 0.f, accx = 0.f, accy = 0.f;
  for (int p = beg; p < end; ++p) {
    int src = csr_src[p];
    float ea0 = csr_ea[p * 3 + 0], ea1 = csr_ea[p * 3 + 1], ea2 = csr_ea[p * 3 + 2];
    float2 xlv = *(const float2*)&xl[(size_t)src * 128 + c];
    float m0 = xlv.x + xrv.x + we00 * ea0 + we01 * ea1 + we02 * ea2;
    float m1 = xlv.y + xrv.y + we10 * ea0 + we11 * ea1 + we12 * ea2;
    m0 = (m0 > 0.f) ? m0 : 0.2f * m0;
    m1 = (m1 > 0.f) ? m1 : 0.2f * m1;
    float s = m0 * a0 + m1 * a1;
    s += __shfl_xor(s, 1);
    s += __shfl_xor(s, 2);
    s += __shfl_xor(s, 4);
    s += __shfl_xor(s, 8);  // all 16 lanes of head group now hold the head score
    float mnew = fmaxf(m, s);
    float sc = __expf(m - mnew);
    float wgt = __expf(s - mnew);
    l = l * sc + wgt;
    accx = accx * sc + wgt * xlv.x;
    accy = accy * sc + wgt * xlv.y;
    m = mnew;
  }
  float inv = 1.0f / (l + 1e-16f);
  float ax = accx * inv + bo[c];
  float ay = accy * inv + bo[c + 1];

  if (last) {
    emb[(size_t)w * 128 + c] = ax;
    emb[(size_t)w * 128 + c + 1] = ay;
    pin[(size_t)w * 128 + c] = fmaxf(ax, 0.f);
    pin[(size_t)w * 128 + c + 1] = fmaxf(ay, 0.f);
  } else {
    float rx = fmaxf(ax, 0.f), ry = fmaxf(ay, 0.f);
    float s = rx + ry;
    s += __shfl_xor(s, 1);
    s += __shfl_xor(s, 2);
    s += __shfl_xor(s, 4);
    s += __shfl_xor(s, 8);
    s += __shfl_xor(s, 16);
    s += __shfl_xor(s, 32);
    float mu = s * 0.0078125f;  // /128
    float dx = rx - mu, dy = ry - mu;
    float v2 = dx * dx + dy * dy;
    v2 += __shfl_xor(v2, 1);
    v2 += __shfl_xor(v2, 2);
    v2 += __shfl_xor(v2, 4);
    v2 += __shfl_xor(v2, 8);
    v2 += __shfl_xor(v2, 16);
    v2 += __shfl_xor(v2, 32);
    float var = v2 * 0.0078125f;
    float rstd = rsqrtf(var + LN_EPS);
    xnext[(size_t)w * 128 + c] = dx * rstd * lng[c] + lnb[c];
    xnext[(size_t)w * 128 + c + 1] = dy * rstd * lng[c + 1] + lnb[c + 1];
  }
}

// ---------------- graph max-pool (values >= 0, so uint atomicMax on 0-init works) ----------------
__global__ void k_pool(const float* __restrict__ pin, const int* __restrict__ batch,
                       float* __restrict__ pooled, int N) {
  int c = threadIdx.x;  // 128 channels
  int base = blockIdx.x * 64;
  int limit = min(base + 64, N);
  float cur = 0.f;
  int curg = -1;
  for (int n = base; n < limit; ++n) {
    int g = batch[n];
    if (g != curg) {
      if (curg >= 0) atomicMax((unsigned int*)&pooled[curg * 128 + c], __float_as_uint(cur));
      curg = g;
      cur = 0.f;
    }
    cur = fmaxf(cur, pin[(size_t)n * 128 + c]);
  }
  if (curg >= 0) atomicMax((unsigned int*)&pooled[curg * 128 + c], __float_as_uint(cur));
}

// ---------------- MLP: 128 -> 32 -> 32 -> 32 -> 1 ----------------
__global__ void k_mlp(const float* __restrict__ pooled,
                      const float* __restrict__ pw1, const float* __restrict__ pb1,
                      const float* __restrict__ pw2, const float* __restrict__ pb2,
                      const float* __restrict__ pw3, const float* __restrict__ pb3,
                      const float* __restrict__ pw4, const float* __restrict__ pb4,
                      float* __restrict__ out) {
  int g = blockIdx.x;
  int t = threadIdx.x;  // 64 threads
  __shared__ float buf1[32], buf2[32];
  if (t < 32) {
    float acc = pb1[t];
    for (int k = 0; k < 128; ++k) acc += pw1[t * 128 + k] * pooled[g * 128 + k];
    buf1[t] = fmaxf(acc, 0.f);
  }
  __syncthreads();
  if (t < 32) {
    float acc = pb2[t];
    for (int k = 0; k < 32; ++k) acc += pw2[t * 32 + k] * buf1[k];
    buf2[t] = fmaxf(acc, 0.f);
  }
  __syncthreads();
  if (t < 32) {
    float acc = pb3[t];
    for (int k = 0; k < 32; ++k) acc += pw3[t * 32 + k] * buf2[k];
    buf1[t] = fmaxf(acc, 0.f);
  }
  __syncthreads();
  if (t == 0) {
    float acc = pb4[0];
    for (int k = 0; k < 32; ++k) acc += pw4[k] * buf1[k];
    out[g] = acc;
  }
}

// ---------------------------------------------------------------------------

extern "C" void kernel_launch(void* const* d_in, const int* in_sizes, int n_in,
                              void* d_out, int out_size, void* d_ws, size_t ws_size,
                              hipStream_t stream) {
  const float* x_in = (const float*)d_in[0];
  const int* ei = (const int*)d_in[1];
  const int* batch = (const int*)d_in[2];

  const int N = in_sizes[0] / 128;
  const int E = in_sizes[1] / 2;
  const int EP = E + N;
  const int G = out_size - N * 128;
  const float* ea = (const float*)d_in[3];

  // layer params
  const float *Wl[3], *bl[3], *Wr[3], *br[3], *We[3], *att[3], *bo[3];
  for (int l = 0; l < 3; ++l) {
    Wl[l] = (const float*)d_in[4 + 7 * l];
    bl[l] = (const float*)d_in[5 + 7 * l];
    Wr[l] = (const float*)d_in[6 + 7 * l];
    br[l] = (const float*)d_in[7 + 7 * l];
    We[l] = (const float*)d_in[8 + 7 * l];
    att[l] = (const float*)d_in[9 + 7 * l];
    bo[l] = (const float*)d_in[10 + 7 * l];
  }
  const float* lng[2] = {(const float*)d_in[25], (const float*)d_in[27]};
  const float* lnb[2] = {(const float*)d_in[26], (const float*)d_in[28]};
  const float* pw1 = (const float*)d_in[29];
  const float* pb1 = (const float*)d_in[30];
  const float* pw2 = (const float*)d_in[31];
  const float* pb2 = (const float*)d_in[32];
  const float* pw3 = (const float*)d_in[33];
  const float* pb3 = (const float*)d_in[34];
  const float* pw4 = (const float*)d_in[35];
  const float* pb4 = (const float*)d_in[36];

  // workspace carve-up
  char* base = (char*)d_ws;
  size_t cur = 0;
  auto carve = [&](size_t bytes) -> char* {
    char* p = base + cur;
    cur += (bytes + 255) & ~(size_t)255;
    return p;
  };
  float* xl = (float*)carve((size_t)N * 128 * 4);
  float* xr = (float*)carve((size_t)N * 128 * 4);
  float* xbuf = (float*)carve((size_t)N * 128 * 4);
  int* csr_src = (int*)carve((size_t)EP * 4);
  float* csr_ea = (float*)carve((size_t)EP * 3 * 4);
  int* offs = (int*)carve((size_t)(N + 1) * 4);
  int* cursor = (int*)carve((size_t)N * 4);
  int* cnt = (int*)carve((size_t)N * 4);
  int* bsum = (int*)carve(1024);
  float* pooled = (float*)carve((size_t)G * 128 * 4);

  float* emb_out = (float*)d_out;
  float* mlp_out = (float*)d_out + (size_t)N * 128;

  const int NB = (N + 255) / 256;

  hipMemsetAsync(cnt, 0, (size_t)N * 4, stream);
  hipMemsetAsync(pooled, 0, (size_t)G * 128 * 4, stream);

  k_degree<<<(E + 255) / 256, 256, 0, stream>>>(ei, cnt, E);
  k_scan1<<<NB, 256, 0, stream>>>(cnt, bsum, N);
  k_scan2<<<1, 256, 0, stream>>>(bsum, offs, NB, EP, N);
  k_scan3<<<NB, 256, 0, stream>>>(cnt, bsum, offs, cursor, N);
  k_scatter<<<(E + 255) / 256, 256, 0, stream>>>(ei, ea, cursor, csr_src, csr_ea, E);
  k_selfloop<<<NB, 256, 0, stream>>>(offs, csr_src, csr_ea, N);

  for (int l = 0; l < 3; ++l) {
    const float* xsrc = (l == 0) ? x_in : xbuf;
    dim3 ggrid((N + 63) / 64, 2);
    k_gemm<<<ggrid, 256, 0, stream>>>(xsrc, Wl[l], bl[l], Wr[l], br[l], xl, xr, N);
    int last = (l == 2) ? 1 : 0;
    const float* g = last ? bo[l] : lng[l];
    const float* b = last ? bo[l] : lnb[l];
    k_agg<<<(N * 64 + 255) / 256, 256, 0, stream>>>(xl, xr, csr_src, csr_ea, offs,
                                                    We[l], att[l], bo[l], g, b,
                                                    xbuf, emb_out, xbuf, last, N);
  }

  k_pool<<<(N + 63) / 64, 128, 0, stream>>>(xbuf, batch, pooled, N);
  k_mlp<<<G, 64, 0, stream>>>(pooled, pw1, pb1, pw2, pb2, pw3, pb3, pw4, pb4, mlp_out);
}

// Round 3
// 793.329 us; speedup vs baseline: 1.6285x; 1.2709x over previous
//
#include <hip/hip_runtime.h>
#include <math.h>

// ---------------------------------------------------------------------------
// GATv2 x3 + LN + graph max-pool + MLP.
// Round 3: xl/xr GEMMs -> bf16 MFMA (16x16x32), LDS-free, one wave per
// 16-node strip x all 128 outputs. x converted to bf16 once; k_agg emits
// bf16 activations for the next layer's GEMM. fp32 everywhere else.
// ---------------------------------------------------------------------------

#define LN_EPS 1e-5f

typedef short bf16x8 __attribute__((ext_vector_type(8)));
typedef float f32x4 __attribute__((ext_vector_type(4)));

static __device__ __forceinline__ unsigned short f2bf(float f) {
  unsigned int u = __float_as_uint(f);
  u += 0x7fffu + ((u >> 16) & 1u);  // RNE
  return (unsigned short)(u >> 16);
}

// ---------------- prepass ----------------

__global__ void k_degree(const int* __restrict__ ei, int* __restrict__ cnt, int E) {
  int e = blockIdx.x * blockDim.x + threadIdx.x;
  if (e >= E) return;
  atomicAdd(&cnt[ei[E + e]], 1);
}

__global__ void k_scan1(const int* __restrict__ cnt, int* __restrict__ bsum, int N) {
  __shared__ int sh[256];
  int t = threadIdx.x;
  int n = blockIdx.x * 256 + t;
  sh[t] = (n < N) ? (cnt[n] + 1) : 0;
  __syncthreads();
  for (int s = 128; s > 0; s >>= 1) {
    if (t < s) sh[t] += sh[t + s];
    __syncthreads();
  }
  if (t == 0) bsum[blockIdx.x] = sh[0];
}

__global__ void k_scan2(int* __restrict__ bsum, int* __restrict__ offs, int nb, int total, int N) {
  __shared__ int sh[256];
  int t = threadIdx.x;
  int v = (t < nb) ? bsum[t] : 0;
  sh[t] = v;
  __syncthreads();
  for (int d = 1; d < 256; d <<= 1) {
    int add = (t >= d) ? sh[t - d] : 0;
    __syncthreads();
    sh[t] += add;
    __syncthreads();
  }
  if (t < nb) bsum[t] = sh[t] - v;  // exclusive block bases
  if (t == 0) offs[N] = total;
}

__global__ void k_scan3(const int* __restrict__ cnt, const int* __restrict__ bsum,
                        int* __restrict__ offs, int* __restrict__ cursor, int N) {
  __shared__ int sh[256];
  int t = threadIdx.x;
  int n = blockIdx.x * 256 + t;
  int v = (n < N) ? (cnt[n] + 1) : 0;
  sh[t] = v;
  __syncthreads();
  for (int d = 1; d < 256; d <<= 1) {
    int add = (t >= d) ? sh[t - d] : 0;
    __syncthreads();
    sh[t] += add;
    __syncthreads();
  }
  if (n < N) {
    int o = bsum[blockIdx.x] + sh[t] - v;
    offs[n] = o;
    cursor[n] = o;  // real edges fill from offs[n]; self-loop slot is offs[n+1]-1
  }
}

__global__ void k_scatter(const int* __restrict__ ei, const float* __restrict__ ea,
                          int* __restrict__ cursor, int* __restrict__ csr_src,
                          float* __restrict__ csr_ea, int E) {
  int e = blockIdx.x * blockDim.x + threadIdx.x;
  if (e >= E) return;
  int s = ei[e];
  int d = ei[E + e];
  int pos = atomicAdd(&cursor[d], 1);
  csr_src[pos] = s;
  csr_ea[pos * 3 + 0] = ea[e * 3 + 0];
  csr_ea[pos * 3 + 1] = ea[e * 3 + 1];
  csr_ea[pos * 3 + 2] = ea[e * 3 + 2];
}

__global__ void k_selfloop(const int* __restrict__ offs, int* __restrict__ csr_src,
                           float* __restrict__ csr_ea, int N) {
  int n = blockIdx.x * blockDim.x + threadIdx.x;
  if (n >= N) return;
  int beg = offs[n], last = offs[n + 1] - 1;
  float s0 = 0.f, s1 = 0.f, s2 = 0.f;
  for (int p = beg; p < last; ++p) {
    s0 += csr_ea[p * 3 + 0];
    s1 += csr_ea[p * 3 + 1];
    s2 += csr_ea[p * 3 + 2];
  }
  float invc = 1.0f / fmaxf((float)(last - beg), 1.0f);
  csr_src[last] = n;
  csr_ea[last * 3 + 0] = s0 * invc;
  csr_ea[last * 3 + 1] = s1 * invc;
  csr_ea[last * 3 + 2] = s2 * invc;
}

// ---------------- fp32 -> bf16 converters ----------------

__global__ void k_convx(const float* __restrict__ x, unsigned short* __restrict__ xb, int n) {
  int i = (blockIdx.x * blockDim.x + threadIdx.x) * 4;
  if (i >= n) return;
  float4 v = *(const float4*)&x[i];
  ushort4 o;
  o.x = f2bf(v.x); o.y = f2bf(v.y); o.z = f2bf(v.z); o.w = f2bf(v.w);
  *(ushort4*)&xb[i] = o;
}

// 6 weight matrices (Wl0,Wr0,Wl1,Wr1,Wl2,Wr2), each 128x128, into one bf16 buf
__global__ void k_convW(const float* __restrict__ w0, const float* __restrict__ w1,
                        const float* __restrict__ w2, const float* __restrict__ w3,
                        const float* __restrict__ w4, const float* __restrict__ w5,
                        unsigned short* __restrict__ dst) {
  const float* srcs[6] = {w0, w1, w2, w3, w4, w5};
  const float* s = srcs[blockIdx.y];
  int i = blockIdx.x * 256 + threadIdx.x;  // 0..16383
  dst[(size_t)blockIdx.y * 16384 + i] = f2bf(s[i]);
}

// ---------------- MFMA GEMM: out[n][j] = bias[j] + sum_k x[n][k] * W[j][k] ----------------
// One wave per 16-node strip; full 128 output channels (8 jt tiles), K=128 (4 kt).
// A[m=lane&15][k=(lane>>4)*8+j]; B col n=lane&15 is W row j (contiguous k);
// D col=lane&15, row=(lane>>4)*4+r.  No LDS.
__global__ __launch_bounds__(256) void k_gemm_mfma(const unsigned short* __restrict__ xb,
                                                   const unsigned short* __restrict__ Wb,  // [2][128][128]
                                                   const float* __restrict__ bl, const float* __restrict__ br,
                                                   float* __restrict__ xl, float* __restrict__ xr, int N) {
  int wave = threadIdx.x >> 6;
  int lane = threadIdx.x & 63;
  int which = blockIdx.y;
  const unsigned short* W = Wb + (size_t)which * 16384;
  const float* bias = which ? br : bl;
  float* out = which ? xr : xl;

  int row0 = (blockIdx.x * 4 + wave) * 16;
  if (row0 >= N) return;
  int m = lane & 15;
  int q = lane >> 4;

  int arow = row0 + m;
  if (arow >= N) arow = N - 1;  // safe clamp (N%16==0 makes this moot)
  const unsigned short* xrow = xb + (size_t)arow * 128 + q * 8;

  bf16x8 afrag[4];
#pragma unroll
  for (int kt = 0; kt < 4; ++kt) afrag[kt] = *(const bf16x8*)(xrow + kt * 32);

  f32x4 acc[8];
#pragma unroll
  for (int jt = 0; jt < 8; ++jt) acc[jt] = (f32x4){0.f, 0.f, 0.f, 0.f};

  const unsigned short* wbase = W + (size_t)m * 128 + q * 8;
#pragma unroll
  for (int kt = 0; kt < 4; ++kt) {
    bf16x8 a = afrag[kt];
#pragma unroll
    for (int jt = 0; jt < 8; ++jt) {
      bf16x8 b = *(const bf16x8*)(wbase + (size_t)jt * 16 * 128 + kt * 32);
      acc[jt] = __builtin_amdgcn_mfma_f32_16x16x32_bf16(a, b, acc[jt], 0, 0, 0);
    }
  }

#pragma unroll
  for (int jt = 0; jt < 8; ++jt) {
    float bs = bias[jt * 16 + m];
#pragma unroll
    for (int r = 0; r < 4; ++r) {
      int rr = row0 + q * 4 + r;
      if (rr < N) out[(size_t)rr * 128 + jt * 16 + m] = acc[jt][r] + bs;
    }
  }
}

// ---------------- fused: score + online softmax + weighted agg + (bias, relu, LN) ----------------
// one wave (64 lanes) per node; lane handles channels 2*lane, 2*lane+1; head = lane>>4.
__global__ __launch_bounds__(256) void k_agg(const float* __restrict__ xl, const float* __restrict__ xr,
                                             const int* __restrict__ csr_src, const float* __restrict__ csr_ea,
                                             const int* __restrict__ offs,
                                             const float* __restrict__ We, const float* __restrict__ att,
                                             const float* __restrict__ bo,
                                             const float* __restrict__ lng, const float* __restrict__ lnb,
                                             unsigned short* __restrict__ xnext_bf,
                                             float* __restrict__ emb, int last, int N) {
  int w = (blockIdx.x * blockDim.x + threadIdx.x) >> 6;
  if (w >= N) return;
  int lane = threadIdx.x & 63;
  int c = lane * 2;
  int beg = offs[w], end = offs[w + 1];

  const float2 xrv = *(const float2*)&xr[(size_t)w * 128 + c];
  float we00 = We[c * 3 + 0], we01 = We[c * 3 + 1], we02 = We[c * 3 + 2];
  float we10 = We[c * 3 + 3], we11 = We[c * 3 + 4], we12 = We[c * 3 + 5];
  float a0 = att[c], a1 = att[c + 1];

  float m = -1e30f, l = 0.f, accx = 0.f, accy = 0.f;
  for (int p = beg; p < end; ++p) {
    int src = csr_src[p];
    float ea0 = csr_ea[p * 3 + 0], ea1 = csr_ea[p * 3 + 1], ea2 = csr_ea[p * 3 + 2];
    float2 xlv = *(const float2*)&xl[(size_t)src * 128 + c];
    float m0 = xlv.x + xrv.x + we00 * ea0 + we01 * ea1 + we02 * ea2;
    float m1 = xlv.y + xrv.y + we10 * ea0 + we11 * ea1 + we12 * ea2;
    m0 = (m0 > 0.f) ? m0 : 0.2f * m0;
    m1 = (m1 > 0.f) ? m1 : 0.2f * m1;
    float s = m0 * a0 + m1 * a1;
    s += __shfl_xor(s, 1);
    s += __shfl_xor(s, 2);
    s += __shfl_xor(s, 4);
    s += __shfl_xor(s, 8);
    float mnew = fmaxf(m, s);
    float sc = __expf(m - mnew);
    float wgt = __expf(s - mnew);
    l = l * sc + wgt;
    accx = accx * sc + wgt * xlv.x;
    accy = accy * sc + wgt * xlv.y;
    m = mnew;
  }
  float inv = 1.0f / (l + 1e-16f);
  float ax = accx * inv + bo[c];
  float ay = accy * inv + bo[c + 1];

  if (last) {
    emb[(size_t)w * 128 + c] = ax;
    emb[(size_t)w * 128 + c + 1] = ay;
  } else {
    float rx = fmaxf(ax, 0.f), ry = fmaxf(ay, 0.f);
    float s = rx + ry;
    s += __shfl_xor(s, 1);
    s += __shfl_xor(s, 2);
    s += __shfl_xor(s, 4);
    s += __shfl_xor(s, 8);
    s += __shfl_xor(s, 16);
    s += __shfl_xor(s, 32);
    float mu = s * 0.0078125f;  // /128
    float dx = rx - mu, dy = ry - mu;
    float v2 = dx * dx + dy * dy;
    v2 += __shfl_xor(v2, 1);
    v2 += __shfl_xor(v2, 2);
    v2 += __shfl_xor(v2, 4);
    v2 += __shfl_xor(v2, 8);
    v2 += __shfl_xor(v2, 16);
    v2 += __shfl_xor(v2, 32);
    float var = v2 * 0.0078125f;
    float rstd = rsqrtf(var + LN_EPS);
    float o0 = dx * rstd * lng[c] + lnb[c];
    float o1 = dy * rstd * lng[c + 1] + lnb[c + 1];
    unsigned int pack = (unsigned int)f2bf(o0) | ((unsigned int)f2bf(o1) << 16);
    *(unsigned int*)&xnext_bf[(size_t)w * 128 + c] = pack;
  }
}

// ---------------- graph max-pool (relu implicit: atomicMax vs 0-init) ----------------
__global__ void k_pool(const float* __restrict__ emb, const int* __restrict__ batch,
                       float* __restrict__ pooled, int N) {
  int c = threadIdx.x;  // 128 channels
  int base = blockIdx.x * 64;
  int limit = min(base + 64, N);
  float cur = 0.f;
  int curg = -1;
  for (int n = base; n < limit; ++n) {
    int g = batch[n];
    if (g != curg) {
      if (curg >= 0) atomicMax((unsigned int*)&pooled[curg * 128 + c], __float_as_uint(cur));
      curg = g;
      cur = 0.f;
    }
    cur = fmaxf(cur, emb[(size_t)n * 128 + c]);  // max(0, max emb) == max relu(emb)
  }
  if (curg >= 0) atomicMax((unsigned int*)&pooled[curg * 128 + c], __float_as_uint(cur));
}

// ---------------- MLP: 128 -> 32 -> 32 -> 32 -> 1 ----------------
__global__ void k_mlp(const float* __restrict__ pooled,
                      const float* __restrict__ pw1, const float* __restrict__ pb1,
                      const float* __restrict__ pw2, const float* __restrict__ pb2,
                      const float* __restrict__ pw3, const float* __restrict__ pb3,
                      const float* __restrict__ pw4, const float* __restrict__ pb4,
                      float* __restrict__ out) {
  int g = blockIdx.x;
  int t = threadIdx.x;  // 64 threads
  __shared__ float buf1[32], buf2[32];
  if (t < 32) {
    float acc = pb1[t];
    for (int k = 0; k < 128; ++k) acc += pw1[t * 128 + k] * pooled[g * 128 + k];
    buf1[t] = fmaxf(acc, 0.f);
  }
  __syncthreads();
  if (t < 32) {
    float acc = pb2[t];
    for (int k = 0; k < 32; ++k) acc += pw2[t * 32 + k] * buf1[k];
    buf2[t] = fmaxf(acc, 0.f);
  }
  __syncthreads();
  if (t < 32) {
    float acc = pb3[t];
    for (int k = 0; k < 32; ++k) acc += pw3[t * 32 + k] * buf2[k];
    buf1[t] = fmaxf(acc, 0.f);
  }
  __syncthreads();
  if (t == 0) {
    float acc = pb4[0];
    for (int k = 0; k < 32; ++k) acc += pw4[k] * buf1[k];
    out[g] = acc;
  }
}

// ---------------------------------------------------------------------------

extern "C" void kernel_launch(void* const* d_in, const int* in_sizes, int n_in,
                              void* d_out, int out_size, void* d_ws, size_t ws_size,
                              hipStream_t stream) {
  const float* x_in = (const float*)d_in[0];
  const int* ei = (const int*)d_in[1];
  const int* batch = (const int*)d_in[2];
  const float* ea = (const float*)d_in[3];

  const int N = in_sizes[0] / 128;
  const int E = in_sizes[1] / 2;
  const int EP = E + N;
  const int G = out_size - N * 128;

  const float *Wl[3], *bl[3], *Wr[3], *br[3], *We[3], *att[3], *bo[3];
  for (int l = 0; l < 3; ++l) {
    Wl[l] = (const float*)d_in[4 + 7 * l];
    bl[l] = (const float*)d_in[5 + 7 * l];
    Wr[l] = (const float*)d_in[6 + 7 * l];
    br[l] = (const float*)d_in[7 + 7 * l];
    We[l] = (const float*)d_in[8 + 7 * l];
    att[l] = (const float*)d_in[9 + 7 * l];
    bo[l] = (const float*)d_in[10 + 7 * l];
  }
  const float* lng[2] = {(const float*)d_in[25], (const float*)d_in[27]};
  const float* lnb[2] = {(const float*)d_in[26], (const float*)d_in[28]};
  const float* pw1 = (const float*)d_in[29];
  const float* pb1 = (const float*)d_in[30];
  const float* pw2 = (const float*)d_in[31];
  const float* pb2 = (const float*)d_in[32];
  const float* pw3 = (const float*)d_in[33];
  const float* pb3 = (const float*)d_in[34];
  const float* pw4 = (const float*)d_in[35];
  const float* pb4 = (const float*)d_in[36];

  char* base = (char*)d_ws;
  size_t cur = 0;
  auto carve = [&](size_t bytes) -> char* {
    char* p = base + cur;
    cur += (bytes + 255) & ~(size_t)255;
    return p;
  };
  float* xl = (float*)carve((size_t)N * 128 * 4);
  float* xr = (float*)carve((size_t)N * 128 * 4);
  unsigned short* xb = (unsigned short*)carve((size_t)N * 128 * 2);  // bf16 activations
  unsigned short* Wb = (unsigned short*)carve((size_t)6 * 16384 * 2);
  int* csr_src = (int*)carve((size_t)EP * 4);
  float* csr_ea = (float*)carve((size_t)EP * 3 * 4);
  int* offs = (int*)carve((size_t)(N + 1) * 4);
  int* cursor = (int*)carve((size_t)N * 4);
  int* cnt = (int*)carve((size_t)N * 4);
  int* bsum = (int*)carve(1024);
  float* pooled = (float*)carve((size_t)G * 128 * 4);

  float* emb_out = (float*)d_out;
  float* mlp_out = (float*)d_out + (size_t)N * 128;

  const int NB = (N + 255) / 256;

  hipMemsetAsync(cnt, 0, (size_t)N * 4, stream);
  hipMemsetAsync(pooled, 0, (size_t)G * 128 * 4, stream);

  k_degree<<<(E + 255) / 256, 256, 0, stream>>>(ei, cnt, E);
  k_scan1<<<NB, 256, 0, stream>>>(cnt, bsum, N);
  k_scan2<<<1, 256, 0, stream>>>(bsum, offs, NB, EP, N);
  k_scan3<<<NB, 256, 0, stream>>>(cnt, bsum, offs, cursor, N);
  k_scatter<<<(E + 255) / 256, 256, 0, stream>>>(ei, ea, cursor, csr_src, csr_ea, E);
  k_selfloop<<<NB, 256, 0, stream>>>(offs, csr_src, csr_ea, N);

  k_convx<<<(N * 128 / 4 + 255) / 256, 256, 0, stream>>>(x_in, xb, N * 128);
  {
    dim3 g(64, 6);
    k_convW<<<g, 256, 0, stream>>>(Wl[0], Wr[0], Wl[1], Wr[1], Wl[2], Wr[2], Wb);
  }

  for (int l = 0; l < 3; ++l) {
    dim3 ggrid((N + 63) / 64, 2);
    k_gemm_mfma<<<ggrid, 256, 0, stream>>>(xb, Wb + (size_t)l * 32768, bl[l], br[l], xl, xr, N);
    int last = (l == 2) ? 1 : 0;
    const float* g = last ? bo[l] : lng[l];
    const float* b = last ? bo[l] : lnb[l];
    k_agg<<<(N * 64 + 255) / 256, 256, 0, stream>>>(xl, xr, csr_src, csr_ea, offs,
                                                    We[l], att[l], bo[l], g, b,
                                                    xb, emb_out, last, N);
  }

  k_pool<<<(N + 63) / 64, 128, 0, stream>>>(emb_out, batch, pooled, N);
  k_mlp<<<G, 64, 0, stream>>>(pooled, pw1, pb1, pw2, pb2, pw3, pb3, pw4, pb4, mlp_out);
}

// Round 4
// 606.948 us; speedup vs baseline: 2.1286x; 1.3071x over previous
//
#include <hip/hip_runtime.h>
#include <math.h>

// ---------------------------------------------------------------------------
// GATv2 x3 + LN + graph max-pool + MLP.
// Round 4: k_agg overhaul -- direct exp (no online-softmax serial chain),
// bf16 gather table (GEMM emits bf16 xl/xr), DPP 16-lane reductions instead
// of ds_swizzle shfl, packed float4 edge record {ea0,ea1,ea2,src_bits},
// 2-way unrolled edge loop.  MFMA GEMM unchanged otherwise.
// ---------------------------------------------------------------------------

#define LN_EPS 1e-5f

typedef short bf16x8 __attribute__((ext_vector_type(8)));
typedef float f32x4 __attribute__((ext_vector_type(4)));

static __device__ __forceinline__ unsigned short f2bf(float f) {
  unsigned int u = __float_as_uint(f);
  u += 0x7fffu + ((u >> 16) & 1u);  // RNE
  return (unsigned short)(u >> 16);
}

// sum over each 16-lane row (head group) via DPP: ror8, ror4, quad xor2, xor1
static __device__ __forceinline__ float dpp_sum16(float v) {
  int x;
  x = __builtin_amdgcn_update_dpp(0, __float_as_int(v), 0x128, 0xf, 0xf, true);  // row_ror:8
  v += __int_as_float(x);
  x = __builtin_amdgcn_update_dpp(0, __float_as_int(v), 0x124, 0xf, 0xf, true);  // row_ror:4
  v += __int_as_float(x);
  x = __builtin_amdgcn_update_dpp(0, __float_as_int(v), 0x04E, 0xf, 0xf, true);  // quad_perm 2,3,0,1
  v += __int_as_float(x);
  x = __builtin_amdgcn_update_dpp(0, __float_as_int(v), 0x0B1, 0xf, 0xf, true);  // quad_perm 1,0,3,2
  v += __int_as_float(x);
  return v;
}

// ---------------- prepass ----------------

__global__ void k_degree(const int* __restrict__ ei, int* __restrict__ cnt, int E) {
  int e = blockIdx.x * blockDim.x + threadIdx.x;
  if (e >= E) return;
  atomicAdd(&cnt[ei[E + e]], 1);
}

__global__ void k_scan1(const int* __restrict__ cnt, int* __restrict__ bsum, int N) {
  __shared__ int sh[256];
  int t = threadIdx.x;
  int n = blockIdx.x * 256 + t;
  sh[t] = (n < N) ? (cnt[n] + 1) : 0;
  __syncthreads();
  for (int s = 128; s > 0; s >>= 1) {
    if (t < s) sh[t] += sh[t + s];
    __syncthreads();
  }
  if (t == 0) bsum[blockIdx.x] = sh[0];
}

__global__ void k_scan2(int* __restrict__ bsum, int* __restrict__ offs, int nb, int total, int N) {
  __shared__ int sh[256];
  int t = threadIdx.x;
  int v = (t < nb) ? bsum[t] : 0;
  sh[t] = v;
  __syncthreads();
  for (int d = 1; d < 256; d <<= 1) {
    int add = (t >= d) ? sh[t - d] : 0;
    __syncthreads();
    sh[t] += add;
    __syncthreads();
  }
  if (t < nb) bsum[t] = sh[t] - v;  // exclusive block bases
  if (t == 0) offs[N] = total;
}

__global__ void k_scan3(const int* __restrict__ cnt, const int* __restrict__ bsum,
                        int* __restrict__ offs, int* __restrict__ cursor, int N) {
  __shared__ int sh[256];
  int t = threadIdx.x;
  int n = blockIdx.x * 256 + t;
  int v = (n < N) ? (cnt[n] + 1) : 0;
  sh[t] = v;
  __syncthreads();
  for (int d = 1; d < 256; d <<= 1) {
    int add = (t >= d) ? sh[t - d] : 0;
    __syncthreads();
    sh[t] += add;
    __syncthreads();
  }
  if (n < N) {
    int o = bsum[blockIdx.x] + sh[t] - v;
    offs[n] = o;
    cursor[n] = o;  // real edges fill from offs[n]; self-loop slot is offs[n+1]-1
  }
}

// packed edge record: {ea0, ea1, ea2, bits(src)}
__global__ void k_scatter(const int* __restrict__ ei, const float* __restrict__ ea,
                          int* __restrict__ cursor, float4* __restrict__ e4, int E) {
  int e = blockIdx.x * blockDim.x + threadIdx.x;
  if (e >= E) return;
  int s = ei[e];
  int d = ei[E + e];
  int pos = atomicAdd(&cursor[d], 1);
  float4 r;
  r.x = ea[e * 3 + 0];
  r.y = ea[e * 3 + 1];
  r.z = ea[e * 3 + 2];
  r.w = __int_as_float(s);
  e4[pos] = r;
}

__global__ void k_selfloop(const int* __restrict__ offs, float4* __restrict__ e4, int N) {
  int n = blockIdx.x * blockDim.x + threadIdx.x;
  if (n >= N) return;
  int beg = offs[n], last = offs[n + 1] - 1;
  float s0 = 0.f, s1 = 0.f, s2 = 0.f;
  for (int p = beg; p < last; ++p) {
    float4 v = e4[p];
    s0 += v.x;
    s1 += v.y;
    s2 += v.z;
  }
  float invc = 1.0f / fmaxf((float)(last - beg), 1.0f);
  float4 r;
  r.x = s0 * invc;
  r.y = s1 * invc;
  r.z = s2 * invc;
  r.w = __int_as_float(n);
  e4[last] = r;
}

// ---------------- fp32 -> bf16 converters ----------------

__global__ void k_convx(const float* __restrict__ x, unsigned short* __restrict__ xb, int n) {
  int i = (blockIdx.x * blockDim.x + threadIdx.x) * 4;
  if (i >= n) return;
  float4 v = *(const float4*)&x[i];
  ushort4 o;
  o.x = f2bf(v.x); o.y = f2bf(v.y); o.z = f2bf(v.z); o.w = f2bf(v.w);
  *(ushort4*)&xb[i] = o;
}

__global__ void k_convW(const float* __restrict__ w0, const float* __restrict__ w1,
                        const float* __restrict__ w2, const float* __restrict__ w3,
                        const float* __restrict__ w4, const float* __restrict__ w5,
                        unsigned short* __restrict__ dst) {
  const float* srcs[6] = {w0, w1, w2, w3, w4, w5};
  const float* s = srcs[blockIdx.y];
  int i = blockIdx.x * 256 + threadIdx.x;  // 0..16383
  dst[(size_t)blockIdx.y * 16384 + i] = f2bf(s[i]);
}

// ---------------- MFMA GEMM: out_bf16[n][j] = bf16(bias[j] + sum_k x[n][k]*W[j][k]) ----------------
__global__ __launch_bounds__(256) void k_gemm_mfma(const unsigned short* __restrict__ xb,
                                                   const unsigned short* __restrict__ Wb,
                                                   const float* __restrict__ bl, const float* __restrict__ br,
                                                   unsigned short* __restrict__ xlb,
                                                   unsigned short* __restrict__ xrb, int N) {
  int wave = threadIdx.x >> 6;
  int lane = threadIdx.x & 63;
  int which = blockIdx.y;
  const unsigned short* W = Wb + (size_t)which * 16384;
  const float* bias = which ? br : bl;
  unsigned short* out = which ? xrb : xlb;

  int row0 = (blockIdx.x * 4 + wave) * 16;
  if (row0 >= N) return;
  int m = lane & 15;
  int q = lane >> 4;

  int arow = row0 + m;
  if (arow >= N) arow = N - 1;
  const unsigned short* xrow = xb + (size_t)arow * 128 + q * 8;

  bf16x8 afrag[4];
#pragma unroll
  for (int kt = 0; kt < 4; ++kt) afrag[kt] = *(const bf16x8*)(xrow + kt * 32);

  f32x4 acc[8];
#pragma unroll
  for (int jt = 0; jt < 8; ++jt) acc[jt] = (f32x4){0.f, 0.f, 0.f, 0.f};

  const unsigned short* wbase = W + (size_t)m * 128 + q * 8;
#pragma unroll
  for (int kt = 0; kt < 4; ++kt) {
    bf16x8 a = afrag[kt];
#pragma unroll
    for (int jt = 0; jt < 8; ++jt) {
      bf16x8 b = *(const bf16x8*)(wbase + (size_t)jt * 16 * 128 + kt * 32);
      acc[jt] = __builtin_amdgcn_mfma_f32_16x16x32_bf16(a, b, acc[jt], 0, 0, 0);
    }
  }

#pragma unroll
  for (int jt = 0; jt < 8; ++jt) {
    float bs = bias[jt * 16 + m];
#pragma unroll
    for (int r = 0; r < 4; ++r) {
      int rr = row0 + q * 4 + r;
      if (rr < N) out[(size_t)rr * 128 + jt * 16 + m] = f2bf(acc[jt][r] + bs);
    }
  }
}

// ---------------- fused: score + softmax(direct exp) + weighted agg + epilogue ----------------
// one wave per node; lane owns channels 2*lane, 2*lane+1; head group = 16 lanes.
__global__ __launch_bounds__(256) void k_agg(const unsigned short* __restrict__ xlb,
                                             const unsigned short* __restrict__ xrb,
                                             const float4* __restrict__ e4,
                                             const int* __restrict__ offs,
                                             const float* __restrict__ We, const float* __restrict__ att,
                                             const float* __restrict__ bo,
                                             const float* __restrict__ lng, const float* __restrict__ lnb,
                                             unsigned short* __restrict__ xnext_bf,
                                             float* __restrict__ emb, int last, int N) {
  int w = (blockIdx.x * blockDim.x + threadIdx.x) >> 6;
  if (w >= N) return;
  int lane = threadIdx.x & 63;
  int c = lane * 2;
  int beg = offs[w], end = offs[w + 1];

  unsigned int vr = *(const unsigned int*)&xrb[(size_t)w * 128 + c];
  float xr0 = __uint_as_float(vr << 16);
  float xr1 = __uint_as_float(vr & 0xffff0000u);
  float we00 = We[c * 3 + 0], we01 = We[c * 3 + 1], we02 = We[c * 3 + 2];
  float we10 = We[c * 3 + 3], we11 = We[c * 3 + 4], we12 = We[c * 3 + 5];
  float a0 = att[c], a1 = att[c + 1];

  float lA = 0.f, axA = 0.f, ayA = 0.f;
  float lB = 0.f, axB = 0.f, ayB = 0.f;

  int p = beg;
  for (; p + 2 <= end; p += 2) {
    float4 eA = e4[p];
    float4 eB = e4[p + 1];
    int sA = __float_as_int(eA.w);
    int sB = __float_as_int(eB.w);
    unsigned int vA = *(const unsigned int*)&xlb[(size_t)sA * 128 + c];
    unsigned int vB = *(const unsigned int*)&xlb[(size_t)sB * 128 + c];
    float xA0 = __uint_as_float(vA << 16), xA1 = __uint_as_float(vA & 0xffff0000u);
    float xB0 = __uint_as_float(vB << 16), xB1 = __uint_as_float(vB & 0xffff0000u);

    float tA0 = xr0 + we00 * eA.x + we01 * eA.y + we02 * eA.z;
    float tA1 = xr1 + we10 * eA.x + we11 * eA.y + we12 * eA.z;
    float tB0 = xr0 + we00 * eB.x + we01 * eB.y + we02 * eB.z;
    float tB1 = xr1 + we10 * eB.x + we11 * eB.y + we12 * eB.z;

    float mA0 = xA0 + tA0, mA1 = xA1 + tA1;
    float mB0 = xB0 + tB0, mB1 = xB1 + tB1;
    mA0 = fmaxf(mA0, 0.2f * mA0);
    mA1 = fmaxf(mA1, 0.2f * mA1);
    mB0 = fmaxf(mB0, 0.2f * mB0);
    mB1 = fmaxf(mB1, 0.2f * mB1);

    float sc_A = dpp_sum16(mA0 * a0 + mA1 * a1);
    float sc_B = dpp_sum16(mB0 * a0 + mB1 * a1);
    float wA = __expf(sc_A);
    float wB = __expf(sc_B);
    lA += wA;
    axA = fmaf(wA, xA0, axA);
    ayA = fmaf(wA, xA1, ayA);
    lB += wB;
    axB = fmaf(wB, xB0, axB);
    ayB = fmaf(wB, xB1, ayB);
  }
  if (p < end) {
    float4 eA = e4[p];
    int sA = __float_as_int(eA.w);
    unsigned int vA = *(const unsigned int*)&xlb[(size_t)sA * 128 + c];
    float xA0 = __uint_as_float(vA << 16), xA1 = __uint_as_float(vA & 0xffff0000u);
    float tA0 = xr0 + we00 * eA.x + we01 * eA.y + we02 * eA.z;
    float tA1 = xr1 + we10 * eA.x + we11 * eA.y + we12 * eA.z;
    float mA0 = xA0 + tA0, mA1 = xA1 + tA1;
    mA0 = fmaxf(mA0, 0.2f * mA0);
    mA1 = fmaxf(mA1, 0.2f * mA1);
    float sc_A = dpp_sum16(mA0 * a0 + mA1 * a1);
    float wA = __expf(sc_A);
    lA += wA;
    axA = fmaf(wA, xA0, axA);
    ayA = fmaf(wA, xA1, ayA);
  }
  float l = lA + lB;
  float accx = axA + axB, accy = ayA + ayB;

  float inv = 1.0f / l;
  float ax = accx * inv + bo[c];
  float ay = accy * inv + bo[c + 1];

  if (last) {
    emb[(size_t)w * 128 + c] = ax;
    emb[(size_t)w * 128 + c + 1] = ay;
  } else {
    float rx = fmaxf(ax, 0.f), ry = fmaxf(ay, 0.f);
    float s = rx + ry;
    s += __shfl_xor(s, 1);
    s += __shfl_xor(s, 2);
    s += __shfl_xor(s, 4);
    s += __shfl_xor(s, 8);
    s += __shfl_xor(s, 16);
    s += __shfl_xor(s, 32);
    float mu = s * 0.0078125f;  // /128
    float dx = rx - mu, dy = ry - mu;
    float v2 = dx * dx + dy * dy;
    v2 += __shfl_xor(v2, 1);
    v2 += __shfl_xor(v2, 2);
    v2 += __shfl_xor(v2, 4);
    v2 += __shfl_xor(v2, 8);
    v2 += __shfl_xor(v2, 16);
    v2 += __shfl_xor(v2, 32);
    float var = v2 * 0.0078125f;
    float rstd = rsqrtf(var + LN_EPS);
    float o0 = dx * rstd * lng[c] + lnb[c];
    float o1 = dy * rstd * lng[c + 1] + lnb[c + 1];
    unsigned int pack = (unsigned int)f2bf(o0) | ((unsigned int)f2bf(o1) << 16);
    *(unsigned int*)&xnext_bf[(size_t)w * 128 + c] = pack;
  }
}

// ---------------- graph max-pool (relu implicit: atomicMax vs 0-init) ----------------
__global__ void k_pool(const float* __restrict__ emb, const int* __restrict__ batch,
                       float* __restrict__ pooled, int N) {
  int c = threadIdx.x;  // 128 channels
  int base = blockIdx.x * 64;
  int limit = min(base + 64, N);
  float cur = 0.f;
  int curg = -1;
  for (int n = base; n < limit; ++n) {
    int g = batch[n];
    if (g != curg) {
      if (curg >= 0) atomicMax((unsigned int*)&pooled[curg * 128 + c], __float_as_uint(cur));
      curg = g;
      cur = 0.f;
    }
    cur = fmaxf(cur, emb[(size_t)n * 128 + c]);
  }
  if (curg >= 0) atomicMax((unsigned int*)&pooled[curg * 128 + c], __float_as_uint(cur));
}

// ---------------- MLP: 128 -> 32 -> 32 -> 32 -> 1 ----------------
__global__ void k_mlp(const float* __restrict__ pooled,
                      const float* __restrict__ pw1, const float* __restrict__ pb1,
                      const float* __restrict__ pw2, const float* __restrict__ pb2,
                      const float* __restrict__ pw3, const float* __restrict__ pb3,
                      const float* __restrict__ pw4, const float* __restrict__ pb4,
                      float* __restrict__ out) {
  int g = blockIdx.x;
  int t = threadIdx.x;  // 64 threads
  __shared__ float buf1[32], buf2[32];
  if (t < 32) {
    float acc = pb1[t];
    for (int k = 0; k < 128; ++k) acc += pw1[t * 128 + k] * pooled[g * 128 + k];
    buf1[t] = fmaxf(acc, 0.f);
  }
  __syncthreads();
  if (t < 32) {
    float acc = pb2[t];
    for (int k = 0; k < 32; ++k) acc += pw2[t * 32 + k] * buf1[k];
    buf2[t] = fmaxf(acc, 0.f);
  }
  __syncthreads();
  if (t < 32) {
    float acc = pb3[t];
    for (int k = 0; k < 32; ++k) acc += pw3[t * 32 + k] * buf2[k];
    buf1[t] = fmaxf(acc, 0.f);
  }
  __syncthreads();
  if (t == 0) {
    float acc = pb4[0];
    for (int k = 0; k < 32; ++k) acc += pw4[k] * buf1[k];
    out[g] = acc;
  }
}

// ---------------------------------------------------------------------------

extern "C" void kernel_launch(void* const* d_in, const int* in_sizes, int n_in,
                              void* d_out, int out_size, void* d_ws, size_t ws_size,
                              hipStream_t stream) {
  const float* x_in = (const float*)d_in[0];
  const int* ei = (const int*)d_in[1];
  const int* batch = (const int*)d_in[2];
  const float* ea = (const float*)d_in[3];

  const int N = in_sizes[0] / 128;
  const int E = in_sizes[1] / 2;
  const int EP = E + N;
  const int G = out_size - N * 128;

  const float *Wl[3], *bl[3], *Wr[3], *br[3], *We[3], *att[3], *bo[3];
  for (int l = 0; l < 3; ++l) {
    Wl[l] = (const float*)d_in[4 + 7 * l];
    bl[l] = (const float*)d_in[5 + 7 * l];
    Wr[l] = (const float*)d_in[6 + 7 * l];
    br[l] = (const float*)d_in[7 + 7 * l];
    We[l] = (const float*)d_in[8 + 7 * l];
    att[l] = (const float*)d_in[9 + 7 * l];
    bo[l] = (const float*)d_in[10 + 7 * l];
  }
  const float* lng[2] = {(const float*)d_in[25], (const float*)d_in[27]};
  const float* lnb[2] = {(const float*)d_in[26], (const float*)d_in[28]};
  const float* pw1 = (const float*)d_in[29];
  const float* pb1 = (const float*)d_in[30];
  const float* pw2 = (const float*)d_in[31];
  const float* pb2 = (const float*)d_in[32];
  const float* pw3 = (const float*)d_in[33];
  const float* pb3 = (const float*)d_in[34];
  const float* pw4 = (const float*)d_in[35];
  const float* pb4 = (const float*)d_in[36];

  char* base = (char*)d_ws;
  size_t cur = 0;
  auto carve = [&](size_t bytes) -> char* {
    char* p = base + cur;
    cur += (bytes + 255) & ~(size_t)255;
    return p;
  };
  unsigned short* xlb = (unsigned short*)carve((size_t)N * 128 * 2);
  unsigned short* xrb = (unsigned short*)carve((size_t)N * 128 * 2);
  unsigned short* xb = (unsigned short*)carve((size_t)N * 128 * 2);  // bf16 activations
  unsigned short* Wb = (unsigned short*)carve((size_t)6 * 16384 * 2);
  float4* e4 = (float4*)carve((size_t)EP * 16);
  int* offs = (int*)carve((size_t)(N + 1) * 4);
  int* cursor = (int*)carve((size_t)N * 4);
  int* cnt = (int*)carve((size_t)N * 4);
  int* bsum = (int*)carve(1024);
  float* pooled = (float*)carve((size_t)G * 128 * 4);

  float* emb_out = (float*)d_out;
  float* mlp_out = (float*)d_out + (size_t)N * 128;

  const int NB = (N + 255) / 256;

  hipMemsetAsync(cnt, 0, (size_t)N * 4, stream);
  hipMemsetAsync(pooled, 0, (size_t)G * 128 * 4, stream);

  k_degree<<<(E + 255) / 256, 256, 0, stream>>>(ei, cnt, E);
  k_scan1<<<NB, 256, 0, stream>>>(cnt, bsum, N);
  k_scan2<<<1, 256, 0, stream>>>(bsum, offs, NB, EP, N);
  k_scan3<<<NB, 256, 0, stream>>>(cnt, bsum, offs, cursor, N);
  k_scatter<<<(E + 255) / 256, 256, 0, stream>>>(ei, ea, cursor, e4, E);
  k_selfloop<<<NB, 256, 0, stream>>>(offs, e4, N);

  k_convx<<<(N * 128 / 4 + 255) / 256, 256, 0, stream>>>(x_in, xb, N * 128);
  {
    dim3 g(64, 6);
    k_convW<<<g, 256, 0, stream>>>(Wl[0], Wr[0], Wl[1], Wr[1], Wl[2], Wr[2], Wb);
  }

  for (int l = 0; l < 3; ++l) {
    dim3 ggrid((N + 63) / 64, 2);
    k_gemm_mfma<<<ggrid, 256, 0, stream>>>(xb, Wb + (size_t)l * 32768, bl[l], br[l], xlb, xrb, N);
    int last = (l == 2) ? 1 : 0;
    const float* g = last ? bo[l] : lng[l];
    const float* b = last ? bo[l] : lnb[l];
    k_agg<<<(N * 64 + 255) / 256, 256, 0, stream>>>(xlb, xrb, e4, offs,
                                                    We[l], att[l], bo[l], g, b,
                                                    xb, emb_out, last, N);
  }

  k_pool<<<(N + 63) / 64, 128, 0, stream>>>(emb_out, batch, pooled, N);
  k_mlp<<<G, 64, 0, stream>>>(pooled, pw1, pb1, pw2, pb2, pw3, pb3, pw4, pb4, mlp_out);
}

// Round 5
// 594.103 us; speedup vs baseline: 2.1746x; 1.0216x over previous
//
#include <hip/hip_runtime.h>
#include <math.h>

// ---------------------------------------------------------------------------
// GATv2 x3 + LN + graph max-pool + MLP.
// Round 5: k_agg 32-bit byte-offset gathers (e4.w holds src*256), exp2-folded
// attention weights, pointer-walk e4; k_degree int4-vectorized; k_pool 2-way.
// ---------------------------------------------------------------------------

#define LN_EPS 1e-5f
#define LOG2E 1.44269504088896340736f

typedef short bf16x8 __attribute__((ext_vector_type(8)));
typedef float f32x4 __attribute__((ext_vector_type(4)));

static __device__ __forceinline__ unsigned short f2bf(float f) {
  unsigned int u = __float_as_uint(f);
  u += 0x7fffu + ((u >> 16) & 1u);  // RNE
  return (unsigned short)(u >> 16);
}

// sum over each 16-lane row (head group) via DPP: ror8, ror4, quad xor2, xor1
static __device__ __forceinline__ float dpp_sum16(float v) {
  int x;
  x = __builtin_amdgcn_update_dpp(0, __float_as_int(v), 0x128, 0xf, 0xf, true);  // row_ror:8
  v += __int_as_float(x);
  x = __builtin_amdgcn_update_dpp(0, __float_as_int(v), 0x124, 0xf, 0xf, true);  // row_ror:4
  v += __int_as_float(x);
  x = __builtin_amdgcn_update_dpp(0, __float_as_int(v), 0x04E, 0xf, 0xf, true);  // quad_perm 2,3,0,1
  v += __int_as_float(x);
  x = __builtin_amdgcn_update_dpp(0, __float_as_int(v), 0x0B1, 0xf, 0xf, true);  // quad_perm 1,0,3,2
  v += __int_as_float(x);
  return v;
}

// ---------------- prepass ----------------

__global__ void k_degree(const int* __restrict__ ei, int* __restrict__ cnt, int E) {
  int e = (blockIdx.x * blockDim.x + threadIdx.x) * 4;
  if (e + 3 < E) {
    int4 d = *(const int4*)&ei[E + e];
    atomicAdd(&cnt[d.x], 1);
    atomicAdd(&cnt[d.y], 1);
    atomicAdd(&cnt[d.z], 1);
    atomicAdd(&cnt[d.w], 1);
  } else {
    int lim = min(e + 4, E);
    for (; e < lim; ++e) atomicAdd(&cnt[ei[E + e]], 1);
  }
}

__global__ void k_scan1(const int* __restrict__ cnt, int* __restrict__ bsum, int N) {
  __shared__ int sh[256];
  int t = threadIdx.x;
  int n = blockIdx.x * 256 + t;
  sh[t] = (n < N) ? (cnt[n] + 1) : 0;
  __syncthreads();
  for (int s = 128; s > 0; s >>= 1) {
    if (t < s) sh[t] += sh[t + s];
    __syncthreads();
  }
  if (t == 0) bsum[blockIdx.x] = sh[0];
}

__global__ void k_scan2(int* __restrict__ bsum, int* __restrict__ offs, int nb, int total, int N) {
  __shared__ int sh[256];
  int t = threadIdx.x;
  int v = (t < nb) ? bsum[t] : 0;
  sh[t] = v;
  __syncthreads();
  for (int d = 1; d < 256; d <<= 1) {
    int add = (t >= d) ? sh[t - d] : 0;
    __syncthreads();
    sh[t] += add;
    __syncthreads();
  }
  if (t < nb) bsum[t] = sh[t] - v;  // exclusive block bases
  if (t == 0) offs[N] = total;
}

__global__ void k_scan3(const int* __restrict__ cnt, const int* __restrict__ bsum,
                        int* __restrict__ offs, int* __restrict__ cursor, int N) {
  __shared__ int sh[256];
  int t = threadIdx.x;
  int n = blockIdx.x * 256 + t;
  int v = (n < N) ? (cnt[n] + 1) : 0;
  sh[t] = v;
  __syncthreads();
  for (int d = 1; d < 256; d <<= 1) {
    int add = (t >= d) ? sh[t - d] : 0;
    __syncthreads();
    sh[t] += add;
    __syncthreads();
  }
  if (n < N) {
    int o = bsum[blockIdx.x] + sh[t] - v;
    offs[n] = o;
    cursor[n] = o;  // real edges fill from offs[n]; self-loop slot is offs[n+1]-1
  }
}

// packed edge record: {ea0, ea1, ea2, bits(src*256 byte-offset into bf16 row table)}
__global__ void k_scatter(const int* __restrict__ ei, const float* __restrict__ ea,
                          int* __restrict__ cursor, float4* __restrict__ e4, int E) {
  int e = blockIdx.x * blockDim.x + threadIdx.x;
  if (e >= E) return;
  int s = ei[e];
  int d = ei[E + e];
  int pos = atomicAdd(&cursor[d], 1);
  float4 r;
  r.x = ea[e * 3 + 0];
  r.y = ea[e * 3 + 1];
  r.z = ea[e * 3 + 2];
  r.w = __int_as_float(s * 256);
  e4[pos] = r;
}

__global__ void k_selfloop(const int* __restrict__ offs, float4* __restrict__ e4, int N) {
  int n = blockIdx.x * blockDim.x + threadIdx.x;
  if (n >= N) return;
  int beg = offs[n], last = offs[n + 1] - 1;
  float s0 = 0.f, s1 = 0.f, s2 = 0.f;
  for (int p = beg; p < last; ++p) {
    float4 v = e4[p];
    s0 += v.x;
    s1 += v.y;
    s2 += v.z;
  }
  float invc = 1.0f / fmaxf((float)(last - beg), 1.0f);
  float4 r;
  r.x = s0 * invc;
  r.y = s1 * invc;
  r.z = s2 * invc;
  r.w = __int_as_float(n * 256);
  e4[last] = r;
}

// ---------------- fp32 -> bf16 converters ----------------

__global__ void k_convx(const float* __restrict__ x, unsigned short* __restrict__ xb, int n) {
  int i = (blockIdx.x * blockDim.x + threadIdx.x) * 4;
  if (i >= n) return;
  float4 v = *(const float4*)&x[i];
  ushort4 o;
  o.x = f2bf(v.x); o.y = f2bf(v.y); o.z = f2bf(v.z); o.w = f2bf(v.w);
  *(ushort4*)&xb[i] = o;
}

__global__ void k_convW(const float* __restrict__ w0, const float* __restrict__ w1,
                        const float* __restrict__ w2, const float* __restrict__ w3,
                        const float* __restrict__ w4, const float* __restrict__ w5,
                        unsigned short* __restrict__ dst) {
  const float* srcs[6] = {w0, w1, w2, w3, w4, w5};
  const float* s = srcs[blockIdx.y];
  int i = blockIdx.x * 256 + threadIdx.x;  // 0..16383
  dst[(size_t)blockIdx.y * 16384 + i] = f2bf(s[i]);
}

// ---------------- MFMA GEMM: out_bf16[n][j] = bf16(bias[j] + sum_k x[n][k]*W[j][k]) ----------------
__global__ __launch_bounds__(256) void k_gemm_mfma(const unsigned short* __restrict__ xb,
                                                   const unsigned short* __restrict__ Wb,
                                                   const float* __restrict__ bl, const float* __restrict__ br,
                                                   unsigned short* __restrict__ xlb,
                                                   unsigned short* __restrict__ xrb, int N) {
  int wave = threadIdx.x >> 6;
  int lane = threadIdx.x & 63;
  int which = blockIdx.y;
  const unsigned short* W = Wb + (size_t)which * 16384;
  const float* bias = which ? br : bl;
  unsigned short* out = which ? xrb : xlb;

  int row0 = (blockIdx.x * 4 + wave) * 16;
  if (row0 >= N) return;
  int m = lane & 15;
  int q = lane >> 4;

  int arow = row0 + m;
  if (arow >= N) arow = N - 1;
  const unsigned short* xrow = xb + (size_t)arow * 128 + q * 8;

  bf16x8 afrag[4];
#pragma unroll
  for (int kt = 0; kt < 4; ++kt) afrag[kt] = *(const bf16x8*)(xrow + kt * 32);

  f32x4 acc[8];
#pragma unroll
  for (int jt = 0; jt < 8; ++jt) acc[jt] = (f32x4){0.f, 0.f, 0.f, 0.f};

  const unsigned short* wbase = W + (size_t)m * 128 + q * 8;
#pragma unroll
  for (int kt = 0; kt < 4; ++kt) {
    bf16x8 a = afrag[kt];
#pragma unroll
    for (int jt = 0; jt < 8; ++jt) {
      bf16x8 b = *(const bf16x8*)(wbase + (size_t)jt * 16 * 128 + kt * 32);
      acc[jt] = __builtin_amdgcn_mfma_f32_16x16x32_bf16(a, b, acc[jt], 0, 0, 0);
    }
  }

#pragma unroll
  for (int jt = 0; jt < 8; ++jt) {
    float bs = bias[jt * 16 + m];
#pragma unroll
    for (int r = 0; r < 4; ++r) {
      int rr = row0 + q * 4 + r;
      if (rr < N) out[(size_t)rr * 128 + jt * 16 + m] = f2bf(acc[jt][r] + bs);
    }
  }
}

// ---------------- fused: score + softmax(exp2) + weighted agg + epilogue ----------------
// one wave per node; lane owns channels 2*lane, 2*lane+1; head group = 16 lanes.
__global__ __launch_bounds__(256) void k_agg(const unsigned short* __restrict__ xlb,
                                             const unsigned short* __restrict__ xrb,
                                             const float4* __restrict__ e4,
                                             const int* __restrict__ offs,
                                             const float* __restrict__ We, const float* __restrict__ att,
                                             const float* __restrict__ bo,
                                             const float* __restrict__ lng, const float* __restrict__ lnb,
                                             unsigned short* __restrict__ xnext_bf,
                                             float* __restrict__ emb, int last, int N) {
  int w = (blockIdx.x * blockDim.x + threadIdx.x) >> 6;
  if (w >= N) return;
  int lane = threadIdx.x & 63;
  int c = lane * 2;
  unsigned int c2 = (unsigned int)(c * 2);  // byte offset of this lane's channel pair
  int beg = offs[w], end = offs[w + 1];

  unsigned int vr = *(const unsigned int*)&xrb[(size_t)w * 128 + c];
  float xr0 = __uint_as_float(vr << 16);
  float xr1 = __uint_as_float(vr & 0xffff0000u);
  float we00 = We[c * 3 + 0], we01 = We[c * 3 + 1], we02 = We[c * 3 + 2];
  float we10 = We[c * 3 + 3], we11 = We[c * 3 + 4], we12 = We[c * 3 + 5];
  float a0 = att[c] * LOG2E, a1 = att[c + 1] * LOG2E;  // fold ln->log2 into att

  const char* xlB = (const char*)xlb;

  float lA = 0.f, axA = 0.f, ayA = 0.f;
  float lB = 0.f, axB = 0.f, ayB = 0.f;

  const float4* ep = e4 + beg;
  int cntE = end - beg;
  int i = 0;
  for (; i + 2 <= cntE; i += 2) {
    float4 eA = ep[0];
    float4 eB = ep[1];
    ep += 2;
    unsigned int offA = (unsigned int)__float_as_int(eA.w) + c2;
    unsigned int offB = (unsigned int)__float_as_int(eB.w) + c2;
    unsigned int vA = *(const unsigned int*)(xlB + offA);
    unsigned int vB = *(const unsigned int*)(xlB + offB);
    float xA0 = __uint_as_float(vA << 16), xA1 = __uint_as_float(vA & 0xffff0000u);
    float xB0 = __uint_as_float(vB << 16), xB1 = __uint_as_float(vB & 0xffff0000u);

    float mA0 = xr0 + we00 * eA.x + we01 * eA.y + we02 * eA.z + xA0;
    float mA1 = xr1 + we10 * eA.x + we11 * eA.y + we12 * eA.z + xA1;
    float mB0 = xr0 + we00 * eB.x + we01 * eB.y + we02 * eB.z + xB0;
    float mB1 = xr1 + we10 * eB.x + we11 * eB.y + we12 * eB.z + xB1;

    mA0 = fmaxf(mA0, 0.2f * mA0);
    mA1 = fmaxf(mA1, 0.2f * mA1);
    mB0 = fmaxf(mB0, 0.2f * mB0);
    mB1 = fmaxf(mB1, 0.2f * mB1);

    float wA = __builtin_amdgcn_exp2f(dpp_sum16(mA0 * a0 + mA1 * a1));
    float wB = __builtin_amdgcn_exp2f(dpp_sum16(mB0 * a0 + mB1 * a1));
    lA += wA;
    axA = fmaf(wA, xA0, axA);
    ayA = fmaf(wA, xA1, ayA);
    lB += wB;
    axB = fmaf(wB, xB0, axB);
    ayB = fmaf(wB, xB1, ayB);
  }
  if (i < cntE) {
    float4 eA = ep[0];
    unsigned int offA = (unsigned int)__float_as_int(eA.w) + c2;
    unsigned int vA = *(const unsigned int*)(xlB + offA);
    float xA0 = __uint_as_float(vA << 16), xA1 = __uint_as_float(vA & 0xffff0000u);
    float mA0 = xr0 + we00 * eA.x + we01 * eA.y + we02 * eA.z + xA0;
    float mA1 = xr1 + we10 * eA.x + we11 * eA.y + we12 * eA.z + xA1;
    mA0 = fmaxf(mA0, 0.2f * mA0);
    mA1 = fmaxf(mA1, 0.2f * mA1);
    float wA = __builtin_amdgcn_exp2f(dpp_sum16(mA0 * a0 + mA1 * a1));
    lA += wA;
    axA = fmaf(wA, xA0, axA);
    ayA = fmaf(wA, xA1, ayA);
  }
  float l = lA + lB;
  float accx = axA + axB, accy = ayA + ayB;

  float inv = 1.0f / l;
  float ax = accx * inv + bo[c];
  float ay = accy * inv + bo[c + 1];

  if (last) {
    emb[(size_t)w * 128 + c] = ax;
    emb[(size_t)w * 128 + c + 1] = ay;
  } else {
    float rx = fmaxf(ax, 0.f), ry = fmaxf(ay, 0.f);
    float s = rx + ry;
    s += __shfl_xor(s, 1);
    s += __shfl_xor(s, 2);
    s += __shfl_xor(s, 4);
    s += __shfl_xor(s, 8);
    s += __shfl_xor(s, 16);
    s += __shfl_xor(s, 32);
    float mu = s * 0.0078125f;  // /128
    float dx = rx - mu, dy = ry - mu;
    float v2 = dx * dx + dy * dy;
    v2 += __shfl_xor(v2, 1);
    v2 += __shfl_xor(v2, 2);
    v2 += __shfl_xor(v2, 4);
    v2 += __shfl_xor(v2, 8);
    v2 += __shfl_xor(v2, 16);
    v2 += __shfl_xor(v2, 32);
    float var = v2 * 0.0078125f;
    float rstd = rsqrtf(var + LN_EPS);
    float o0 = dx * rstd * lng[c] + lnb[c];
    float o1 = dy * rstd * lng[c + 1] + lnb[c + 1];
    unsigned int pack = (unsigned int)f2bf(o0) | ((unsigned int)f2bf(o1) << 16);
    *(unsigned int*)&xnext_bf[(size_t)w * 128 + c] = pack;
  }
}

// ---------------- graph max-pool (relu implicit: atomicMax vs 0-init) ----------------
// 256 threads: two nodes in flight (threads 0..127 -> even offset, 128..255 -> odd)
__global__ void k_pool(const float* __restrict__ emb, const int* __restrict__ batch,
                       float* __restrict__ pooled, int N) {
  int c = threadIdx.x & 127;
  int half = threadIdx.x >> 7;
  int base = blockIdx.x * 64 + half;
  int limit = min(blockIdx.x * 64 + 64, N);
  float cur = 0.f;
  int curg = -1;
  for (int n = base; n < limit; n += 2) {
    int g = batch[n];
    if (g != curg) {
      if (curg >= 0) atomicMax((unsigned int*)&pooled[curg * 128 + c], __float_as_uint(cur));
      curg = g;
      cur = 0.f;
    }
    cur = fmaxf(cur, emb[(size_t)n * 128 + c]);
  }
  if (curg >= 0) atomicMax((unsigned int*)&pooled[curg * 128 + c], __float_as_uint(cur));
}

// ---------------- MLP: 128 -> 32 -> 32 -> 32 -> 1 ----------------
__global__ void k_mlp(const float* __restrict__ pooled,
                      const float* __restrict__ pw1, const float* __restrict__ pb1,
                      const float* __restrict__ pw2, const float* __restrict__ pb2,
                      const float* __restrict__ pw3, const float* __restrict__ pb3,
                      const float* __restrict__ pw4, const float* __restrict__ pb4,
                      float* __restrict__ out) {
  int g = blockIdx.x;
  int t = threadIdx.x;  // 64 threads
  __shared__ float buf1[32], buf2[32];
  if (t < 32) {
    float acc = pb1[t];
    for (int k = 0; k < 128; ++k) acc += pw1[t * 128 + k] * pooled[g * 128 + k];
    buf1[t] = fmaxf(acc, 0.f);
  }
  __syncthreads();
  if (t < 32) {
    float acc = pb2[t];
    for (int k = 0; k < 32; ++k) acc += pw2[t * 32 + k] * buf1[k];
    buf2[t] = fmaxf(acc, 0.f);
  }
  __syncthreads();
  if (t < 32) {
    float acc = pb3[t];
    for (int k = 0; k < 32; ++k) acc += pw3[t * 32 + k] * buf2[k];
    buf1[t] = fmaxf(acc, 0.f);
  }
  __syncthreads();
  if (t == 0) {
    float acc = pb4[0];
    for (int k = 0; k < 32; ++k) acc += pw4[k] * buf1[k];
    out[g] = acc;
  }
}

// ---------------------------------------------------------------------------

extern "C" void kernel_launch(void* const* d_in, const int* in_sizes, int n_in,
                              void* d_out, int out_size, void* d_ws, size_t ws_size,
                              hipStream_t stream) {
  const float* x_in = (const float*)d_in[0];
  const int* ei = (const int*)d_in[1];
  const int* batch = (const int*)d_in[2];
  const float* ea = (const float*)d_in[3];

  const int N = in_sizes[0] / 128;
  const int E = in_sizes[1] / 2;
  const int EP = E + N;
  const int G = out_size - N * 128;

  const float *Wl[3], *bl[3], *Wr[3], *br[3], *We[3], *att[3], *bo[3];
  for (int l = 0; l < 3; ++l) {
    Wl[l] = (const float*)d_in[4 + 7 * l];
    bl[l] = (const float*)d_in[5 + 7 * l];
    Wr[l] = (const float*)d_in[6 + 7 * l];
    br[l] = (const float*)d_in[7 + 7 * l];
    We[l] = (const float*)d_in[8 + 7 * l];
    att[l] = (const float*)d_in[9 + 7 * l];
    bo[l] = (const float*)d_in[10 + 7 * l];
  }
  const float* lng[2] = {(const float*)d_in[25], (const float*)d_in[27]};
  const float* lnb[2] = {(const float*)d_in[26], (const float*)d_in[28]};
  const float* pw1 = (const float*)d_in[29];
  const float* pb1 = (const float*)d_in[30];
  const float* pw2 = (const float*)d_in[31];
  const float* pb2 = (const float*)d_in[32];
  const float* pw3 = (const float*)d_in[33];
  const float* pb3 = (const float*)d_in[34];
  const float* pw4 = (const float*)d_in[35];
  const float* pb4 = (const float*)d_in[36];

  char* base = (char*)d_ws;
  size_t cur = 0;
  auto carve = [&](size_t bytes) -> char* {
    char* p = base + cur;
    cur += (bytes + 255) & ~(size_t)255;
    return p;
  };
  unsigned short* xlb = (unsigned short*)carve((size_t)N * 128 * 2);
  unsigned short* xrb = (unsigned short*)carve((size_t)N * 128 * 2);
  unsigned short* xb = (unsigned short*)carve((size_t)N * 128 * 2);  // bf16 activations
  unsigned short* Wb = (unsigned short*)carve((size_t)6 * 16384 * 2);
  float4* e4 = (float4*)carve((size_t)EP * 16);
  int* offs = (int*)carve((size_t)(N + 1) * 4);
  int* cursor = (int*)carve((size_t)N * 4);
  int* cnt = (int*)carve((size_t)N * 4);
  int* bsum = (int*)carve(1024);
  float* pooled = (float*)carve((size_t)G * 128 * 4);

  float* emb_out = (float*)d_out;
  float* mlp_out = (float*)d_out + (size_t)N * 128;

  const int NB = (N + 255) / 256;

  hipMemsetAsync(cnt, 0, (size_t)N * 4, stream);
  hipMemsetAsync(pooled, 0, (size_t)G * 128 * 4, stream);

  k_degree<<<(E / 4 + 255) / 256, 256, 0, stream>>>(ei, cnt, E);
  k_scan1<<<NB, 256, 0, stream>>>(cnt, bsum, N);
  k_scan2<<<1, 256, 0, stream>>>(bsum, offs, NB, EP, N);
  k_scan3<<<NB, 256, 0, stream>>>(cnt, bsum, offs, cursor, N);
  k_scatter<<<(E + 255) / 256, 256, 0, stream>>>(ei, ea, cursor, e4, E);
  k_selfloop<<<NB, 256, 0, stream>>>(offs, e4, N);

  k_convx<<<(N * 128 / 4 + 255) / 256, 256, 0, stream>>>(x_in, xb, N * 128);
  {
    dim3 g(64, 6);
    k_convW<<<g, 256, 0, stream>>>(Wl[0], Wr[0], Wl[1], Wr[1], Wl[2], Wr[2], Wb);
  }

  for (int l = 0; l < 3; ++l) {
    dim3 ggrid((N + 63) / 64, 2);
    k_gemm_mfma<<<ggrid, 256, 0, stream>>>(xb, Wb + (size_t)l * 32768, bl[l], br[l], xlb, xrb, N);
    int last = (l == 2) ? 1 : 0;
    const float* g = last ? bo[l] : lng[l];
    const float* b = last ? bo[l] : lnb[l];
    k_agg<<<(N * 64 + 255) / 256, 256, 0, stream>>>(xlb, xrb, e4, offs,
                                                    We[l], att[l], bo[l], g, b,
                                                    xb, emb_out, last, N);
  }

  k_pool<<<(N + 63) / 64, 256, 0, stream>>>(emb_out, batch, pooled, N);
  k_mlp<<<G, 64, 0, stream>>>(pooled, pw1, pb1, pw2, pb2, pw3, pb3, pw4, pb4, mlp_out);
}

// Round 6
// 554.887 us; speedup vs baseline: 2.3283x; 1.0707x over previous
//
#include <hip/hip_runtime.h>
#include <math.h>

// ---------------------------------------------------------------------------
// GATv2 x3 + LN + graph max-pool + MLP.
// Round 6: k_agg half-wave edge pairing -- lanes 0-31 process edge p, lanes
// 32-63 edge p+1 of the SAME node; 4 channels/lane (dwordx2 gather), one e4
// dwordx4 per pair, one exp2 per pair, 3-step DPP head reduction
// (xor1, xor2, row_half_mirror), e4 prefetch pipeline, peeled masked tail.
// ---------------------------------------------------------------------------

#define LN_EPS 1e-5f
#define LOG2E 1.44269504088896340736f

typedef short bf16x8 __attribute__((ext_vector_type(8)));
typedef float f32x4 __attribute__((ext_vector_type(4)));

static __device__ __forceinline__ unsigned short f2bf(float f) {
  unsigned int u = __float_as_uint(f);
  u += 0x7fffu + ((u >> 16) & 1u);  // RNE
  return (unsigned short)(u >> 16);
}

// sum+broadcast over each 8-lane group: quad xor1, quad xor2, row_half_mirror
static __device__ __forceinline__ float dpp_sum8(float v) {
  int x;
  x = __builtin_amdgcn_update_dpp(0, __float_as_int(v), 0x0B1, 0xf, 0xf, true);  // quad_perm 1,0,3,2
  v += __int_as_float(x);
  x = __builtin_amdgcn_update_dpp(0, __float_as_int(v), 0x04E, 0xf, 0xf, true);  // quad_perm 2,3,0,1
  v += __int_as_float(x);
  x = __builtin_amdgcn_update_dpp(0, __float_as_int(v), 0x141, 0xf, 0xf, true);  // row_half_mirror
  v += __int_as_float(x);
  return v;
}

// ---------------- prepass ----------------

__global__ void k_degree(const int* __restrict__ ei, int* __restrict__ cnt, int E) {
  int e = (blockIdx.x * blockDim.x + threadIdx.x) * 4;
  if (e + 3 < E) {
    int4 d = *(const int4*)&ei[E + e];
    atomicAdd(&cnt[d.x], 1);
    atomicAdd(&cnt[d.y], 1);
    atomicAdd(&cnt[d.z], 1);
    atomicAdd(&cnt[d.w], 1);
  } else {
    int lim = min(e + 4, E);
    for (; e < lim; ++e) atomicAdd(&cnt[ei[E + e]], 1);
  }
}

__global__ void k_scan1(const int* __restrict__ cnt, int* __restrict__ bsum, int N) {
  __shared__ int sh[256];
  int t = threadIdx.x;
  int n = blockIdx.x * 256 + t;
  sh[t] = (n < N) ? (cnt[n] + 1) : 0;
  __syncthreads();
  for (int s = 128; s > 0; s >>= 1) {
    if (t < s) sh[t] += sh[t + s];
    __syncthreads();
  }
  if (t == 0) bsum[blockIdx.x] = sh[0];
}

__global__ void k_scan2(int* __restrict__ bsum, int* __restrict__ offs, int nb, int total, int N) {
  __shared__ int sh[256];
  int t = threadIdx.x;
  int v = (t < nb) ? bsum[t] : 0;
  sh[t] = v;
  __syncthreads();
  for (int d = 1; d < 256; d <<= 1) {
    int add = (t >= d) ? sh[t - d] : 0;
    __syncthreads();
    sh[t] += add;
    __syncthreads();
  }
  if (t < nb) bsum[t] = sh[t] - v;  // exclusive block bases
  if (t == 0) offs[N] = total;
}

__global__ void k_scan3(const int* __restrict__ cnt, const int* __restrict__ bsum,
                        int* __restrict__ offs, int* __restrict__ cursor, int N) {
  __shared__ int sh[256];
  int t = threadIdx.x;
  int n = blockIdx.x * 256 + t;
  int v = (n < N) ? (cnt[n] + 1) : 0;
  sh[t] = v;
  __syncthreads();
  for (int d = 1; d < 256; d <<= 1) {
    int add = (t >= d) ? sh[t - d] : 0;
    __syncthreads();
    sh[t] += add;
    __syncthreads();
  }
  if (n < N) {
    int o = bsum[blockIdx.x] + sh[t] - v;
    offs[n] = o;
    cursor[n] = o;  // real edges fill from offs[n]; self-loop slot is offs[n+1]-1
  }
}

// packed edge record: {ea0, ea1, ea2, bits(src*256 byte-offset into bf16 row table)}
__global__ void k_scatter(const int* __restrict__ ei, const float* __restrict__ ea,
                          int* __restrict__ cursor, float4* __restrict__ e4, int E) {
  int e = blockIdx.x * blockDim.x + threadIdx.x;
  if (e >= E) return;
  int s = ei[e];
  int d = ei[E + e];
  int pos = atomicAdd(&cursor[d], 1);
  float4 r;
  r.x = ea[e * 3 + 0];
  r.y = ea[e * 3 + 1];
  r.z = ea[e * 3 + 2];
  r.w = __int_as_float(s * 256);
  e4[pos] = r;
}

__global__ void k_selfloop(const int* __restrict__ offs, float4* __restrict__ e4, int N) {
  int n = blockIdx.x * blockDim.x + threadIdx.x;
  if (n >= N) return;
  int beg = offs[n], last = offs[n + 1] - 1;
  float s0 = 0.f, s1 = 0.f, s2 = 0.f;
  for (int p = beg; p < last; ++p) {
    float4 v = e4[p];
    s0 += v.x;
    s1 += v.y;
    s2 += v.z;
  }
  float invc = 1.0f / fmaxf((float)(last - beg), 1.0f);
  float4 r;
  r.x = s0 * invc;
  r.y = s1 * invc;
  r.z = s2 * invc;
  r.w = __int_as_float(n * 256);
  e4[last] = r;
}

// ---------------- fp32 -> bf16 converters ----------------

__global__ void k_convx(const float* __restrict__ x, unsigned short* __restrict__ xb, int n) {
  int i = (blockIdx.x * blockDim.x + threadIdx.x) * 4;
  if (i >= n) return;
  float4 v = *(const float4*)&x[i];
  ushort4 o;
  o.x = f2bf(v.x); o.y = f2bf(v.y); o.z = f2bf(v.z); o.w = f2bf(v.w);
  *(ushort4*)&xb[i] = o;
}

__global__ void k_convW(const float* __restrict__ w0, const float* __restrict__ w1,
                        const float* __restrict__ w2, const float* __restrict__ w3,
                        const float* __restrict__ w4, const float* __restrict__ w5,
                        unsigned short* __restrict__ dst) {
  const float* srcs[6] = {w0, w1, w2, w3, w4, w5};
  const float* s = srcs[blockIdx.y];
  int i = blockIdx.x * 256 + threadIdx.x;  // 0..16383
  dst[(size_t)blockIdx.y * 16384 + i] = f2bf(s[i]);
}

// ---------------- MFMA GEMM: out_bf16[n][j] = bf16(bias[j] + sum_k x[n][k]*W[j][k]) ----------------
__global__ __launch_bounds__(256) void k_gemm_mfma(const unsigned short* __restrict__ xb,
                                                   const unsigned short* __restrict__ Wb,
                                                   const float* __restrict__ bl, const float* __restrict__ br,
                                                   unsigned short* __restrict__ xlb,
                                                   unsigned short* __restrict__ xrb, int N) {
  int wave = threadIdx.x >> 6;
  int lane = threadIdx.x & 63;
  int which = blockIdx.y;
  const unsigned short* W = Wb + (size_t)which * 16384;
  const float* bias = which ? br : bl;
  unsigned short* out = which ? xrb : xlb;

  int row0 = (blockIdx.x * 4 + wave) * 16;
  if (row0 >= N) return;
  int m = lane & 15;
  int q = lane >> 4;

  int arow = row0 + m;
  if (arow >= N) arow = N - 1;
  const unsigned short* xrow = xb + (size_t)arow * 128 + q * 8;

  bf16x8 afrag[4];
#pragma unroll
  for (int kt = 0; kt < 4; ++kt) afrag[kt] = *(const bf16x8*)(xrow + kt * 32);

  f32x4 acc[8];
#pragma unroll
  for (int jt = 0; jt < 8; ++jt) acc[jt] = (f32x4){0.f, 0.f, 0.f, 0.f};

  const unsigned short* wbase = W + (size_t)m * 128 + q * 8;
#pragma unroll
  for (int kt = 0; kt < 4; ++kt) {
    bf16x8 a = afrag[kt];
#pragma unroll
    for (int jt = 0; jt < 8; ++jt) {
      bf16x8 b = *(const bf16x8*)(wbase + (size_t)jt * 16 * 128 + kt * 32);
      acc[jt] = __builtin_amdgcn_mfma_f32_16x16x32_bf16(a, b, acc[jt], 0, 0, 0);
    }
  }

#pragma unroll
  for (int jt = 0; jt < 8; ++jt) {
    float bs = bias[jt * 16 + m];
#pragma unroll
    for (int r = 0; r < 4; ++r) {
      int rr = row0 + q * 4 + r;
      if (rr < N) out[(size_t)rr * 128 + jt * 16 + m] = f2bf(acc[jt][r] + bs);
    }
  }
}

// ---------------- fused: score + softmax(exp2) + weighted agg + epilogue ----------------
// one wave per node; lanes 0-31 = edge p, lanes 32-63 = edge p+1 (same node);
// each lane owns 4 channels c = (lane&31)*4; head group = 8 lanes.
__global__ __launch_bounds__(256) void k_agg(const unsigned short* __restrict__ xlb,
                                             const unsigned short* __restrict__ xrb,
                                             const float4* __restrict__ e4,
                                             const int* __restrict__ offs,
                                             const float* __restrict__ We, const float* __restrict__ att,
                                             const float* __restrict__ bo,
                                             const float* __restrict__ lng, const float* __restrict__ lnb,
                                             unsigned short* __restrict__ xnext_bf,
                                             float* __restrict__ emb, int last, int N) {
  int w = (blockIdx.x * blockDim.x + threadIdx.x) >> 6;
  if (w >= N) return;
  int lane = threadIdx.x & 63;
  int half = lane >> 5;
  int sl = lane & 31;
  int c = sl * 4;
  unsigned int c2 = (unsigned int)(c * 2);  // byte offset into bf16 row
  int beg = offs[w], end = offs[w + 1];
  int cnt = end - beg;

  // per-lane params for 4 channels
  f32x4 xr4, wea, web, wec, at4;
  {
    uint2 vr = *(const uint2*)&xrb[(size_t)w * 128 + c];
    xr4[0] = __uint_as_float(vr.x << 16);
    xr4[1] = __uint_as_float(vr.x & 0xffff0000u);
    xr4[2] = __uint_as_float(vr.y << 16);
    xr4[3] = __uint_as_float(vr.y & 0xffff0000u);
#pragma unroll
    for (int j = 0; j < 4; ++j) {
      wea[j] = We[(c + j) * 3 + 0];
      web[j] = We[(c + j) * 3 + 1];
      wec[j] = We[(c + j) * 3 + 2];
      at4[j] = att[c + j] * LOG2E;  // fold ln->log2 into att
    }
  }

  const char* xlB = (const char*)xlb;
  const char* e4B = (const char*)e4;
  unsigned int lastoff = (unsigned int)(end - 1) << 4;
  unsigned int eoff = (unsigned int)(beg + half) << 4;
  if (eoff > lastoff) eoff = lastoff;  // cnt==1, half 1 clamps

  float l = 0.f;
  f32x4 acc = {0.f, 0.f, 0.f, 0.f};

  int T = (cnt + 1) >> 1;  // pair iterations
  float4 eC = *(const float4*)(e4B + eoff);

#pragma unroll 2
  for (int it = 0; it < T - 1; ++it) {
    unsigned int noff = eoff + 32u;
    if (noff > lastoff) noff = lastoff;
    float4 eN = *(const float4*)(e4B + noff);
    eoff = noff;

    unsigned int go = (unsigned int)__float_as_int(eC.w) + c2;
    uint2 v = *(const uint2*)(xlB + go);
    f32x4 xl4;
    xl4[0] = __uint_as_float(v.x << 16);
    xl4[1] = __uint_as_float(v.x & 0xffff0000u);
    xl4[2] = __uint_as_float(v.y << 16);
    xl4[3] = __uint_as_float(v.y & 0xffff0000u);

    f32x4 t = xr4 + wea * eC.x + web * eC.y + wec * eC.z + xl4;
    t[0] = fmaxf(t[0], 0.2f * t[0]);
    t[1] = fmaxf(t[1], 0.2f * t[1]);
    t[2] = fmaxf(t[2], 0.2f * t[2]);
    t[3] = fmaxf(t[3], 0.2f * t[3]);
    float s = t[0] * at4[0] + t[1] * at4[1] + t[2] * at4[2] + t[3] * at4[3];
    float wgt = __builtin_amdgcn_exp2f(dpp_sum8(s));
    l += wgt;
    acc += xl4 * wgt;
    eC = eN;
  }
  {  // peeled last pair with validity mask
    int idx = 2 * (T - 1) + half;
    unsigned int go = (unsigned int)__float_as_int(eC.w) + c2;
    uint2 v = *(const uint2*)(xlB + go);
    f32x4 xl4;
    xl4[0] = __uint_as_float(v.x << 16);
    xl4[1] = __uint_as_float(v.x & 0xffff0000u);
    xl4[2] = __uint_as_float(v.y << 16);
    xl4[3] = __uint_as_float(v.y & 0xffff0000u);
    f32x4 t = xr4 + wea * eC.x + web * eC.y + wec * eC.z + xl4;
    t[0] = fmaxf(t[0], 0.2f * t[0]);
    t[1] = fmaxf(t[1], 0.2f * t[1]);
    t[2] = fmaxf(t[2], 0.2f * t[2]);
    t[3] = fmaxf(t[3], 0.2f * t[3]);
    float s = t[0] * at4[0] + t[1] * at4[1] + t[2] * at4[2] + t[3] * at4[3];
    float wgt = __builtin_amdgcn_exp2f(dpp_sum8(s));
    if (idx >= cnt) wgt = 0.f;
    l += wgt;
    acc += xl4 * wgt;
  }

  // combine halves
  l += __shfl_xor(l, 32);
  acc[0] += __shfl_xor(acc[0], 32);
  acc[1] += __shfl_xor(acc[1], 32);
  acc[2] += __shfl_xor(acc[2], 32);
  acc[3] += __shfl_xor(acc[3], 32);

  float inv = 1.0f / l;
  f32x4 o;
  const float4 bo4 = *(const float4*)&bo[c];
  o[0] = acc[0] * inv + bo4.x;
  o[1] = acc[1] * inv + bo4.y;
  o[2] = acc[2] * inv + bo4.z;
  o[3] = acc[3] * inv + bo4.w;

  if (last) {
    if (half == 0) {
      float4 st = {o[0], o[1], o[2], o[3]};
      *(float4*)&emb[(size_t)w * 128 + c] = st;
    }
  } else {
    f32x4 r;
    r[0] = fmaxf(o[0], 0.f);
    r[1] = fmaxf(o[1], 0.f);
    r[2] = fmaxf(o[2], 0.f);
    r[3] = fmaxf(o[3], 0.f);
    float s = r[0] + r[1] + r[2] + r[3];
    s += __shfl_xor(s, 1);
    s += __shfl_xor(s, 2);
    s += __shfl_xor(s, 4);
    s += __shfl_xor(s, 8);
    s += __shfl_xor(s, 16);
    float mu = s * 0.0078125f;  // /128
    f32x4 d;
    d[0] = r[0] - mu;
    d[1] = r[1] - mu;
    d[2] = r[2] - mu;
    d[3] = r[3] - mu;
    float v2 = d[0] * d[0] + d[1] * d[1] + d[2] * d[2] + d[3] * d[3];
    v2 += __shfl_xor(v2, 1);
    v2 += __shfl_xor(v2, 2);
    v2 += __shfl_xor(v2, 4);
    v2 += __shfl_xor(v2, 8);
    v2 += __shfl_xor(v2, 16);
    float var = v2 * 0.0078125f;
    float rstd = rsqrtf(var + LN_EPS);
    if (half == 0) {
      const float4 g4 = *(const float4*)&lng[c];
      const float4 b4 = *(const float4*)&lnb[c];
      float o0 = d[0] * rstd * g4.x + b4.x;
      float o1 = d[1] * rstd * g4.y + b4.y;
      float o2 = d[2] * rstd * g4.z + b4.z;
      float o3 = d[3] * rstd * g4.w + b4.w;
      uint2 pack;
      pack.x = (unsigned int)f2bf(o0) | ((unsigned int)f2bf(o1) << 16);
      pack.y = (unsigned int)f2bf(o2) | ((unsigned int)f2bf(o3) << 16);
      *(uint2*)&xnext_bf[(size_t)w * 128 + c] = pack;
    }
  }
}

// ---------------- graph max-pool (relu implicit: atomicMax vs 0-init) ----------------
// 256 threads: two nodes in flight (threads 0..127 -> even offset, 128..255 -> odd)
__global__ void k_pool(const float* __restrict__ emb, const int* __restrict__ batch,
                       float* __restrict__ pooled, int N) {
  int c = threadIdx.x & 127;
  int half = threadIdx.x >> 7;
  int base = blockIdx.x * 64 + half;
  int limit = min(blockIdx.x * 64 + 64, N);
  float cur = 0.f;
  int curg = -1;
  for (int n = base; n < limit; n += 2) {
    int g = batch[n];
    if (g != curg) {
      if (curg >= 0) atomicMax((unsigned int*)&pooled[curg * 128 + c], __float_as_uint(cur));
      curg = g;
      cur = 0.f;
    }
    cur = fmaxf(cur, emb[(size_t)n * 128 + c]);
  }
  if (curg >= 0) atomicMax((unsigned int*)&pooled[curg * 128 + c], __float_as_uint(cur));
}

// ---------------- MLP: 128 -> 32 -> 32 -> 32 -> 1 ----------------
__global__ void k_mlp(const float* __restrict__ pooled,
                      const float* __restrict__ pw1, const float* __restrict__ pb1,
                      const float* __restrict__ pw2, const float* __restrict__ pb2,
                      const float* __restrict__ pw3, const float* __restrict__ pb3,
                      const float* __restrict__ pw4, const float* __restrict__ pb4,
                      float* __restrict__ out) {
  int g = blockIdx.x;
  int t = threadIdx.x;  // 64 threads
  __shared__ float buf1[32], buf2[32];
  if (t < 32) {
    float acc = pb1[t];
    for (int k = 0; k < 128; ++k) acc += pw1[t * 128 + k] * pooled[g * 128 + k];
    buf1[t] = fmaxf(acc, 0.f);
  }
  __syncthreads();
  if (t < 32) {
    float acc = pb2[t];
    for (int k = 0; k < 32; ++k) acc += pw2[t * 32 + k] * buf1[k];
    buf2[t] = fmaxf(acc, 0.f);
  }
  __syncthreads();
  if (t < 32) {
    float acc = pb3[t];
    for (int k = 0; k < 32; ++k) acc += pw3[t * 32 + k] * buf2[k];
    buf1[t] = fmaxf(acc, 0.f);
  }
  __syncthreads();
  if (t == 0) {
    float acc = pb4[0];
    for (int k = 0; k < 32; ++k) acc += pw4[k] * buf1[k];
    out[g] = acc;
  }
}

// ---------------------------------------------------------------------------

extern "C" void kernel_launch(void* const* d_in, const int* in_sizes, int n_in,
                              void* d_out, int out_size, void* d_ws, size_t ws_size,
                              hipStream_t stream) {
  const float* x_in = (const float*)d_in[0];
  const int* ei = (const int*)d_in[1];
  const int* batch = (const int*)d_in[2];
  const float* ea = (const float*)d_in[3];

  const int N = in_sizes[0] / 128;
  const int E = in_sizes[1] / 2;
  const int EP = E + N;
  const int G = out_size - N * 128;

  const float *Wl[3], *bl[3], *Wr[3], *br[3], *We[3], *att[3], *bo[3];
  for (int l = 0; l < 3; ++l) {
    Wl[l] = (const float*)d_in[4 + 7 * l];
    bl[l] = (const float*)d_in[5 + 7 * l];
    Wr[l] = (const float*)d_in[6 + 7 * l];
    br[l] = (const float*)d_in[7 + 7 * l];
    We[l] = (const float*)d_in[8 + 7 * l];
    att[l] = (const float*)d_in[9 + 7 * l];
    bo[l] = (const float*)d_in[10 + 7 * l];
  }
  const float* lng[2] = {(const float*)d_in[25], (const float*)d_in[27]};
  const float* lnb[2] = {(const float*)d_in[26], (const float*)d_in[28]};
  const float* pw1 = (const float*)d_in[29];
  const float* pb1 = (const float*)d_in[30];
  const float* pw2 = (const float*)d_in[31];
  const float* pb2 = (const float*)d_in[32];
  const float* pw3 = (const float*)d_in[33];
  const float* pb3 = (const float*)d_in[34];
  const float* pw4 = (const float*)d_in[35];
  const float* pb4 = (const float*)d_in[36];

  char* base = (char*)d_ws;
  size_t cur = 0;
  auto carve = [&](size_t bytes) -> char* {
    char* p = base + cur;
    cur += (bytes + 255) & ~(size_t)255;
    return p;
  };
  unsigned short* xlb = (unsigned short*)carve((size_t)N * 128 * 2);
  unsigned short* xrb = (unsigned short*)carve((size_t)N * 128 * 2);
  unsigned short* xb = (unsigned short*)carve((size_t)N * 128 * 2);  // bf16 activations
  unsigned short* Wb = (unsigned short*)carve((size_t)6 * 16384 * 2);
  float4* e4 = (float4*)carve((size_t)EP * 16);
  int* offs = (int*)carve((size_t)(N + 1) * 4);
  int* cursor = (int*)carve((size_t)N * 4);
  int* cnt = (int*)carve((size_t)N * 4);
  int* bsum = (int*)carve(1024);
  float* pooled = (float*)carve((size_t)G * 128 * 4);

  float* emb_out = (float*)d_out;
  float* mlp_out = (float*)d_out + (size_t)N * 128;

  const int NB = (N + 255) / 256;

  hipMemsetAsync(cnt, 0, (size_t)N * 4, stream);
  hipMemsetAsync(pooled, 0, (size_t)G * 128 * 4, stream);

  k_degree<<<(E / 4 + 255) / 256, 256, 0, stream>>>(ei, cnt, E);
  k_scan1<<<NB, 256, 0, stream>>>(cnt, bsum, N);
  k_scan2<<<1, 256, 0, stream>>>(bsum, offs, NB, EP, N);
  k_scan3<<<NB, 256, 0, stream>>>(cnt, bsum, offs, cursor, N);
  k_scatter<<<(E + 255) / 256, 256, 0, stream>>>(ei, ea, cursor, e4, E);
  k_selfloop<<<NB, 256, 0, stream>>>(offs, e4, N);

  k_convx<<<(N * 128 / 4 + 255) / 256, 256, 0, stream>>>(x_in, xb, N * 128);
  {
    dim3 g(64, 6);
    k_convW<<<g, 256, 0, stream>>>(Wl[0], Wr[0], Wl[1], Wr[1], Wl[2], Wr[2], Wb);
  }

  for (int l = 0; l < 3; ++l) {
    dim3 ggrid((N + 63) / 64, 2);
    k_gemm_mfma<<<ggrid, 256, 0, stream>>>(xb, Wb + (size_t)l * 32768, bl[l], br[l], xlb, xrb, N);
    int last = (l == 2) ? 1 : 0;
    const float* g = last ? bo[l] : lng[l];
    const float* b = last ? bo[l] : lnb[l];
    k_agg<<<(N * 64 + 255) / 256, 256, 0, stream>>>(xlb, xrb, e4, offs,
                                                    We[l], att[l], bo[l], g, b,
                                                    xb, emb_out, last, N);
  }

  k_pool<<<(N + 63) / 64, 256, 0, stream>>>(emb_out, batch, pooled, N);
  k_mlp<<<G, 64, 0, stream>>>(pooled, pw1, pb1, pw2, pb2, pw3, pb3, pw4, pb4, mlp_out);
}

// Round 7
// 530.229 us; speedup vs baseline: 2.4366x; 1.0465x over previous
//
#include <hip/hip_runtime.h>
#include <math.h>

// ---------------------------------------------------------------------------
// GATv2 x3 + LN + graph max-pool + MLP.
// Round 7: two-phase binned CSR build. Phase A bins edges by dst>>8 into the
// exact CSR bucket regions (dense staged writes, LDS histogram + per-block
// chunk reservation); Phase B (one block per bucket) places records at final
// slots via LDS cursors -- all writes L2-local to one XCD. Replaces the
// random-16B-scatter that cost 58us / 50MB HBM writes. k_agg unchanged.
// ---------------------------------------------------------------------------

#define LN_EPS 1e-5f
#define LOG2E 1.44269504088896340736f

typedef short bf16x8 __attribute__((ext_vector_type(8)));
typedef float f32x4 __attribute__((ext_vector_type(4)));

static __device__ __forceinline__ unsigned short f2bf(float f) {
  unsigned int u = __float_as_uint(f);
  u += 0x7fffu + ((u >> 16) & 1u);  // RNE
  return (unsigned short)(u >> 16);
}

// sum+broadcast over each 8-lane group: quad xor1, quad xor2, row_half_mirror
static __device__ __forceinline__ float dpp_sum8(float v) {
  int x;
  x = __builtin_amdgcn_update_dpp(0, __float_as_int(v), 0x0B1, 0xf, 0xf, true);  // quad_perm 1,0,3,2
  v += __int_as_float(x);
  x = __builtin_amdgcn_update_dpp(0, __float_as_int(v), 0x04E, 0xf, 0xf, true);  // quad_perm 2,3,0,1
  v += __int_as_float(x);
  x = __builtin_amdgcn_update_dpp(0, __float_as_int(v), 0x141, 0xf, 0xf, true);  // row_half_mirror
  v += __int_as_float(x);
  return v;
}

// ---------------- prepass ----------------

__global__ void k_degree(const int* __restrict__ ei, int* __restrict__ cnt, int E) {
  int e = (blockIdx.x * blockDim.x + threadIdx.x) * 4;
  if (e + 3 < E) {
    int4 d = *(const int4*)&ei[E + e];
    atomicAdd(&cnt[d.x], 1);
    atomicAdd(&cnt[d.y], 1);
    atomicAdd(&cnt[d.z], 1);
    atomicAdd(&cnt[d.w], 1);
  } else {
    int lim = min(e + 4, E);
    for (; e < lim; ++e) atomicAdd(&cnt[ei[E + e]], 1);
  }
}

__global__ void k_scan1(const int* __restrict__ cnt, int* __restrict__ bsum, int N) {
  __shared__ int sh[256];
  int t = threadIdx.x;
  int n = blockIdx.x * 256 + t;
  sh[t] = (n < N) ? (cnt[n] + 1) : 0;
  __syncthreads();
  for (int s = 128; s > 0; s >>= 1) {
    if (t < s) sh[t] += sh[t + s];
    __syncthreads();
  }
  if (t == 0) bsum[blockIdx.x] = sh[0];
}

__global__ void k_scan2(int* __restrict__ bsum, int* __restrict__ offs, int nb, int total, int N) {
  __shared__ int sh[256];
  int t = threadIdx.x;
  int v = (t < nb) ? bsum[t] : 0;
  sh[t] = v;
  __syncthreads();
  for (int d = 1; d < 256; d <<= 1) {
    int add = (t >= d) ? sh[t - d] : 0;
    __syncthreads();
    sh[t] += add;
    __syncthreads();
  }
  if (t < nb) bsum[t] = sh[t] - v;  // exclusive block bases
  if (t == 0) offs[N] = total;
}

__global__ void k_scan3(const int* __restrict__ cnt, const int* __restrict__ bsum,
                        int* __restrict__ offs, int N) {
  __shared__ int sh[256];
  int t = threadIdx.x;
  int n = blockIdx.x * 256 + t;
  int v = (n < N) ? (cnt[n] + 1) : 0;
  sh[t] = v;
  __syncthreads();
  for (int d = 1; d < 256; d <<= 1) {
    int add = (t >= d) ? sh[t - d] : 0;
    __syncthreads();
    sh[t] += add;
    __syncthreads();
  }
  if (n < N) offs[n] = bsum[blockIdx.x] + sh[t] - v;
}

// gcur[b] = offs[b*256]  (start of bucket b's CSR region)
__global__ void k_initcur(const int* __restrict__ offs, int* __restrict__ gcur, int nbuk) {
  int t = threadIdx.x;
  if (t < nbuk) gcur[t] = offs[t * 256];
}

// Phase A: bin edges by dst>>8 into staged[] (records land inside their
// bucket's CSR region, arbitrary order). Record: {ea0,ea1,ea2, src|dst<<16}.
#define CHUNK 4096
__global__ __launch_bounds__(256) void k_binA(const int* __restrict__ ei, const float* __restrict__ ea,
                                              int* __restrict__ gcur, float4* __restrict__ staged,
                                              int E, int nbuk) {
  __shared__ int hist[256];
  __shared__ int basebuf[256];
  int t = threadIdx.x;
  int e0 = blockIdx.x * CHUNK;

  hist[t] = 0;
  __syncthreads();
#pragma unroll
  for (int i = 0; i < CHUNK / 256; ++i) {
    int e = e0 + i * 256 + t;
    if (e < E) atomicAdd(&hist[ei[E + e] >> 8], 1);
  }
  __syncthreads();
  int h = hist[t];
  if (t < nbuk && h > 0) basebuf[t] = atomicAdd(&gcur[t], h);
  hist[t] = 0;
  __syncthreads();
#pragma unroll
  for (int i = 0; i < CHUNK / 256; ++i) {
    int e = e0 + i * 256 + t;
    if (e < E) {
      int s = ei[e];
      int d = ei[E + e];
      int b = d >> 8;
      int r = atomicAdd(&hist[b], 1);
      float4 rec;
      rec.x = ea[e * 3 + 0];
      rec.y = ea[e * 3 + 1];
      rec.z = ea[e * 3 + 2];
      rec.w = __int_as_float(s | (d << 16));
      staged[basebuf[b] + r] = rec;
    }
  }
}

// Phase B: one block per bucket; LDS cursors place records at final CSR slots.
__global__ __launch_bounds__(256) void k_binB(const float4* __restrict__ staged,
                                              const int* __restrict__ offs,
                                              float4* __restrict__ e4, int N) {
  __shared__ int cur[256];
  int t = threadIdx.x;
  int n0 = blockIdx.x * 256;
  int n1 = min(n0 + 256, N);
  if (n0 + t < n1) cur[t] = offs[n0 + t];
  int start = offs[n0];
  int cntReal = (offs[n1] - start) - (n1 - n0);
  __syncthreads();
  for (int p = start + t; p < start + cntReal; p += 256) {
    float4 rec = staged[p];
    unsigned int u = (unsigned int)__float_as_int(rec.w);
    int s = (int)(u & 0xffffu);
    int d = (int)(u >> 16);
    int pos = atomicAdd(&cur[d - n0], 1);
    float4 out;
    out.x = rec.x;
    out.y = rec.y;
    out.z = rec.z;
    out.w = __int_as_float(s * 256);
    e4[pos] = out;
  }
}

// self-loop mean: 4 threads per node, quad shfl reduction
__global__ void k_selfloop(const int* __restrict__ offs, float4* __restrict__ e4, int N) {
  int idx = blockIdx.x * blockDim.x + threadIdx.x;
  int n = idx >> 2;
  if (n >= N) return;
  int sub = idx & 3;
  int beg = offs[n], last = offs[n + 1] - 1;
  float s0 = 0.f, s1 = 0.f, s2 = 0.f;
  for (int p = beg + sub; p < last; p += 4) {
    float4 v = e4[p];
    s0 += v.x;
    s1 += v.y;
    s2 += v.z;
  }
  s0 += __shfl_xor(s0, 1);
  s1 += __shfl_xor(s1, 1);
  s2 += __shfl_xor(s2, 1);
  s0 += __shfl_xor(s0, 2);
  s1 += __shfl_xor(s1, 2);
  s2 += __shfl_xor(s2, 2);
  if (sub == 0) {
    float invc = 1.0f / fmaxf((float)(last - beg), 1.0f);
    float4 r;
    r.x = s0 * invc;
    r.y = s1 * invc;
    r.z = s2 * invc;
    r.w = __int_as_float(n * 256);
    e4[last] = r;
  }
}

// ---------------- fp32 -> bf16 converters ----------------

__global__ void k_convx(const float* __restrict__ x, unsigned short* __restrict__ xb, int n) {
  int i = (blockIdx.x * blockDim.x + threadIdx.x) * 4;
  if (i >= n) return;
  float4 v = *(const float4*)&x[i];
  ushort4 o;
  o.x = f2bf(v.x); o.y = f2bf(v.y); o.z = f2bf(v.z); o.w = f2bf(v.w);
  *(ushort4*)&xb[i] = o;
}

__global__ void k_convW(const float* __restrict__ w0, const float* __restrict__ w1,
                        const float* __restrict__ w2, const float* __restrict__ w3,
                        const float* __restrict__ w4, const float* __restrict__ w5,
                        unsigned short* __restrict__ dst) {
  const float* srcs[6] = {w0, w1, w2, w3, w4, w5};
  const float* s = srcs[blockIdx.y];
  int i = blockIdx.x * 256 + threadIdx.x;  // 0..16383
  dst[(size_t)blockIdx.y * 16384 + i] = f2bf(s[i]);
}

// ---------------- MFMA GEMM: out_bf16[n][j] = bf16(bias[j] + sum_k x[n][k]*W[j][k]) ----------------
__global__ __launch_bounds__(256) void k_gemm_mfma(const unsigned short* __restrict__ xb,
                                                   const unsigned short* __restrict__ Wb,
                                                   const float* __restrict__ bl, const float* __restrict__ br,
                                                   unsigned short* __restrict__ xlb,
                                                   unsigned short* __restrict__ xrb, int N) {
  int wave = threadIdx.x >> 6;
  int lane = threadIdx.x & 63;
  int which = blockIdx.y;
  const unsigned short* W = Wb + (size_t)which * 16384;
  const float* bias = which ? br : bl;
  unsigned short* out = which ? xrb : xlb;

  int row0 = (blockIdx.x * 4 + wave) * 16;
  if (row0 >= N) return;
  int m = lane & 15;
  int q = lane >> 4;

  int arow = row0 + m;
  if (arow >= N) arow = N - 1;
  const unsigned short* xrow = xb + (size_t)arow * 128 + q * 8;

  bf16x8 afrag[4];
#pragma unroll
  for (int kt = 0; kt < 4; ++kt) afrag[kt] = *(const bf16x8*)(xrow + kt * 32);

  f32x4 acc[8];
#pragma unroll
  for (int jt = 0; jt < 8; ++jt) acc[jt] = (f32x4){0.f, 0.f, 0.f, 0.f};

  const unsigned short* wbase = W + (size_t)m * 128 + q * 8;
#pragma unroll
  for (int kt = 0; kt < 4; ++kt) {
    bf16x8 a = afrag[kt];
#pragma unroll
    for (int jt = 0; jt < 8; ++jt) {
      bf16x8 b = *(const bf16x8*)(wbase + (size_t)jt * 16 * 128 + kt * 32);
      acc[jt] = __builtin_amdgcn_mfma_f32_16x16x32_bf16(a, b, acc[jt], 0, 0, 0);
    }
  }

#pragma unroll
  for (int jt = 0; jt < 8; ++jt) {
    float bs = bias[jt * 16 + m];
#pragma unroll
    for (int r = 0; r < 4; ++r) {
      int rr = row0 + q * 4 + r;
      if (rr < N) out[(size_t)rr * 128 + jt * 16 + m] = f2bf(acc[jt][r] + bs);
    }
  }
}

// ---------------- fused: score + softmax(exp2) + weighted agg + epilogue ----------------
// one wave per node; lanes 0-31 = edge p, lanes 32-63 = edge p+1 (same node);
// each lane owns 4 channels c = (lane&31)*4; head group = 8 lanes.
__global__ __launch_bounds__(256) void k_agg(const unsigned short* __restrict__ xlb,
                                             const unsigned short* __restrict__ xrb,
                                             const float4* __restrict__ e4,
                                             const int* __restrict__ offs,
                                             const float* __restrict__ We, const float* __restrict__ att,
                                             const float* __restrict__ bo,
                                             const float* __restrict__ lng, const float* __restrict__ lnb,
                                             unsigned short* __restrict__ xnext_bf,
                                             float* __restrict__ emb, int last, int N) {
  int w = (blockIdx.x * blockDim.x + threadIdx.x) >> 6;
  if (w >= N) return;
  int lane = threadIdx.x & 63;
  int half = lane >> 5;
  int sl = lane & 31;
  int c = sl * 4;
  unsigned int c2 = (unsigned int)(c * 2);  // byte offset into bf16 row
  int beg = offs[w], end = offs[w + 1];
  int cnt = end - beg;

  // per-lane params for 4 channels
  f32x4 xr4, wea, web, wec, at4;
  {
    uint2 vr = *(const uint2*)&xrb[(size_t)w * 128 + c];
    xr4[0] = __uint_as_float(vr.x << 16);
    xr4[1] = __uint_as_float(vr.x & 0xffff0000u);
    xr4[2] = __uint_as_float(vr.y << 16);
    xr4[3] = __uint_as_float(vr.y & 0xffff0000u);
#pragma unroll
    for (int j = 0; j < 4; ++j) {
      wea[j] = We[(c + j) * 3 + 0];
      web[j] = We[(c + j) * 3 + 1];
      wec[j] = We[(c + j) * 3 + 2];
      at4[j] = att[c + j] * LOG2E;  // fold ln->log2 into att
    }
  }

  const char* xlB = (const char*)xlb;
  const char* e4B = (const char*)e4;
  unsigned int lastoff = (unsigned int)(end - 1) << 4;
  unsigned int eoff = (unsigned int)(beg + half) << 4;
  if (eoff > lastoff) eoff = lastoff;  // cnt==1, half 1 clamps

  float l = 0.f;
  f32x4 acc = {0.f, 0.f, 0.f, 0.f};

  int T = (cnt + 1) >> 1;  // pair iterations
  float4 eC = *(const float4*)(e4B + eoff);

#pragma unroll 2
  for (int it = 0; it < T - 1; ++it) {
    unsigned int noff = eoff + 32u;
    if (noff > lastoff) noff = lastoff;
    float4 eN = *(const float4*)(e4B + noff);
    eoff = noff;

    unsigned int go = (unsigned int)__float_as_int(eC.w) + c2;
    uint2 v = *(const uint2*)(xlB + go);
    f32x4 xl4;
    xl4[0] = __uint_as_float(v.x << 16);
    xl4[1] = __uint_as_float(v.x & 0xffff0000u);
    xl4[2] = __uint_as_float(v.y << 16);
    xl4[3] = __uint_as_float(v.y & 0xffff0000u);

    f32x4 t = xr4 + wea * eC.x + web * eC.y + wec * eC.z + xl4;
    t[0] = fmaxf(t[0], 0.2f * t[0]);
    t[1] = fmaxf(t[1], 0.2f * t[1]);
    t[2] = fmaxf(t[2], 0.2f * t[2]);
    t[3] = fmaxf(t[3], 0.2f * t[3]);
    float s = t[0] * at4[0] + t[1] * at4[1] + t[2] * at4[2] + t[3] * at4[3];
    float wgt = __builtin_amdgcn_exp2f(dpp_sum8(s));
    l += wgt;
    acc += xl4 * wgt;
    eC = eN;
  }
  {  // peeled last pair with validity mask
    int idx = 2 * (T - 1) + half;
    unsigned int go = (unsigned int)__float_as_int(eC.w) + c2;
    uint2 v = *(const uint2*)(xlB + go);
    f32x4 xl4;
    xl4[0] = __uint_as_float(v.x << 16);
    xl4[1] = __uint_as_float(v.x & 0xffff0000u);
    xl4[2] = __uint_as_float(v.y << 16);
    xl4[3] = __uint_as_float(v.y & 0xffff0000u);
    f32x4 t = xr4 + wea * eC.x + web * eC.y + wec * eC.z + xl4;
    t[0] = fmaxf(t[0], 0.2f * t[0]);
    t[1] = fmaxf(t[1], 0.2f * t[1]);
    t[2] = fmaxf(t[2], 0.2f * t[2]);
    t[3] = fmaxf(t[3], 0.2f * t[3]);
    float s = t[0] * at4[0] + t[1] * at4[1] + t[2] * at4[2] + t[3] * at4[3];
    float wgt = __builtin_amdgcn_exp2f(dpp_sum8(s));
    if (idx >= cnt) wgt = 0.f;
    l += wgt;
    acc += xl4 * wgt;
  }

  // combine halves
  l += __shfl_xor(l, 32);
  acc[0] += __shfl_xor(acc[0], 32);
  acc[1] += __shfl_xor(acc[1], 32);
  acc[2] += __shfl_xor(acc[2], 32);
  acc[3] += __shfl_xor(acc[3], 32);

  float inv = 1.0f / l;
  f32x4 o;
  const float4 bo4 = *(const float4*)&bo[c];
  o[0] = acc[0] * inv + bo4.x;
  o[1] = acc[1] * inv + bo4.y;
  o[2] = acc[2] * inv + bo4.z;
  o[3] = acc[3] * inv + bo4.w;

  if (last) {
    if (half == 0) {
      float4 st = {o[0], o[1], o[2], o[3]};
      *(float4*)&emb[(size_t)w * 128 + c] = st;
    }
  } else {
    f32x4 r;
    r[0] = fmaxf(o[0], 0.f);
    r[1] = fmaxf(o[1], 0.f);
    r[2] = fmaxf(o[2], 0.f);
    r[3] = fmaxf(o[3], 0.f);
    float s = r[0] + r[1] + r[2] + r[3];
    s += __shfl_xor(s, 1);
    s += __shfl_xor(s, 2);
    s += __shfl_xor(s, 4);
    s += __shfl_xor(s, 8);
    s += __shfl_xor(s, 16);
    float mu = s * 0.0078125f;  // /128
    f32x4 d;
    d[0] = r[0] - mu;
    d[1] = r[1] - mu;
    d[2] = r[2] - mu;
    d[3] = r[3] - mu;
    float v2 = d[0] * d[0] + d[1] * d[1] + d[2] * d[2] + d[3] * d[3];
    v2 += __shfl_xor(v2, 1);
    v2 += __shfl_xor(v2, 2);
    v2 += __shfl_xor(v2, 4);
    v2 += __shfl_xor(v2, 8);
    v2 += __shfl_xor(v2, 16);
    float var = v2 * 0.0078125f;
    float rstd = rsqrtf(var + LN_EPS);
    if (half == 0) {
      const float4 g4 = *(const float4*)&lng[c];
      const float4 b4 = *(const float4*)&lnb[c];
      float o0 = d[0] * rstd * g4.x + b4.x;
      float o1 = d[1] * rstd * g4.y + b4.y;
      float o2 = d[2] * rstd * g4.z + b4.z;
      float o3 = d[3] * rstd * g4.w + b4.w;
      uint2 pack;
      pack.x = (unsigned int)f2bf(o0) | ((unsigned int)f2bf(o1) << 16);
      pack.y = (unsigned int)f2bf(o2) | ((unsigned int)f2bf(o3) << 16);
      *(uint2*)&xnext_bf[(size_t)w * 128 + c] = pack;
    }
  }
}

// ---------------- graph max-pool (relu implicit: atomicMax vs 0-init) ----------------
__global__ void k_pool(const float* __restrict__ emb, const int* __restrict__ batch,
                       float* __restrict__ pooled, int N) {
  int c = threadIdx.x & 127;
  int half = threadIdx.x >> 7;
  int base = blockIdx.x * 64 + half;
  int limit = min(blockIdx.x * 64 + 64, N);
  float cur = 0.f;
  int curg = -1;
  for (int n = base; n < limit; n += 2) {
    int g = batch[n];
    if (g != curg) {
      if (curg >= 0) atomicMax((unsigned int*)&pooled[curg * 128 + c], __float_as_uint(cur));
      curg = g;
      cur = 0.f;
    }
    cur = fmaxf(cur, emb[(size_t)n * 128 + c]);
  }
  if (curg >= 0) atomicMax((unsigned int*)&pooled[curg * 128 + c], __float_as_uint(cur));
}

// ---------------- MLP: 128 -> 32 -> 32 -> 32 -> 1 ----------------
__global__ void k_mlp(const float* __restrict__ pooled,
                      const float* __restrict__ pw1, const float* __restrict__ pb1,
                      const float* __restrict__ pw2, const float* __restrict__ pb2,
                      const float* __restrict__ pw3, const float* __restrict__ pb3,
                      const float* __restrict__ pw4, const float* __restrict__ pb4,
                      float* __restrict__ out) {
  int g = blockIdx.x;
  int t = threadIdx.x;  // 64 threads
  __shared__ float buf1[32], buf2[32];
  if (t < 32) {
    float acc = pb1[t];
    for (int k = 0; k < 128; ++k) acc += pw1[t * 128 + k] * pooled[g * 128 + k];
    buf1[t] = fmaxf(acc, 0.f);
  }
  __syncthreads();
  if (t < 32) {
    float acc = pb2[t];
    for (int k = 0; k < 32; ++k) acc += pw2[t * 32 + k] * buf1[k];
    buf2[t] = fmaxf(acc, 0.f);
  }
  __syncthreads();
  if (t < 32) {
    float acc = pb3[t];
    for (int k = 0; k < 32; ++k) acc += pw3[t * 32 + k] * buf2[k];
    buf1[t] = fmaxf(acc, 0.f);
  }
  __syncthreads();
  if (t == 0) {
    float acc = pb4[0];
    for (int k = 0; k < 32; ++k) acc += pw4[k] * buf1[k];
    out[g] = acc;
  }
}

// ---------------------------------------------------------------------------

extern "C" void kernel_launch(void* const* d_in, const int* in_sizes, int n_in,
                              void* d_out, int out_size, void* d_ws, size_t ws_size,
                              hipStream_t stream) {
  const float* x_in = (const float*)d_in[0];
  const int* ei = (const int*)d_in[1];
  const int* batch = (const int*)d_in[2];
  const float* ea = (const float*)d_in[3];

  const int N = in_sizes[0] / 128;
  const int E = in_sizes[1] / 2;
  const int EP = E + N;
  const int G = out_size - N * 128;
  const int NBUK = (N + 255) / 256;

  const float *Wl[3], *bl[3], *Wr[3], *br[3], *We[3], *att[3], *bo[3];
  for (int l = 0; l < 3; ++l) {
    Wl[l] = (const float*)d_in[4 + 7 * l];
    bl[l] = (const float*)d_in[5 + 7 * l];
    Wr[l] = (const float*)d_in[6 + 7 * l];
    br[l] = (const float*)d_in[7 + 7 * l];
    We[l] = (const float*)d_in[8 + 7 * l];
    att[l] = (const float*)d_in[9 + 7 * l];
    bo[l] = (const float*)d_in[10 + 7 * l];
  }
  const float* lng[2] = {(const float*)d_in[25], (const float*)d_in[27]};
  const float* lnb[2] = {(const float*)d_in[26], (const float*)d_in[28]};
  const float* pw1 = (const float*)d_in[29];
  const float* pb1 = (const float*)d_in[30];
  const float* pw2 = (const float*)d_in[31];
  const float* pb2 = (const float*)d_in[32];
  const float* pw3 = (const float*)d_in[33];
  const float* pb3 = (const float*)d_in[34];
  const float* pw4 = (const float*)d_in[35];
  const float* pb4 = (const float*)d_in[36];

  char* base = (char*)d_ws;
  size_t cur = 0;
  auto carve = [&](size_t bytes) -> char* {
    char* p = base + cur;
    cur += (bytes + 255) & ~(size_t)255;
    return p;
  };
  unsigned short* xlb = (unsigned short*)carve((size_t)N * 128 * 2);
  unsigned short* xrb = (unsigned short*)carve((size_t)N * 128 * 2);
  unsigned short* xb = (unsigned short*)carve((size_t)N * 128 * 2);  // bf16 activations
  unsigned short* Wb = (unsigned short*)carve((size_t)6 * 16384 * 2);
  float4* e4 = (float4*)carve((size_t)EP * 16);
  float4* staged = (float4*)carve((size_t)EP * 16);
  int* offs = (int*)carve((size_t)(N + 1) * 4);
  int* cnt = (int*)carve((size_t)N * 4);
  int* gcur = (int*)carve((size_t)(NBUK + 1) * 4);
  int* bsum = (int*)carve(1024);
  float* pooled = (float*)carve((size_t)G * 128 * 4);

  float* emb_out = (float*)d_out;
  float* mlp_out = (float*)d_out + (size_t)N * 128;

  const int NB = (N + 255) / 256;

  hipMemsetAsync(cnt, 0, (size_t)N * 4, stream);
  hipMemsetAsync(pooled, 0, (size_t)G * 128 * 4, stream);

  k_degree<<<(E / 4 + 255) / 256, 256, 0, stream>>>(ei, cnt, E);
  k_scan1<<<NB, 256, 0, stream>>>(cnt, bsum, N);
  k_scan2<<<1, 256, 0, stream>>>(bsum, offs, NB, EP, N);
  k_scan3<<<NB, 256, 0, stream>>>(cnt, bsum, offs, N);
  k_initcur<<<1, 256, 0, stream>>>(offs, gcur, NBUK);
  k_binA<<<(E + CHUNK - 1) / CHUNK, 256, 0, stream>>>(ei, ea, gcur, staged, E, NBUK);
  k_binB<<<NBUK, 256, 0, stream>>>(staged, offs, e4, N);
  k_selfloop<<<(N * 4 + 255) / 256, 256, 0, stream>>>(offs, e4, N);

  k_convx<<<(N * 128 / 4 + 255) / 256, 256, 0, stream>>>(x_in, xb, N * 128);
  {
    dim3 g(64, 6);
    k_convW<<<g, 256, 0, stream>>>(Wl[0], Wr[0], Wl[1], Wr[1], Wl[2], Wr[2], Wb);
  }

  for (int l = 0; l < 3; ++l) {
    dim3 ggrid((N + 63) / 64, 2);
    k_gemm_mfma<<<ggrid, 256, 0, stream>>>(xb, Wb + (size_t)l * 32768, bl[l], br[l], xlb, xrb, N);
    int last = (l == 2) ? 1 : 0;
    const float* g = last ? bo[l] : lng[l];
    const float* b = last ? bo[l] : lnb[l];
    k_agg<<<(N * 64 + 255) / 256, 256, 0, stream>>>(xlb, xrb, e4, offs,
                                                    We[l], att[l], bo[l], g, b,
                                                    xb, emb_out, last, N);
  }

  k_pool<<<(N + 63) / 64, 256, 0, stream>>>(emb_out, batch, pooled, N);
  k_mlp<<<G, 64, 0, stream>>>(pooled, pw1, pb1, pw2, pb2, pw3, pb3, pw4, pb4, mlp_out);
}

// Round 8
// 529.060 us; speedup vs baseline: 2.4419x; 1.0022x over previous
//
#include <hip/hip_runtime.h>
#include <math.h>

// ---------------------------------------------------------------------------
// GATv2 x3 + LN + graph max-pool + MLP.
// Round 8: (a) degree/scan chain deleted -- binA stages into fixed-capacity
// bucket regions while counting; k_bscan (1 block) scans 196 bucket totals;
// k_binB builds per-node hist + scan in LDS, emits offs, places records, and
// does self-loop means in-block. (b) k_agg quad-edge layout: 4 edges/wave,
// 16 lanes/edge, 8 ch/lane, dwordx4 gathers, 2-step quad-DPP reduction.
// ---------------------------------------------------------------------------

#define LN_EPS 1e-5f
#define LOG2E 1.44269504088896340736f
#define CHUNK 4096
#define BCAP 8192  // records per staging bucket (avg 4096, sigma ~64)

typedef short bf16x8 __attribute__((ext_vector_type(8)));
typedef float f32x4 __attribute__((ext_vector_type(4)));

static __device__ __forceinline__ unsigned short f2bf(float f) {
  unsigned int u = __float_as_uint(f);
  u += 0x7fffu + ((u >> 16) & 1u);  // RNE
  return (unsigned short)(u >> 16);
}

// sum+broadcast over each 4-lane quad: quad xor1, quad xor2
static __device__ __forceinline__ float dpp_sum4(float v) {
  int x;
  x = __builtin_amdgcn_update_dpp(0, __float_as_int(v), 0x0B1, 0xf, 0xf, true);  // quad_perm 1,0,3,2
  v += __int_as_float(x);
  x = __builtin_amdgcn_update_dpp(0, __float_as_int(v), 0x04E, 0xf, 0xf, true);  // quad_perm 2,3,0,1
  v += __int_as_float(x);
  return v;
}

// ---------------- binned CSR build ----------------

// Phase A: stage edges into bucket b = dst>>8 region [b*BCAP ...), counting in
// gcnt[b].  Record: {ea0,ea1,ea2, src|dst<<16}.
__global__ __launch_bounds__(256) void k_binA(const int* __restrict__ ei, const float* __restrict__ ea,
                                              int* __restrict__ gcnt, float4* __restrict__ staged,
                                              int E, int nbuk) {
  __shared__ int hist[256];
  __shared__ int basebuf[256];
  int t = threadIdx.x;
  int e0 = blockIdx.x * CHUNK;

  hist[t] = 0;
  __syncthreads();
#pragma unroll
  for (int i = 0; i < CHUNK / 256; ++i) {
    int e = e0 + i * 256 + t;
    if (e < E) atomicAdd(&hist[ei[E + e] >> 8], 1);
  }
  __syncthreads();
  int h = hist[t];
  if (t < nbuk && h > 0) basebuf[t] = t * BCAP + atomicAdd(&gcnt[t], h);
  hist[t] = 0;
  __syncthreads();
#pragma unroll
  for (int i = 0; i < CHUNK / 256; ++i) {
    int e = e0 + i * 256 + t;
    if (e < E) {
      int s = ei[e];
      int d = ei[E + e];
      int b = d >> 8;
      int r = atomicAdd(&hist[b], 1);
      float4 rec;
      rec.x = ea[e * 3 + 0];
      rec.y = ea[e * 3 + 1];
      rec.z = ea[e * 3 + 2];
      rec.w = __int_as_float(s | (d << 16));
      staged[basebuf[b] + r] = rec;
    }
  }
}

// exclusive scan over bucket totals (real edges + self-loops) -> bukStart
__global__ void k_bscan(const int* __restrict__ gcnt, int* __restrict__ bukStart,
                        int* __restrict__ offs, int N, int nbuk, int EP) {
  __shared__ int sh[256];
  int t = threadIdx.x;
  int nodes = (t < nbuk) ? min(256, N - t * 256) : 0;
  int v = (t < nbuk) ? gcnt[t] + nodes : 0;
  sh[t] = v;
  __syncthreads();
  for (int d = 1; d < 256; d <<= 1) {
    int add = (t >= d) ? sh[t - d] : 0;
    __syncthreads();
    sh[t] += add;
    __syncthreads();
  }
  if (t < nbuk) bukStart[t] = sh[t] - v;
  if (t == 0) offs[N] = EP;
}

// Phase B: per bucket -- LDS node-hist + scan -> offs; place records at final
// slots; compute self-loop means in-block (data L2-hot).
__global__ __launch_bounds__(256) void k_binB(const float4* __restrict__ staged,
                                              const int* __restrict__ gcnt,
                                              const int* __restrict__ bukStart,
                                              float4* __restrict__ e4,
                                              int* __restrict__ offs, int N) {
  __shared__ int hist[256], cur[256], begS[256], sh[256];
  int t = threadIdx.x;
  int b = blockIdx.x;
  int n0 = b * 256;
  int nn = min(256, N - n0);
  int m = gcnt[b];
  size_t sbase = (size_t)b * BCAP;

  hist[t] = 0;
  __syncthreads();
  for (int p = t; p < m; p += 256) {
    unsigned int u = (unsigned int)__float_as_int(staged[sbase + p].w);
    atomicAdd(&hist[(int)(u >> 16) - n0], 1);
  }
  __syncthreads();
  int v = (t < nn) ? hist[t] + 1 : 0;
  sh[t] = v;
  __syncthreads();
  for (int d = 1; d < 256; d <<= 1) {
    int add = (t >= d) ? sh[t - d] : 0;
    __syncthreads();
    sh[t] += add;
    __syncthreads();
  }
  if (t < nn) {
    int base = bukStart[b] + sh[t] - v;
    cur[t] = base;
    begS[t] = base;
    offs[n0 + t] = base;
  }
  __syncthreads();
  for (int p = t; p < m; p += 256) {
    float4 rec = staged[sbase + p];
    unsigned int u = (unsigned int)__float_as_int(rec.w);
    int pos = atomicAdd(&cur[(int)(u >> 16) - n0], 1);
    rec.w = __int_as_float((int)(u & 0xffffu) * 256);
    e4[pos] = rec;
  }
  __syncthreads();
  if (t < nn) {
    int beg = begS[t], last = cur[t];  // cur == self-loop slot after placement
    float s0 = 0.f, s1 = 0.f, s2 = 0.f;
    for (int p = beg; p < last; ++p) {
      float4 r = e4[p];
      s0 += r.x;
      s1 += r.y;
      s2 += r.z;
    }
    float invc = 1.0f / fmaxf((float)(last - beg), 1.0f);
    float4 r;
    r.x = s0 * invc;
    r.y = s1 * invc;
    r.z = s2 * invc;
    r.w = __int_as_float((n0 + t) * 256);
    e4[last] = r;
  }
}

// ---------------- fp32 -> bf16 converters ----------------

__global__ void k_convx(const float* __restrict__ x, unsigned short* __restrict__ xb, int n) {
  int i = (blockIdx.x * blockDim.x + threadIdx.x) * 4;
  if (i >= n) return;
  float4 v = *(const float4*)&x[i];
  ushort4 o;
  o.x = f2bf(v.x); o.y = f2bf(v.y); o.z = f2bf(v.z); o.w = f2bf(v.w);
  *(ushort4*)&xb[i] = o;
}

__global__ void k_convW(const float* __restrict__ w0, const float* __restrict__ w1,
                        const float* __restrict__ w2, const float* __restrict__ w3,
                        const float* __restrict__ w4, const float* __restrict__ w5,
                        unsigned short* __restrict__ dst) {
  const float* srcs[6] = {w0, w1, w2, w3, w4, w5};
  const float* s = srcs[blockIdx.y];
  int i = blockIdx.x * 256 + threadIdx.x;  // 0..16383
  dst[(size_t)blockIdx.y * 16384 + i] = f2bf(s[i]);
}

// ---------------- MFMA GEMM: out_bf16[n][j] = bf16(bias[j] + sum_k x[n][k]*W[j][k]) ----------------
__global__ __launch_bounds__(256) void k_gemm_mfma(const unsigned short* __restrict__ xb,
                                                   const unsigned short* __restrict__ Wb,
                                                   const float* __restrict__ bl, const float* __restrict__ br,
                                                   unsigned short* __restrict__ xlb,
                                                   unsigned short* __restrict__ xrb, int N) {
  int wave = threadIdx.x >> 6;
  int lane = threadIdx.x & 63;
  int which = blockIdx.y;
  const unsigned short* W = Wb + (size_t)which * 16384;
  const float* bias = which ? br : bl;
  unsigned short* out = which ? xrb : xlb;

  int row0 = (blockIdx.x * 4 + wave) * 16;
  if (row0 >= N) return;
  int m = lane & 15;
  int q = lane >> 4;

  int arow = row0 + m;
  if (arow >= N) arow = N - 1;
  const unsigned short* xrow = xb + (size_t)arow * 128 + q * 8;

  bf16x8 afrag[4];
#pragma unroll
  for (int kt = 0; kt < 4; ++kt) afrag[kt] = *(const bf16x8*)(xrow + kt * 32);

  f32x4 acc[8];
#pragma unroll
  for (int jt = 0; jt < 8; ++jt) acc[jt] = (f32x4){0.f, 0.f, 0.f, 0.f};

  const unsigned short* wbase = W + (size_t)m * 128 + q * 8;
#pragma unroll
  for (int kt = 0; kt < 4; ++kt) {
    bf16x8 a = afrag[kt];
#pragma unroll
    for (int jt = 0; jt < 8; ++jt) {
      bf16x8 b = *(const bf16x8*)(wbase + (size_t)jt * 16 * 128 + kt * 32);
      acc[jt] = __builtin_amdgcn_mfma_f32_16x16x32_bf16(a, b, acc[jt], 0, 0, 0);
    }
  }

#pragma unroll
  for (int jt = 0; jt < 8; ++jt) {
    float bs = bias[jt * 16 + m];
#pragma unroll
    for (int r = 0; r < 4; ++r) {
      int rr = row0 + q * 4 + r;
      if (rr < N) out[(size_t)rr * 128 + jt * 16 + m] = f2bf(acc[jt][r] + bs);
    }
  }
}

// ---------------- fused: score + softmax(exp2) + weighted agg + epilogue ----------------
// one wave per node; 4 edges in flight: grp = lane>>4 owns edge 4*it+grp;
// sl = lane&15 owns channels 8*sl..8*sl+7 (dwordx4 gather). Head = 32 ch =
// one 4-lane quad -> dpp_sum4 reduction.
__global__ __launch_bounds__(256) void k_agg(const unsigned short* __restrict__ xlb,
                                             const unsigned short* __restrict__ xrb,
                                             const float4* __restrict__ e4,
                                             const int* __restrict__ offs,
                                             const float* __restrict__ We, const float* __restrict__ att,
                                             const float* __restrict__ bo,
                                             const float* __restrict__ lng, const float* __restrict__ lnb,
                                             unsigned short* __restrict__ xnext_bf,
                                             float* __restrict__ emb, int last, int N) {
  int w = (blockIdx.x * blockDim.x + threadIdx.x) >> 6;
  if (w >= N) return;
  int lane = threadIdx.x & 63;
  int grp = lane >> 4;
  int sl = lane & 15;
  int c = sl * 8;
  unsigned int c2 = (unsigned int)(c * 2);  // byte offset into bf16 row
  int beg = offs[w], end = offs[w + 1];
  int cnt = end - beg;

  float xr8[8];
  {
    uint4 vr = *(const uint4*)&xrb[(size_t)w * 128 + c];
    xr8[0] = __uint_as_float(vr.x << 16);
    xr8[1] = __uint_as_float(vr.x & 0xffff0000u);
    xr8[2] = __uint_as_float(vr.y << 16);
    xr8[3] = __uint_as_float(vr.y & 0xffff0000u);
    xr8[4] = __uint_as_float(vr.z << 16);
    xr8[5] = __uint_as_float(vr.z & 0xffff0000u);
    xr8[6] = __uint_as_float(vr.w << 16);
    xr8[7] = __uint_as_float(vr.w & 0xffff0000u);
  }
  float wea[8], web[8], wec[8], at8[8];
  {
    const float* Wep = We + c * 3;
#pragma unroll
    for (int j = 0; j < 8; ++j) {
      wea[j] = Wep[j * 3 + 0];
      web[j] = Wep[j * 3 + 1];
      wec[j] = Wep[j * 3 + 2];
      at8[j] = att[c + j] * LOG2E;  // fold ln->log2 into att
    }
  }

  const char* xlB = (const char*)xlb;
  const char* e4B = (const char*)e4;
  unsigned int lastoff = (unsigned int)(end - 1) << 4;
  unsigned int eoff = (unsigned int)(beg + grp) << 4;
  if (eoff > lastoff) eoff = lastoff;

  float l = 0.f;
  float acc[8] = {0.f, 0.f, 0.f, 0.f, 0.f, 0.f, 0.f, 0.f};

  int T = (cnt + 3) >> 2;  // quad iterations
  float4 eC = *(const float4*)(e4B + eoff);

  for (int it = 0; it < T - 1; ++it) {
    unsigned int noff = eoff + 64u;
    if (noff > lastoff) noff = lastoff;
    float4 eN = *(const float4*)(e4B + noff);
    eoff = noff;

    unsigned int go = (unsigned int)__float_as_int(eC.w) + c2;
    uint4 v = *(const uint4*)(xlB + go);
    float xl8[8];
    xl8[0] = __uint_as_float(v.x << 16);
    xl8[1] = __uint_as_float(v.x & 0xffff0000u);
    xl8[2] = __uint_as_float(v.y << 16);
    xl8[3] = __uint_as_float(v.y & 0xffff0000u);
    xl8[4] = __uint_as_float(v.z << 16);
    xl8[5] = __uint_as_float(v.z & 0xffff0000u);
    xl8[6] = __uint_as_float(v.w << 16);
    xl8[7] = __uint_as_float(v.w & 0xffff0000u);

    float s = 0.f;
#pragma unroll
    for (int j = 0; j < 8; ++j) {
      float tmp = fmaf(wea[j], eC.x, fmaf(web[j], eC.y, fmaf(wec[j], eC.z, xr8[j]))) + xl8[j];
      tmp = fmaxf(tmp, 0.2f * tmp);
      s = fmaf(tmp, at8[j], s);
    }
    float wgt = __builtin_amdgcn_exp2f(dpp_sum4(s));
    l += wgt;
#pragma unroll
    for (int j = 0; j < 8; ++j) acc[j] = fmaf(wgt, xl8[j], acc[j]);
    eC = eN;
  }
  {  // peeled last quad with validity mask
    int idx = 4 * (T - 1) + grp;
    unsigned int go = (unsigned int)__float_as_int(eC.w) + c2;
    uint4 v = *(const uint4*)(xlB + go);
    float xl8[8];
    xl8[0] = __uint_as_float(v.x << 16);
    xl8[1] = __uint_as_float(v.x & 0xffff0000u);
    xl8[2] = __uint_as_float(v.y << 16);
    xl8[3] = __uint_as_float(v.y & 0xffff0000u);
    xl8[4] = __uint_as_float(v.z << 16);
    xl8[5] = __uint_as_float(v.z & 0xffff0000u);
    xl8[6] = __uint_as_float(v.w << 16);
    xl8[7] = __uint_as_float(v.w & 0xffff0000u);
    float s = 0.f;
#pragma unroll
    for (int j = 0; j < 8; ++j) {
      float tmp = fmaf(wea[j], eC.x, fmaf(web[j], eC.y, fmaf(wec[j], eC.z, xr8[j]))) + xl8[j];
      tmp = fmaxf(tmp, 0.2f * tmp);
      s = fmaf(tmp, at8[j], s);
    }
    float wgt = __builtin_amdgcn_exp2f(dpp_sum4(s));
    if (idx >= cnt) wgt = 0.f;
    l += wgt;
#pragma unroll
    for (int j = 0; j < 8; ++j) acc[j] = fmaf(wgt, xl8[j], acc[j]);
  }

  // combine the 4 edge groups
  l += __shfl_xor(l, 16);
  l += __shfl_xor(l, 32);
#pragma unroll
  for (int j = 0; j < 8; ++j) {
    acc[j] += __shfl_xor(acc[j], 16);
    acc[j] += __shfl_xor(acc[j], 32);
  }

  float inv = 1.0f / l;
  float o[8];
  {
    const float4 b0 = *(const float4*)&bo[c];
    const float4 b1 = *(const float4*)&bo[c + 4];
    o[0] = acc[0] * inv + b0.x;
    o[1] = acc[1] * inv + b0.y;
    o[2] = acc[2] * inv + b0.z;
    o[3] = acc[3] * inv + b0.w;
    o[4] = acc[4] * inv + b1.x;
    o[5] = acc[5] * inv + b1.y;
    o[6] = acc[6] * inv + b1.z;
    o[7] = acc[7] * inv + b1.w;
  }

  if (last) {
    if (grp == 0) {
      float4 s0 = {o[0], o[1], o[2], o[3]};
      float4 s1 = {o[4], o[5], o[6], o[7]};
      *(float4*)&emb[(size_t)w * 128 + c] = s0;
      *(float4*)&emb[(size_t)w * 128 + c + 4] = s1;
    }
  } else {
    float r[8];
#pragma unroll
    for (int j = 0; j < 8; ++j) r[j] = fmaxf(o[j], 0.f);
    float s = r[0] + r[1] + r[2] + r[3] + r[4] + r[5] + r[6] + r[7];
    s += __shfl_xor(s, 1);
    s += __shfl_xor(s, 2);
    s += __shfl_xor(s, 4);
    s += __shfl_xor(s, 8);
    float mu = s * 0.0078125f;  // /128
    float d[8];
    float v2 = 0.f;
#pragma unroll
    for (int j = 0; j < 8; ++j) {
      d[j] = r[j] - mu;
      v2 = fmaf(d[j], d[j], v2);
    }
    v2 += __shfl_xor(v2, 1);
    v2 += __shfl_xor(v2, 2);
    v2 += __shfl_xor(v2, 4);
    v2 += __shfl_xor(v2, 8);
    float var = v2 * 0.0078125f;
    float rstd = rsqrtf(var + LN_EPS);
    if (grp == 0) {
      const float4 g0 = *(const float4*)&lng[c];
      const float4 g1 = *(const float4*)&lng[c + 4];
      const float4 b0 = *(const float4*)&lnb[c];
      const float4 b1 = *(const float4*)&lnb[c + 4];
      float q0 = d[0] * rstd * g0.x + b0.x;
      float q1 = d[1] * rstd * g0.y + b0.y;
      float q2 = d[2] * rstd * g0.z + b0.z;
      float q3 = d[3] * rstd * g0.w + b0.w;
      float q4 = d[4] * rstd * g1.x + b1.x;
      float q5 = d[5] * rstd * g1.y + b1.y;
      float q6 = d[6] * rstd * g1.z + b1.z;
      float q7 = d[7] * rstd * g1.w + b1.w;
      uint4 pack;
      pack.x = (unsigned int)f2bf(q0) | ((unsigned int)f2bf(q1) << 16);
      pack.y = (unsigned int)f2bf(q2) | ((unsigned int)f2bf(q3) << 16);
      pack.z = (unsigned int)f2bf(q4) | ((unsigned int)f2bf(q5) << 16);
      pack.w = (unsigned int)f2bf(q6) | ((unsigned int)f2bf(q7) << 16);
      *(uint4*)&xnext_bf[(size_t)w * 128 + c] = pack;
    }
  }
}

// ---------------- graph max-pool (relu implicit: atomicMax vs 0-init) ----------------
__global__ void k_pool(const float* __restrict__ emb, const int* __restrict__ batch,
                       float* __restrict__ pooled, int N) {
  int c = threadIdx.x & 127;
  int half = threadIdx.x >> 7;
  int base = blockIdx.x * 64 + half;
  int limit = min(blockIdx.x * 64 + 64, N);
  float cur = 0.f;
  int curg = -1;
  for (int n = base; n < limit; n += 2) {
    int g = batch[n];
    if (g != curg) {
      if (curg >= 0) atomicMax((unsigned int*)&pooled[curg * 128 + c], __float_as_uint(cur));
      curg = g;
      cur = 0.f;
    }
    cur = fmaxf(cur, emb[(size_t)n * 128 + c]);
  }
  if (curg >= 0) atomicMax((unsigned int*)&pooled[curg * 128 + c], __float_as_uint(cur));
}

// ---------------- MLP: 128 -> 32 -> 32 -> 32 -> 1 ----------------
__global__ void k_mlp(const float* __restrict__ pooled,
                      const float* __restrict__ pw1, const float* __restrict__ pb1,
                      const float* __restrict__ pw2, const float* __restrict__ pb2,
                      const float* __restrict__ pw3, const float* __restrict__ pb3,
                      const float* __restrict__ pw4, const float* __restrict__ pb4,
                      float* __restrict__ out) {
  int g = blockIdx.x;
  int t = threadIdx.x;  // 64 threads
  __shared__ float buf1[32], buf2[32];
  if (t < 32) {
    float acc = pb1[t];
    for (int k = 0; k < 128; ++k) acc += pw1[t * 128 + k] * pooled[g * 128 + k];
    buf1[t] = fmaxf(acc, 0.f);
  }
  __syncthreads();
  if (t < 32) {
    float acc = pb2[t];
    for (int k = 0; k < 32; ++k) acc += pw2[t * 32 + k] * buf1[k];
    buf2[t] = fmaxf(acc, 0.f);
  }
  __syncthreads();
  if (t < 32) {
    float acc = pb3[t];
    for (int k = 0; k < 32; ++k) acc += pw3[t * 32 + k] * buf2[k];
    buf1[t] = fmaxf(acc, 0.f);
  }
  __syncthreads();
  if (t == 0) {
    float acc = pb4[0];
    for (int k = 0; k < 32; ++k) acc += pw4[k] * buf1[k];
    out[g] = acc;
  }
}

// ---------------------------------------------------------------------------

extern "C" void kernel_launch(void* const* d_in, const int* in_sizes, int n_in,
                              void* d_out, int out_size, void* d_ws, size_t ws_size,
                              hipStream_t stream) {
  const float* x_in = (const float*)d_in[0];
  const int* ei = (const int*)d_in[1];
  const int* batch = (const int*)d_in[2];
  const float* ea = (const float*)d_in[3];

  const int N = in_sizes[0] / 128;
  const int E = in_sizes[1] / 2;
  const int EP = E + N;
  const int G = out_size - N * 128;
  const int NBUK = (N + 255) / 256;

  const float *Wl[3], *bl[3], *Wr[3], *br[3], *We[3], *att[3], *bo[3];
  for (int l = 0; l < 3; ++l) {
    Wl[l] = (const float*)d_in[4 + 7 * l];
    bl[l] = (const float*)d_in[5 + 7 * l];
    Wr[l] = (const float*)d_in[6 + 7 * l];
    br[l] = (const float*)d_in[7 + 7 * l];
    We[l] = (const float*)d_in[8 + 7 * l];
    att[l] = (const float*)d_in[9 + 7 * l];
    bo[l] = (const float*)d_in[10 + 7 * l];
  }
  const float* lng[2] = {(const float*)d_in[25], (const float*)d_in[27]};
  const float* lnb[2] = {(const float*)d_in[26], (const float*)d_in[28]};
  const float* pw1 = (const float*)d_in[29];
  const float* pb1 = (const float*)d_in[30];
  const float* pw2 = (const float*)d_in[31];
  const float* pb2 = (const float*)d_in[32];
  const float* pw3 = (const float*)d_in[33];
  const float* pb3 = (const float*)d_in[34];
  const float* pw4 = (const float*)d_in[35];
  const float* pb4 = (const float*)d_in[36];

  char* base = (char*)d_ws;
  size_t cur = 0;
  auto carve = [&](size_t bytes) -> char* {
    char* p = base + cur;
    cur += (bytes + 255) & ~(size_t)255;
    return p;
  };
  unsigned short* xlb = (unsigned short*)carve((size_t)N * 128 * 2);
  unsigned short* xrb = (unsigned short*)carve((size_t)N * 128 * 2);
  unsigned short* xb = (unsigned short*)carve((size_t)N * 128 * 2);  // bf16 activations
  unsigned short* Wb = (unsigned short*)carve((size_t)6 * 16384 * 2);
  float4* e4 = (float4*)carve((size_t)EP * 16);
  float4* staged = (float4*)carve((size_t)NBUK * BCAP * 16);
  int* offs = (int*)carve((size_t)(N + 1) * 4);
  int* gcnt = (int*)carve((size_t)NBUK * 4);
  int* bukStart = (int*)carve((size_t)(NBUK + 1) * 4);
  float* pooled = (float*)carve((size_t)G * 128 * 4);

  float* emb_out = (float*)d_out;
  float* mlp_out = (float*)d_out + (size_t)N * 128;

  hipMemsetAsync(gcnt, 0, (size_t)NBUK * 4, stream);
  hipMemsetAsync(pooled, 0, (size_t)G * 128 * 4, stream);

  k_binA<<<(E + CHUNK - 1) / CHUNK, 256, 0, stream>>>(ei, ea, gcnt, staged, E, NBUK);
  k_bscan<<<1, 256, 0, stream>>>(gcnt, bukStart, offs, N, NBUK, EP);
  k_binB<<<NBUK, 256, 0, stream>>>(staged, gcnt, bukStart, e4, offs, N);

  k_convx<<<(N * 128 / 4 + 255) / 256, 256, 0, stream>>>(x_in, xb, N * 128);
  {
    dim3 g(64, 6);
    k_convW<<<g, 256, 0, stream>>>(Wl[0], Wr[0], Wl[1], Wr[1], Wl[2], Wr[2], Wb);
  }

  for (int l = 0; l < 3; ++l) {
    dim3 ggrid((N + 63) / 64, 2);
    k_gemm_mfma<<<ggrid, 256, 0, stream>>>(xb, Wb + (size_t)l * 32768, bl[l], br[l], xlb, xrb, N);
    int last = (l == 2) ? 1 : 0;
    const float* g = last ? bo[l] : lng[l];
    const float* b = last ? bo[l] : lnb[l];
    k_agg<<<(N * 64 + 255) / 256, 256, 0, stream>>>(xlb, xrb, e4, offs,
                                                    We[l], att[l], bo[l], g, b,
                                                    xb, emb_out, last, N);
  }

  k_pool<<<(N + 63) / 64, 256, 0, stream>>>(emb_out, batch, pooled, N);
  k_mlp<<<G, 64, 0, stream>>>(pooled, pw1, pb1, pw2, pb2, pw3, pb3, pw4, pb4, mlp_out);
}

// Round 9
// 501.389 us; speedup vs baseline: 2.5767x; 1.0552x over previous
//
#include <hip/hip_runtime.h>
#include <math.h>

// ---------------------------------------------------------------------------
// GATv2 x3 + LN + graph max-pool + MLP.
// Round 9: (a) k_agg reverted to R7 half-wave (2 edges/wave, 4 ch/lane) --
// the R8 quad-edge layout spilled (VGPR 40 vs ~56 needed) and regressed;
// score params pre-packed per-lane (k_pack) -> 4 dwordx4 prologue loads.
// (b) GEMM operand swap: A=W, B=x => D row=channel, col=node; epilogue
// packs 4 contiguous channels -> 8 dwordx2 stores/wave vs 32 scalar shorts.
// Prepass: R8 binned CSR build (binA/bscan/binB) kept.
// ---------------------------------------------------------------------------

#define LN_EPS 1e-5f
#define LOG2E 1.44269504088896340736f
#define CHUNK 4096
#define BCAP 8192  // records per staging bucket (avg 4096)

typedef short bf16x8 __attribute__((ext_vector_type(8)));
typedef float f32x4 __attribute__((ext_vector_type(4)));

static __device__ __forceinline__ unsigned short f2bf(float f) {
  unsigned int u = __float_as_uint(f);
  u += 0x7fffu + ((u >> 16) & 1u);  // RNE
  return (unsigned short)(u >> 16);
}

// sum+broadcast over each 8-lane group: quad xor1, quad xor2, row_half_mirror
static __device__ __forceinline__ float dpp_sum8(float v) {
  int x;
  x = __builtin_amdgcn_update_dpp(0, __float_as_int(v), 0x0B1, 0xf, 0xf, true);  // quad_perm 1,0,3,2
  v += __int_as_float(x);
  x = __builtin_amdgcn_update_dpp(0, __float_as_int(v), 0x04E, 0xf, 0xf, true);  // quad_perm 2,3,0,1
  v += __int_as_float(x);
  x = __builtin_amdgcn_update_dpp(0, __float_as_int(v), 0x141, 0xf, 0xf, true);  // row_half_mirror
  v += __int_as_float(x);
  return v;
}

// ---------------- binned CSR build ----------------

__global__ __launch_bounds__(256) void k_binA(const int* __restrict__ ei, const float* __restrict__ ea,
                                              int* __restrict__ gcnt, float4* __restrict__ staged,
                                              int E, int nbuk) {
  __shared__ int hist[256];
  __shared__ int basebuf[256];
  int t = threadIdx.x;
  int e0 = blockIdx.x * CHUNK;

  hist[t] = 0;
  __syncthreads();
#pragma unroll
  for (int i = 0; i < CHUNK / 256; ++i) {
    int e = e0 + i * 256 + t;
    if (e < E) atomicAdd(&hist[ei[E + e] >> 8], 1);
  }
  __syncthreads();
  int h = hist[t];
  if (t < nbuk && h > 0) basebuf[t] = t * BCAP + atomicAdd(&gcnt[t], h);
  hist[t] = 0;
  __syncthreads();
#pragma unroll
  for (int i = 0; i < CHUNK / 256; ++i) {
    int e = e0 + i * 256 + t;
    if (e < E) {
      int s = ei[e];
      int d = ei[E + e];
      int b = d >> 8;
      int r = atomicAdd(&hist[b], 1);
      float4 rec;
      rec.x = ea[e * 3 + 0];
      rec.y = ea[e * 3 + 1];
      rec.z = ea[e * 3 + 2];
      rec.w = __int_as_float(s | (d << 16));
      staged[basebuf[b] + r] = rec;
    }
  }
}

__global__ void k_bscan(const int* __restrict__ gcnt, int* __restrict__ bukStart,
                        int* __restrict__ offs, int N, int nbuk, int EP) {
  __shared__ int sh[256];
  int t = threadIdx.x;
  int nodes = (t < nbuk) ? min(256, N - t * 256) : 0;
  int v = (t < nbuk) ? gcnt[t] + nodes : 0;
  sh[t] = v;
  __syncthreads();
  for (int d = 1; d < 256; d <<= 1) {
    int add = (t >= d) ? sh[t - d] : 0;
    __syncthreads();
    sh[t] += add;
    __syncthreads();
  }
  if (t < nbuk) bukStart[t] = sh[t] - v;
  if (t == 0) offs[N] = EP;
}

__global__ __launch_bounds__(256) void k_binB(const float4* __restrict__ staged,
                                              const int* __restrict__ gcnt,
                                              const int* __restrict__ bukStart,
                                              float4* __restrict__ e4,
                                              int* __restrict__ offs, int N) {
  __shared__ int hist[256], cur[256], begS[256], sh[256];
  int t = threadIdx.x;
  int b = blockIdx.x;
  int n0 = b * 256;
  int nn = min(256, N - n0);
  int m = gcnt[b];
  size_t sbase = (size_t)b * BCAP;

  hist[t] = 0;
  __syncthreads();
  for (int p = t; p < m; p += 256) {
    unsigned int u = (unsigned int)__float_as_int(staged[sbase + p].w);
    atomicAdd(&hist[(int)(u >> 16) - n0], 1);
  }
  __syncthreads();
  int v = (t < nn) ? hist[t] + 1 : 0;
  sh[t] = v;
  __syncthreads();
  for (int d = 1; d < 256; d <<= 1) {
    int add = (t >= d) ? sh[t - d] : 0;
    __syncthreads();
    sh[t] += add;
    __syncthreads();
  }
  if (t < nn) {
    int base = bukStart[b] + sh[t] - v;
    cur[t] = base;
    begS[t] = base;
    offs[n0 + t] = base;
  }
  __syncthreads();
  for (int p = t; p < m; p += 256) {
    float4 rec = staged[sbase + p];
    unsigned int u = (unsigned int)__float_as_int(rec.w);
    int pos = atomicAdd(&cur[(int)(u >> 16) - n0], 1);
    rec.w = __int_as_float((int)(u & 0xffffu) * 256);
    e4[pos] = rec;
  }
  __syncthreads();
  if (t < nn) {
    int beg = begS[t], last = cur[t];  // cur == self-loop slot after placement
    float s0 = 0.f, s1 = 0.f, s2 = 0.f;
    for (int p = beg; p < last; ++p) {
      float4 r = e4[p];
      s0 += r.x;
      s1 += r.y;
      s2 += r.z;
    }
    float invc = 1.0f / fmaxf((float)(last - beg), 1.0f);
    float4 r;
    r.x = s0 * invc;
    r.y = s1 * invc;
    r.z = s2 * invc;
    r.w = __int_as_float((n0 + t) * 256);
    e4[last] = r;
  }
}

// ---------------- converters / param packing ----------------

__global__ void k_convx(const float* __restrict__ x, unsigned short* __restrict__ xb, int n) {
  int i = (blockIdx.x * blockDim.x + threadIdx.x) * 4;
  if (i >= n) return;
  float4 v = *(const float4*)&x[i];
  ushort4 o;
  o.x = f2bf(v.x); o.y = f2bf(v.y); o.z = f2bf(v.z); o.w = f2bf(v.w);
  *(ushort4*)&xb[i] = o;
}

__global__ void k_convW(const float* __restrict__ w0, const float* __restrict__ w1,
                        const float* __restrict__ w2, const float* __restrict__ w3,
                        const float* __restrict__ w4, const float* __restrict__ w5,
                        unsigned short* __restrict__ dst) {
  const float* srcs[6] = {w0, w1, w2, w3, w4, w5};
  const float* s = srcs[blockIdx.y];
  int i = blockIdx.x * 256 + threadIdx.x;  // 0..16383
  dst[(size_t)blockIdx.y * 16384 + i] = f2bf(s[i]);
}

// per-layer, per-lane score params: tab[l][sl][16] = {wea[4], web[4], wec[4], att*LOG2E[4]}
__global__ void k_pack(const float* __restrict__ We0, const float* __restrict__ att0,
                       const float* __restrict__ We1, const float* __restrict__ att1,
                       const float* __restrict__ We2, const float* __restrict__ att2,
                       float* __restrict__ tab) {
  int l = blockIdx.x;   // 3
  int t = threadIdx.x;  // 32 (= sl)
  const float* We = (l == 0) ? We0 : ((l == 1) ? We1 : We2);
  const float* att = (l == 0) ? att0 : ((l == 1) ? att1 : att2);
  float* o = tab + (size_t)l * 512 + t * 16;
#pragma unroll
  for (int j = 0; j < 4; ++j) {
    o[j] = We[(t * 4 + j) * 3 + 0];
    o[4 + j] = We[(t * 4 + j) * 3 + 1];
    o[8 + j] = We[(t * 4 + j) * 3 + 2];
    o[12 + j] = att[t * 4 + j] * LOG2E;
  }
}

// ---------------- MFMA GEMM (swapped operands): out_bf16[n][j] = bias[j] + x[n]·W[j] ----------------
// A=W rows (channel jt*16+m), B=x rows (node row0+m); D row=channel q*4+r,
// col=node m -> lane holds 4 contiguous channels -> uint2 packed stores.
__global__ __launch_bounds__(256) void k_gemm_mfma(const unsigned short* __restrict__ xb,
                                                   const unsigned short* __restrict__ Wb,
                                                   const float* __restrict__ bl, const float* __restrict__ br,
                                                   unsigned short* __restrict__ xlb,
                                                   unsigned short* __restrict__ xrb, int N) {
  int wave = threadIdx.x >> 6;
  int lane = threadIdx.x & 63;
  int which = blockIdx.y;
  const unsigned short* W = Wb + (size_t)which * 16384;
  const float* bias = which ? br : bl;
  unsigned short* out = which ? xrb : xlb;

  int row0 = (blockIdx.x * 4 + wave) * 16;
  if (row0 >= N) return;
  int m = lane & 15;
  int q = lane >> 4;

  int brow = row0 + m;
  if (brow >= N) brow = N - 1;
  const unsigned short* xrow = xb + (size_t)brow * 128 + q * 8;

  bf16x8 bfrag[4];
#pragma unroll
  for (int kt = 0; kt < 4; ++kt) bfrag[kt] = *(const bf16x8*)(xrow + kt * 32);

  f32x4 acc[8];
#pragma unroll
  for (int jt = 0; jt < 8; ++jt) acc[jt] = (f32x4){0.f, 0.f, 0.f, 0.f};

  const unsigned short* wbase = W + (size_t)m * 128 + q * 8;
#pragma unroll
  for (int kt = 0; kt < 4; ++kt) {
#pragma unroll
    for (int jt = 0; jt < 8; ++jt) {
      bf16x8 a = *(const bf16x8*)(wbase + (size_t)jt * 16 * 128 + kt * 32);
      acc[jt] = __builtin_amdgcn_mfma_f32_16x16x32_bf16(a, bfrag[kt], acc[jt], 0, 0, 0);
    }
  }

  int node = row0 + m;
  if (node < N) {
    unsigned short* orow = out + (size_t)node * 128 + q * 4;
#pragma unroll
    for (int jt = 0; jt < 8; ++jt) {
      float4 bs = *(const float4*)&bias[jt * 16 + q * 4];
      uint2 pack;
      pack.x = (unsigned int)f2bf(acc[jt][0] + bs.x) | ((unsigned int)f2bf(acc[jt][1] + bs.y) << 16);
      pack.y = (unsigned int)f2bf(acc[jt][2] + bs.z) | ((unsigned int)f2bf(acc[jt][3] + bs.w) << 16);
      *(uint2*)(orow + jt * 16) = pack;
    }
  }
}

// ---------------- fused: score + softmax(exp2) + weighted agg + epilogue ----------------
// one wave per node; lanes 0-31 = edge p, lanes 32-63 = edge p+1 (same node);
// each lane owns 4 channels c = (lane&31)*4; head group = 8 lanes.
__global__ __launch_bounds__(256) void k_agg(const unsigned short* __restrict__ xlb,
                                             const unsigned short* __restrict__ xrb,
                                             const float4* __restrict__ e4,
                                             const int* __restrict__ offs,
                                             const float* __restrict__ scoreTab,
                                             const float* __restrict__ bo,
                                             const float* __restrict__ lng, const float* __restrict__ lnb,
                                             unsigned short* __restrict__ xnext_bf,
                                             float* __restrict__ emb, int last, int N) {
  int w = (blockIdx.x * blockDim.x + threadIdx.x) >> 6;
  if (w >= N) return;
  int lane = threadIdx.x & 63;
  int half = lane >> 5;
  int sl = lane & 31;
  int c = sl * 4;
  unsigned int c2 = (unsigned int)(c * 2);  // byte offset into bf16 row
  int beg = offs[w], end = offs[w + 1];
  int cnt = end - beg;

  // packed per-lane params
  f32x4 xr4, wea, web, wec, at4;
  {
    const float4* tp = (const float4*)(scoreTab + (size_t)sl * 16);
    float4 pa = tp[0], pb = tp[1], pc = tp[2], pt = tp[3];
    wea[0] = pa.x; wea[1] = pa.y; wea[2] = pa.z; wea[3] = pa.w;
    web[0] = pb.x; web[1] = pb.y; web[2] = pb.z; web[3] = pb.w;
    wec[0] = pc.x; wec[1] = pc.y; wec[2] = pc.z; wec[3] = pc.w;
    at4[0] = pt.x; at4[1] = pt.y; at4[2] = pt.z; at4[3] = pt.w;
    uint2 vr = *(const uint2*)&xrb[(size_t)w * 128 + c];
    xr4[0] = __uint_as_float(vr.x << 16);
    xr4[1] = __uint_as_float(vr.x & 0xffff0000u);
    xr4[2] = __uint_as_float(vr.y << 16);
    xr4[3] = __uint_as_float(vr.y & 0xffff0000u);
  }

  const char* xlB = (const char*)xlb;
  const char* e4B = (const char*)e4;
  unsigned int lastoff = (unsigned int)(end - 1) << 4;
  unsigned int eoff = (unsigned int)(beg + half) << 4;
  if (eoff > lastoff) eoff = lastoff;  // cnt==1, half 1 clamps

  float l = 0.f;
  f32x4 acc = {0.f, 0.f, 0.f, 0.f};

  int T = (cnt + 1) >> 1;  // pair iterations
  float4 eC = *(const float4*)(e4B + eoff);

#pragma unroll 2
  for (int it = 0; it < T - 1; ++it) {
    unsigned int noff = eoff + 32u;
    if (noff > lastoff) noff = lastoff;
    float4 eN = *(const float4*)(e4B + noff);
    eoff = noff;

    unsigned int go = (unsigned int)__float_as_int(eC.w) + c2;
    uint2 v = *(const uint2*)(xlB + go);
    f32x4 xl4;
    xl4[0] = __uint_as_float(v.x << 16);
    xl4[1] = __uint_as_float(v.x & 0xffff0000u);
    xl4[2] = __uint_as_float(v.y << 16);
    xl4[3] = __uint_as_float(v.y & 0xffff0000u);

    f32x4 t = xr4 + wea * eC.x + web * eC.y + wec * eC.z + xl4;
    t[0] = fmaxf(t[0], 0.2f * t[0]);
    t[1] = fmaxf(t[1], 0.2f * t[1]);
    t[2] = fmaxf(t[2], 0.2f * t[2]);
    t[3] = fmaxf(t[3], 0.2f * t[3]);
    float s = t[0] * at4[0] + t[1] * at4[1] + t[2] * at4[2] + t[3] * at4[3];
    float wgt = __builtin_amdgcn_exp2f(dpp_sum8(s));
    l += wgt;
    acc += xl4 * wgt;
    eC = eN;
  }
  {  // peeled last pair with validity mask
    int idx = 2 * (T - 1) + half;
    unsigned int go = (unsigned int)__float_as_int(eC.w) + c2;
    uint2 v = *(const uint2*)(xlB + go);
    f32x4 xl4;
    xl4[0] = __uint_as_float(v.x << 16);
    xl4[1] = __uint_as_float(v.x & 0xffff0000u);
    xl4[2] = __uint_as_float(v.y << 16);
    xl4[3] = __uint_as_float(v.y & 0xffff0000u);
    f32x4 t = xr4 + wea * eC.x + web * eC.y + wec * eC.z + xl4;
    t[0] = fmaxf(t[0], 0.2f * t[0]);
    t[1] = fmaxf(t[1], 0.2f * t[1]);
    t[2] = fmaxf(t[2], 0.2f * t[2]);
    t[3] = fmaxf(t[3], 0.2f * t[3]);
    float s = t[0] * at4[0] + t[1] * at4[1] + t[2] * at4[2] + t[3] * at4[3];
    float wgt = __builtin_amdgcn_exp2f(dpp_sum8(s));
    if (idx >= cnt) wgt = 0.f;
    l += wgt;
    acc += xl4 * wgt;
  }

  // combine halves
  l += __shfl_xor(l, 32);
  acc[0] += __shfl_xor(acc[0], 32);
  acc[1] += __shfl_xor(acc[1], 32);
  acc[2] += __shfl_xor(acc[2], 32);
  acc[3] += __shfl_xor(acc[3], 32);

  float inv = 1.0f / l;
  f32x4 o;
  const float4 bo4 = *(const float4*)&bo[c];
  o[0] = acc[0] * inv + bo4.x;
  o[1] = acc[1] * inv + bo4.y;
  o[2] = acc[2] * inv + bo4.z;
  o[3] = acc[3] * inv + bo4.w;

  if (last) {
    if (half == 0) {
      float4 st = {o[0], o[1], o[2], o[3]};
      *(float4*)&emb[(size_t)w * 128 + c] = st;
    }
  } else {
    f32x4 r;
    r[0] = fmaxf(o[0], 0.f);
    r[1] = fmaxf(o[1], 0.f);
    r[2] = fmaxf(o[2], 0.f);
    r[3] = fmaxf(o[3], 0.f);
    float s = r[0] + r[1] + r[2] + r[3];
    s += __shfl_xor(s, 1);
    s += __shfl_xor(s, 2);
    s += __shfl_xor(s, 4);
    s += __shfl_xor(s, 8);
    s += __shfl_xor(s, 16);
    float mu = s * 0.0078125f;  // /128
    f32x4 d;
    d[0] = r[0] - mu;
    d[1] = r[1] - mu;
    d[2] = r[2] - mu;
    d[3] = r[3] - mu;
    float v2 = d[0] * d[0] + d[1] * d[1] + d[2] * d[2] + d[3] * d[3];
    v2 += __shfl_xor(v2, 1);
    v2 += __shfl_xor(v2, 2);
    v2 += __shfl_xor(v2, 4);
    v2 += __shfl_xor(v2, 8);
    v2 += __shfl_xor(v2, 16);
    float var = v2 * 0.0078125f;
    float rstd = rsqrtf(var + LN_EPS);
    if (half == 0) {
      const float4 g4 = *(const float4*)&lng[c];
      const float4 b4 = *(const float4*)&lnb[c];
      float o0 = d[0] * rstd * g4.x + b4.x;
      float o1 = d[1] * rstd * g4.y + b4.y;
      float o2 = d[2] * rstd * g4.z + b4.z;
      float o3 = d[3] * rstd * g4.w + b4.w;
      uint2 pack;
      pack.x = (unsigned int)f2bf(o0) | ((unsigned int)f2bf(o1) << 16);
      pack.y = (unsigned int)f2bf(o2) | ((unsigned int)f2bf(o3) << 16);
      *(uint2*)&xnext_bf[(size_t)w * 128 + c] = pack;
    }
  }
}

// ---------------- graph max-pool (relu implicit: atomicMax vs 0-init) ----------------
__global__ void k_pool(const float* __restrict__ emb, const int* __restrict__ batch,
                       float* __restrict__ pooled, int N) {
  int c = threadIdx.x & 127;
  int half = threadIdx.x >> 7;
  int base = blockIdx.x * 64 + half;
  int limit = min(blockIdx.x * 64 + 64, N);
  float cur = 0.f;
  int curg = -1;
  for (int n = base; n < limit; n += 2) {
    int g = batch[n];
    if (g != curg) {
      if (curg >= 0) atomicMax((unsigned int*)&pooled[curg * 128 + c], __float_as_uint(cur));
      curg = g;
      cur = 0.f;
    }
    cur = fmaxf(cur, emb[(size_t)n * 128 + c]);
  }
  if (curg >= 0) atomicMax((unsigned int*)&pooled[curg * 128 + c], __float_as_uint(cur));
}

// ---------------- MLP: 128 -> 32 -> 32 -> 32 -> 1 ----------------
__global__ void k_mlp(const float* __restrict__ pooled,
                      const float* __restrict__ pw1, const float* __restrict__ pb1,
                      const float* __restrict__ pw2, const float* __restrict__ pb2,
                      const float* __restrict__ pw3, const float* __restrict__ pb3,
                      const float* __restrict__ pw4, const float* __restrict__ pb4,
                      float* __restrict__ out) {
  int g = blockIdx.x;
  int t = threadIdx.x;  // 64 threads
  __shared__ float buf1[32], buf2[32];
  if (t < 32) {
    float acc = pb1[t];
    for (int k = 0; k < 128; ++k) acc += pw1[t * 128 + k] * pooled[g * 128 + k];
    buf1[t] = fmaxf(acc, 0.f);
  }
  __syncthreads();
  if (t < 32) {
    float acc = pb2[t];
    for (int k = 0; k < 32; ++k) acc += pw2[t * 32 + k] * buf1[k];
    buf2[t] = fmaxf(acc, 0.f);
  }
  __syncthreads();
  if (t < 32) {
    float acc = pb3[t];
    for (int k = 0; k < 32; ++k) acc += pw3[t * 32 + k] * buf2[k];
    buf1[t] = fmaxf(acc, 0.f);
  }
  __syncthreads();
  if (t == 0) {
    float acc = pb4[0];
    for (int k = 0; k < 32; ++k) acc += pw4[k] * buf1[k];
    out[g] = acc;
  }
}

// ---------------------------------------------------------------------------

extern "C" void kernel_launch(void* const* d_in, const int* in_sizes, int n_in,
                              void* d_out, int out_size, void* d_ws, size_t ws_size,
                              hipStream_t stream) {
  const float* x_in = (const float*)d_in[0];
  const int* ei = (const int*)d_in[1];
  const int* batch = (const int*)d_in[2];
  const float* ea = (const float*)d_in[3];

  const int N = in_sizes[0] / 128;
  const int E = in_sizes[1] / 2;
  const int EP = E + N;
  const int G = out_size - N * 128;
  const int NBUK = (N + 255) / 256;

  const float *Wl[3], *bl[3], *Wr[3], *br[3], *We[3], *att[3], *bo[3];
  for (int l = 0; l < 3; ++l) {
    Wl[l] = (const float*)d_in[4 + 7 * l];
    bl[l] = (const float*)d_in[5 + 7 * l];
    Wr[l] = (const float*)d_in[6 + 7 * l];
    br[l] = (const float*)d_in[7 + 7 * l];
    We[l] = (const float*)d_in[8 + 7 * l];
    att[l] = (const float*)d_in[9 + 7 * l];
    bo[l] = (const float*)d_in[10 + 7 * l];
  }
  const float* lng[2] = {(const float*)d_in[25], (const float*)d_in[27]};
  const float* lnb[2] = {(const float*)d_in[26], (const float*)d_in[28]};
  const float* pw1 = (const float*)d_in[29];
  const float* pb1 = (const float*)d_in[30];
  const float* pw2 = (const float*)d_in[31];
  const float* pb2 = (const float*)d_in[32];
  const float* pw3 = (const float*)d_in[33];
  const float* pb3 = (const float*)d_in[34];
  const float* pw4 = (const float*)d_in[35];
  const float* pb4 = (const float*)d_in[36];

  char* base = (char*)d_ws;
  size_t cur = 0;
  auto carve = [&](size_t bytes) -> char* {
    char* p = base + cur;
    cur += (bytes + 255) & ~(size_t)255;
    return p;
  };
  unsigned short* xlb = (unsigned short*)carve((size_t)N * 128 * 2);
  unsigned short* xrb = (unsigned short*)carve((size_t)N * 128 * 2);
  unsigned short* xb = (unsigned short*)carve((size_t)N * 128 * 2);  // bf16 activations
  unsigned short* Wb = (unsigned short*)carve((size_t)6 * 16384 * 2);
  float4* e4 = (float4*)carve((size_t)EP * 16);
  float4* staged = (float4*)carve((size_t)NBUK * BCAP * 16);
  int* offs = (int*)carve((size_t)(N + 1) * 4);
  int* gcnt = (int*)carve((size_t)NBUK * 4);
  int* bukStart = (int*)carve((size_t)(NBUK + 1) * 4);
  float* scoreTab = (float*)carve((size_t)3 * 512 * 4);
  float* pooled = (float*)carve((size_t)G * 128 * 4);

  float* emb_out = (float*)d_out;
  float* mlp_out = (float*)d_out + (size_t)N * 128;

  hipMemsetAsync(gcnt, 0, (size_t)NBUK * 4, stream);
  hipMemsetAsync(pooled, 0, (size_t)G * 128 * 4, stream);

  k_binA<<<(E + CHUNK - 1) / CHUNK, 256, 0, stream>>>(ei, ea, gcnt, staged, E, NBUK);
  k_bscan<<<1, 256, 0, stream>>>(gcnt, bukStart, offs, N, NBUK, EP);
  k_binB<<<NBUK, 256, 0, stream>>>(staged, gcnt, bukStart, e4, offs, N);

  k_convx<<<(N * 128 / 4 + 255) / 256, 256, 0, stream>>>(x_in, xb, N * 128);
  {
    dim3 g(64, 6);
    k_convW<<<g, 256, 0, stream>>>(Wl[0], Wr[0], Wl[1], Wr[1], Wl[2], Wr[2], Wb);
  }
  k_pack<<<3, 32, 0, stream>>>(We[0], att[0], We[1], att[1], We[2], att[2], scoreTab);

  for (int l = 0; l < 3; ++l) {
    dim3 ggrid((N + 63) / 64, 2);
    k_gemm_mfma<<<ggrid, 256, 0, stream>>>(xb, Wb + (size_t)l * 32768, bl[l], br[l], xlb, xrb, N);
    int last = (l == 2) ? 1 : 0;
    const float* g = last ? bo[l] : lng[l];
    const float* b = last ? bo[l] : lnb[l];
    k_agg<<<(N * 64 + 255) / 256, 256, 0, stream>>>(xlb, xrb, e4, offs,
                                                    scoreTab + (size_t)l * 512,
                                                    bo[l], g, b,
                                                    xb, emb_out, last, N);
  }

  k_pool<<<(N + 63) / 64, 256, 0, stream>>>(emb_out, batch, pooled, N);
  k_mlp<<<G, 64, 0, stream>>>(pooled, pw1, pb1, pw2, pb2, pw3, pb3, pw4, pb4, mlp_out);
}